// Round 11
// baseline (885.519 us; speedup 1.0000x reference)
//
#include <hip/hip_runtime.h>
#include <hip/hip_bf16.h>

// UniqueEq3Net: conv stack -> e(640,64); t = e⊗e⊗e never materialized.
// Layer1 (transposed MFMA): h^T[o][k] = (B1⊙e_l)^T · U + Y0 + cadd.
// R11: kh01/kh2 at 512 threads, l-range split across two 4-wave groups sharing
// one LDS setup -> 2x resident waves (latency hiding), sacc combined via LDS.

typedef unsigned short u16;
typedef __attribute__((ext_vector_type(8))) short bf8_t;   // 8 bf16 (4 VGPRs)
typedef __attribute__((ext_vector_type(4))) float f4_t;

#define LSTR 72   // padded LDS row stride (u16): 144B rows, 16B-aligned

__device__ inline u16 f2bf(float f){
  union { float f; unsigned u; } v; v.f = f;
  unsigned r = v.u + 0x7fffu + ((v.u >> 16) & 1u);
  return (u16)(r >> 16);
}
__device__ inline float bflo(unsigned u){ union { unsigned x; float f; } v; v.x = u << 16; return v.f; }
__device__ inline float bfhi(unsigned u){ union { unsigned x; float f; } v; v.x = u & 0xffff0000u; return v.f; }
__device__ inline unsigned pack2(float a, float b){ return (unsigned)f2bf(a) | ((unsigned)f2bf(b) << 16); }
__device__ inline unsigned cvtpk(float lo, float hi){
  __hip_bfloat162 h2 = __float22bfloat162_rn(make_float2(lo, hi));
  union { __hip_bfloat162 h; unsigned u; } c; c.h = h2; return c.u;
}
__device__ inline void unpack8(bf8_t x, float* o){
  union { bf8_t v; unsigned u[4]; } q; q.v = x;
  #pragma unroll
  for (int p = 0; p < 4; ++p){ o[2*p] = bflo(q.u[p]); o[2*p+1] = bfhi(q.u[p]); }
}
__device__ inline f4_t shfl4x(f4_t v, int m){
  f4_t r;
  r[0] = __shfl_xor(v[0], m); r[1] = __shfl_xor(v[1], m);
  r[2] = __shfl_xor(v[2], m); r[3] = __shfl_xor(v[3], m);
  return r;
}

// ---------------- conv1 + pool -> z1t ; blocks >=640 do weight prep ----------------
__global__ __launch_bounds__(256) void kconv1(const float* __restrict__ x, const float* __restrict__ w1,
                                              const float* __restrict__ b1, u16* __restrict__ z1t,
                                              const float* __restrict__ w2, const float* __restrict__ fcw,
                                              u16* __restrict__ wt2, u16* __restrict__ fcwT){
  __shared__ float simg[784];
  int img = blockIdx.x, tid = threadIdx.x;
  if (img >= 640){
    int t = (img - 640)*256 + tid, stride = 32*256;
    for (int i = t; i < 51200; i += stride){
      int tap = i >> 11, rc = i & 2047, co = rc >> 5, ci = rc & 31;
      wt2[i] = f2bf(w2[co*800 + ci*25 + tap]);
    }
    for (int i = t; i < 65536; i += stride){
      int o = i >> 10, k = i & 1023;
      fcwT[i] = f2bf(fcw[k*64 + o]);
    }
    return;
  }
  for (int i = tid; i < 784; i += 256) simg[i] = x[img*784 + i];
  const int c = tid & 31;
  float wc[25];
  #pragma unroll
  for (int t = 0; t < 25; ++t) wc[t] = w1[c*25 + t];
  const float bb = b1[c];
  __syncthreads();
  #pragma unroll 2
  for (int it = 0; it < 18; ++it){
    int p = (tid >> 5) + it*8;
    int py = p / 12, px = p % 12;
    float patch[36];
    const float* sp = &simg[2*py*28 + 2*px];
    #pragma unroll
    for (int yy = 0; yy < 6; ++yy)
      #pragma unroll
      for (int xx = 0; xx < 6; ++xx) patch[yy*6+xx] = sp[yy*28+xx];
    float mx = -1e30f;
    #pragma unroll
    for (int sy = 0; sy < 2; ++sy)
    #pragma unroll
    for (int sx = 0; sx < 2; ++sx){
      float s = bb;
      #pragma unroll
      for (int dy = 0; dy < 5; ++dy)
        #pragma unroll
        for (int dx = 0; dx < 5; ++dx)
          s += patch[(sy+dy)*6 + sx+dx] * wc[dy*5+dx];
      mx = fmaxf(mx, s);
    }
    z1t[(size_t)img*4608 + p*32 + c] = f2bf(fmaxf(mx, 0.f));
  }
}

// ---------------- conv2 (MFMA, 25 shifted K=32 GEMMs) + pool -> z2g (640,1024) bf16 ----------------
__global__ __launch_bounds__(256) void kconv2m(const u16* __restrict__ z1t, const u16* __restrict__ wt2,
                                               const float* __restrict__ b2, u16* __restrict__ z2g){
  __shared__ __align__(16) u16 sz[4608];
  __shared__ __align__(16) u16 sz2[1024];
  int img = blockIdx.x, tid = threadIdx.x;
  for (int i = tid; i < 576; i += 256)
    ((uint4*)sz)[i] = ((const uint4*)(z1t + (size_t)img*4608))[i];
  __syncthreads();
  const int wave = tid >> 6, lane = tid & 63, l15 = lane & 15, quad = lane >> 4;
  const int y = wave*2 + (l15 >> 3), x = l15 & 7;
  f4_t acc[4];
  acc[0] = (f4_t){0.f,0.f,0.f,0.f}; acc[1] = acc[0]; acc[2] = acc[0]; acc[3] = acc[0];
  #pragma unroll
  for (int dy = 0; dy < 5; ++dy)
    #pragma unroll
    for (int dx = 0; dx < 5; ++dx){
      const int tap = dy*5 + dx;
      bf8_t af = *(const bf8_t*)&sz[((y+dy)*12 + (x+dx))*32 + quad*8];
      const u16* wp = wt2 + tap*2048 + l15*32 + quad*8;
      #pragma unroll
      for (int nt = 0; nt < 4; ++nt){
        bf8_t bf = *(const bf8_t*)(wp + nt*512);
        acc[nt] = __builtin_amdgcn_mfma_f32_16x16x32_bf16(af, bf, acc[nt], 0, 0, 0);
      }
    }
  #pragma unroll
  for (int nt = 0; nt < 4; ++nt){
    int co = nt*16 + l15;
    float v0 = fmaxf(acc[nt][0], acc[nt][1]);
    float v1 = fmaxf(acc[nt][2], acc[nt][3]);
    v0 = fmaxf(v0, __shfl_xor(v0, 32));
    v1 = fmaxf(v1, __shfl_xor(v1, 32));
    if (quad < 2){
      float bb = b2[co];
      sz2[co*16 + wave*4 + quad*2 + 0] = f2bf(fmaxf(v0 + bb, 0.f));
      sz2[co*16 + wave*4 + quad*2 + 1] = f2bf(fmaxf(v1 + bb, 0.f));
    }
  }
  __syncthreads();
  if (tid < 128) ((uint4*)(z2g + (size_t)img*1024))[tid] = ((const uint4*)sz2)[tid];
}

// ---------------- fc: e = relu(z2g @ fcw + fcb) ----------------
__global__ __launch_bounds__(256) void kfc(const u16* __restrict__ z2g, const u16* __restrict__ fcwT,
                                           const float* __restrict__ fcb,
                                           float* __restrict__ e_f, u16* __restrict__ e_b){
  __shared__ __align__(16) u16 sA[16*1032];
  int img0 = blockIdx.x*16, tid = threadIdx.x;
  for (int i = tid; i < 2048; i += 256){
    int row = i >> 7, c16 = i & 127;
    ((uint4*)(sA + row*1032))[c16] = ((const uint4*)(z2g + (size_t)(img0+row)*1024))[c16];
  }
  __syncthreads();
  const int wave = tid >> 6, lane = tid & 63, l15 = lane & 15, quad = lane >> 4;
  const int o = wave*16 + l15;
  f4_t acc = (f4_t){0.f,0.f,0.f,0.f};
  #pragma unroll 8
  for (int ks = 0; ks < 32; ++ks){
    bf8_t af = *(const bf8_t*)&sA[l15*1032 + ks*32 + quad*8];
    bf8_t bf = *(const bf8_t*)(fcwT + (size_t)o*1024 + ks*32 + quad*8);
    acc = __builtin_amdgcn_mfma_f32_16x16x32_bf16(af, bf, acc, 0, 0, 0);
  }
  const float bb = fcb[o];
  #pragma unroll
  for (int r = 0; r < 4; ++r){
    int img = img0 + quad*4 + r;
    float v = fmaxf(acc[r] + bb, 0.f);
    e_f[img*64 + o] = v;
    e_b[img*64 + o] = f2bf(v);
  }
}

// ---------------- per-b precompute, grid (16,4) ----------------
__global__ __launch_bounds__(256) void kprep(const float* __restrict__ e_f, const float* __restrict__ e1w,
    const float* __restrict__ e1b, const float* __restrict__ e2w,
    float* __restrict__ Sg, u16* __restrict__ Vt, float* __restrict__ c0,
    float* __restrict__ P5, float* __restrict__ P6, u16* __restrict__ W2T0,
    u16* __restrict__ W3St){
  int b = blockIdx.x, ph = blockIdx.y, tid = threadIdx.x;
  __shared__ float se[2560];
  __shared__ float S[64], S2[64], S3[64];
  for (int i = tid; i < 2560; i += 256) se[i] = e_f[b*2560 + i];
  __syncthreads();
  if (tid < 64){
    float s = 0.f;
    for (int i = 0; i < 40; ++i) s += se[i*64 + tid];
    S[tid] = s; S2[tid] = s*s; S3[tid] = s*s*s;
    if (ph == 0) Sg[b*64 + tid] = s;
  }
  __syncthreads();
  {
    const int m = ph;
    for (int idx = tid; idx < 4096; idx += 256){
      int o = idx >> 6, d = idx & 63;
      float v;
      if (m == 0)      v = e1w[d*64 + o];
      else if (m == 1) v = S[d] * e1w[4096  + d*64 + o];
      else if (m == 2) v = S[d] * e1w[8192  + d*64 + o];
      else             v = S2[d] * e1w[16384 + d*64 + o];
      Vt[(size_t)b*16384 + m*4096 + idx] = f2bf(v);
    }
  }
  if (ph == 0){
    if (tid < 64){
      float a = e1b[tid];
      for (int d = 0; d < 64; ++d) a += S3[d] * e1w[7*4096 + d*64 + tid];
      c0[b*64 + tid] = a;
    }
  } else if (ph == 1){
    for (int idx = tid; idx < 4096; idx += 256){
      int o = idx >> 6, d = idx & 63;
      W3St[(size_t)b*4096 + idx] = f2bf(S[d] * e1w[3*4096 + d*64 + o]);
    }
  } else {
    int lo = (ph == 2) ? 0 : 1280, hi = lo + 1280;
    for (int idx = lo + tid; idx < hi; idx += 256){
      int j = idx >> 6, o = idx & 63;
      float a5 = 0.f, a6 = 0.f;
      for (int d = 0; d < 64; ++d){
        float es = se[j*64 + d] * S2[d];
        a5 += es * e1w[5*4096 + d*64 + o];
        a6 += es * e1w[6*4096 + d*64 + o];
      }
      P5[(b*40+j)*64 + o] = a5;
      P6[(b*40+j)*64 + o] = a6;
    }
    if (ph == 3 && b == 0){
      for (int idx = tid; idx < 2048; idx += 256){
        int o = idx >> 6, d = idx & 63;
        W2T0[o*64 + d] = f2bf(e2w[d*32 + o]);
      }
    }
  }
}

// ---------------- kpq: P[i] tile in LDS AND Q3c[b,i,:,:] via MFMA ----------------
__global__ __launch_bounds__(256) void kpq(const u16* __restrict__ e_b, const u16* __restrict__ W3St,
    const float* __restrict__ P5, const float* __restrict__ P6, const float* __restrict__ c0,
    float* __restrict__ Q3c){
  __shared__ __align__(16) u16 sP[48*LSTR];
  __shared__ __align__(16) u16 sW[64*LSTR];
  int blk = blockIdx.x, b = blk/40, i = blk%40, tid = threadIdx.x;
  const int wave = tid >> 6, lane = tid & 63, l15 = lane & 15, quad = lane >> 4;
  for (int idx = tid; idx < 2048; idx += 256){
    int o = idx >> 5, c = idx & 31;
    ((unsigned*)(sW + o*LSTR))[c] = ((const unsigned*)(W3St + (size_t)b*4096))[idx];
  }
  const unsigned* eb32 = (const unsigned*)(e_b + (size_t)b*2560);
  const unsigned* el = eb32 + i*32;
  #pragma unroll
  for (int it = 0; it < 6; ++it){
    int idx = tid + it*256;
    int k = idx >> 5, d2 = idx & 31;
    unsigned pv = 0;
    if (k < 40){
      unsigned ul = el[d2], uk = eb32[k*32 + d2];
      pv = pack2(bflo(ul)*bflo(uk), bfhi(ul)*bfhi(uk));
    }
    ((unsigned*)(sP + k*LSTR))[d2] = pv;
  }
  __syncthreads();
  bf8_t wf[2];
  #pragma unroll
  for (int ks = 0; ks < 2; ++ks)
    wf[ks] = *(const bf8_t*)&sW[(wave*16 + l15)*LSTR + ks*32 + quad*8];
  f4_t acc[3];
  #pragma unroll
  for (int n = 0; n < 3; ++n){
    f4_t a = (f4_t){0.f,0.f,0.f,0.f};
    #pragma unroll
    for (int ks = 0; ks < 2; ++ks){
      bf8_t pkf = *(const bf8_t*)&sP[(n*16 + l15)*LSTR + ks*32 + quad*8];
      a = __builtin_amdgcn_mfma_f32_16x16x32_bf16(wf[ks], pkf, a, 0, 0, 0);
    }
    acc[n] = a;
  }
  const int obase = wave*16 + quad*4;
  f4_t p6v = *(const f4_t*)&P6[(b*40+i)*64 + obase];
  f4_t c0v = *(const f4_t*)&c0[b*64 + obase];
  #pragma unroll
  for (int n = 0; n < 3; ++n){
    int j = n*16 + l15;
    if (j < 40){
      f4_t p5v = *(const f4_t*)&P5[(b*40+j)*64 + obase];
      f4_t outv = acc[n] + p5v + p6v + c0v;
      *(f4_t*)&Q3c[((size_t)((b*40+i)*40 + j))*64 + obase] = outv;
    }
  }
}

// ---------------- layer-1 reduction passes; 512 thr, l-split across 2 groups ----------------
__global__ __launch_bounds__(512, 8) void kh01(
    const u16* __restrict__ e_b, const float* __restrict__ e_f,
    const u16* __restrict__ Vt, const float* __restrict__ Q3c,
    float* __restrict__ si2, float* __restrict__ sj2, float* __restrict__ sk2)
{
  __shared__ __align__(16) char smem[25344];
  u16*   sU  = (u16*)smem;             // dead after setup
  u16*   sB1 = (u16*)(smem + 6912);    // dead after setup
  u16*   sB0 = (u16*)(smem + 16128);   // dead after setup
  float* sUf = (float*)smem;           // 10240B, aliases sU+sB1
  float* sAcc = (float*)(smem + 10240);// 48 rows x stride 68 f32 = 13056B (post-loop only)
  const int tid = threadIdx.x;
  const int b = blockIdx.x / 40, fix = blockIdx.x % 40;
  const int mode = blockIdx.y;
  const int wave = tid >> 6, lane = tid & 63, l15 = lane & 15, quad = lane >> 4;
  const int g = wave >> 2, w4 = wave & 3;
  const int lbeg = g*20;
  const f4_t z4 = (f4_t){0.f,0.f,0.f,0.f};

  for (int idx = tid; idx < 1536; idx += 512){
    int r = idx >> 5, c = idx & 31;
    unsigned v = (r < 40) ? ((const unsigned*)e_b)[(b*40 + r)*32 + c] : 0u;
    ((unsigned*)(sU + r*LSTR))[c] = v;
  }
  float efr[5];
  #pragma unroll
  for (int t = 0; t < 5; ++t) efr[t] = e_f[b*2560 + tid + t*512];
  const unsigned* eg = (const unsigned*)(e_b + (size_t)(b*40 + fix)*64);
  const unsigned* Vb = (const unsigned*)(Vt + (size_t)b*16384);
  for (int idx = tid; idx < 2048; idx += 512){
    int o = idx >> 5, d2 = idx & 31;
    unsigned eu = eg[d2];
    unsigned v0 = Vb[o*32 + d2];
    unsigned vA = Vb[(2-mode)*2048 + o*32 + d2];
    unsigned vB = Vb[(1+mode)*2048 + o*32 + d2];
    unsigned v3 = Vb[3*2048 + o*32 + d2];
    float e0 = bflo(eu), e1 = bfhi(eu);
    ((unsigned*)(sB1 + o*LSTR))[d2] = pack2(e0*bflo(v0)+bflo(vA), e1*bfhi(v0)+bfhi(vA));
    ((unsigned*)(sB0 + o*LSTR))[d2] = pack2(e0*bflo(vB)+bflo(v3), e1*bfhi(vB)+bfhi(v3));
  }
  __syncthreads();

  f4_t b1v[4];
  bf8_t ua[3][2];
  f4_t Y0[3];
  {
    bf8_t b0f[2], b1f[2];
    float tmp[8];
    #pragma unroll
    for (int ks = 0; ks < 2; ++ks){
      b1f[ks] = *(const bf8_t*)&sB1[(w4*16 + l15)*LSTR + ks*32 + quad*8];
      b0f[ks] = *(const bf8_t*)&sB0[(w4*16 + l15)*LSTR + ks*32 + quad*8];
      unpack8(b1f[ks], tmp);
      b1v[2*ks]   = (f4_t){tmp[0],tmp[1],tmp[2],tmp[3]};
      b1v[2*ks+1] = (f4_t){tmp[4],tmp[5],tmp[6],tmp[7]};
    }
    #pragma unroll
    for (int n = 0; n < 3; ++n){
      f4_t a = z4;
      #pragma unroll
      for (int ks = 0; ks < 2; ++ks){
        ua[n][ks] = *(const bf8_t*)&sU[(n*16 + l15)*LSTR + ks*32 + quad*8];
        a = __builtin_amdgcn_mfma_f32_16x16x32_bf16(b0f[ks], ua[n][ks], a, 0, 0, 0);
      }
      Y0[n] = a;
    }
  }
  __syncthreads();
  #pragma unroll
  for (int t = 0; t < 5; ++t) sUf[tid + t*512] = efr[t];
  __syncthreads();

  const int obase = w4*16 + quad*4;
  const float km = (l15 < 8) ? 1.f : 0.f;
  const f4_t km4 = (f4_t){km, km, km, km};
  f4_t sacc[3];
  sacc[0] = z4; sacc[1] = z4; sacc[2] = z4;

  const int qstride = mode ? 64 : 2560;
  const float* qp = Q3c + (size_t)b*102400 + (mode ? (size_t)fix*2560 : (size_t)fix*64)
                    + (size_t)lbeg*qstride + obase;
  float* skp = sk2 + ((size_t)((b*40 + lbeg)*40) + fix)*64 + obase;   // stride 2560
  const float* ep = sUf + lbeg*64 + quad*8;

  f4_t cadd_n = *(const f4_t*)qp; qp += qstride;
  #pragma unroll 2
  for (int l = 0; l < 20; ++l){
    f4_t cadd = cadd_n;
    if (l < 19){ cadd_n = *(const f4_t*)qp; qp += qstride; }
    f4_t p00 = b1v[0] * *(const f4_t*)(ep);
    f4_t p01 = b1v[1] * *(const f4_t*)(ep + 4);
    f4_t p10 = b1v[2] * *(const f4_t*)(ep + 32);
    f4_t p11 = b1v[3] * *(const f4_t*)(ep + 36);
    ep += 64;
    union { bf8_t v; unsigned u[4]; } m0, m1;
    m0.u[0] = cvtpk(p00[0], p00[1]); m0.u[1] = cvtpk(p00[2], p00[3]);
    m0.u[2] = cvtpk(p01[0], p01[1]); m0.u[3] = cvtpk(p01[2], p01[3]);
    m1.u[0] = cvtpk(p10[0], p10[1]); m1.u[1] = cvtpk(p10[2], p10[3]);
    m1.u[2] = cvtpk(p11[0], p11[1]); m1.u[3] = cvtpk(p11[2], p11[3]);
    f4_t khs = z4;
    #pragma unroll
    for (int n = 0; n < 3; ++n){
      f4_t a = Y0[n];
      a = __builtin_amdgcn_mfma_f32_16x16x32_bf16(m0.v, ua[n][0], a, 0, 0, 0);
      a = __builtin_amdgcn_mfma_f32_16x16x32_bf16(m1.v, ua[n][1], a, 0, 0, 0);
      f4_t h = __builtin_elementwise_max(a + cadd, z4);
      sacc[n] += h;                         // k>=40 garbage: write-guarded later
      if (mode == 0) khs += (n == 2) ? h * km4 : h;
    }
    if (mode == 0){
      khs += shfl4x(khs, 1);
      khs += shfl4x(khs, 2);
      khs += shfl4x(khs, 4);
      khs += shfl4x(khs, 8);
      if (l15 == 0) *(f4_t*)skp = khs;
      skp += 2560;
    }
  }
  // combine the two groups' sacc through LDS (stride 68 to spread banks)
  __syncthreads();
  if (g == 1){
    #pragma unroll
    for (int n = 0; n < 3; ++n)
      *(f4_t*)&sAcc[(n*16 + l15)*68 + obase] = sacc[n];
  }
  __syncthreads();
  if (g == 0){
    float* dst = mode ? sj2 : si2;
    #pragma unroll
    for (int n = 0; n < 3; ++n){
      int k = n*16 + l15;
      if (k < 40){
        f4_t ov = sacc[n] + *(const f4_t*)&sAcc[(n*16 + l15)*68 + obase];
        *(f4_t*)&dst[((size_t)((b*40 + fix)*40 + k))*64 + obase] = ov;
      }
    }
  }
}

// ---------------- k5ar: the three 40-deep sums, grid (16,3,2) ----------------
__global__ __launch_bounds__(256) void k5ar(const float* __restrict__ si2, const float* __restrict__ sj2,
    float* __restrict__ ssij, float* __restrict__ ssik, float* __restrict__ ssjk){
  int b = blockIdx.x, which = blockIdx.y, half = blockIdx.z, tid = threadIdx.x;
  int base = half*1280;
  for (int idx = base + tid; idx < base + 1280; idx += 256){
    int r = idx >> 6, d = idx & 63;
    float a = 0.f;
    if (which == 0){
      for (int j = 0; j < 40; ++j) a += si2[((size_t)(b*40+j)*40 + r)*64 + d];
      ssij[b*2560 + idx] = a;
    } else if (which == 1){
      const float* p = &si2[(size_t)(b*40+r)*2560 + d];
      for (int k = 0; k < 40; ++k) a += p[k*64];
      ssik[b*2560 + idx] = a;
    } else {
      const float* q = &sj2[(size_t)(b*40+r)*2560 + d];
      for (int k = 0; k < 40; ++k) a += q[k*64];
      ssjk[b*2560 + idx] = a;
    }
  }
}

// ---------------- k5am: A4/A5/A6/A7 matmuls, grid (16,2) ----------------
__global__ __launch_bounds__(256) void k5am(const float* __restrict__ ssij, const float* __restrict__ ssik,
    const float* __restrict__ ssjk, const float* __restrict__ e2w, const float* __restrict__ e2b,
    float* __restrict__ A4, float* __restrict__ A5, float* __restrict__ A6, float* __restrict__ A7){
  int b = blockIdx.x, half = blockIdx.y, tid = threadIdx.x;
  __shared__ float s1[2560], s2[2560], ss2[64];
  if (half == 0){
    for (int i = tid; i < 2560; i += 256) s1[i] = ssij[b*2560 + i];
    __syncthreads();
    if (tid < 64){
      float a = 0.f;
      for (int k = 0; k < 40; ++k) a += s1[k*64 + tid];
      ss2[tid] = a;
    }
    __syncthreads();
    for (int idx = tid; idx < 1280; idx += 256){
      int k = idx >> 5, o = idx & 31;
      float a4 = 0.f;
      for (int d = 0; d < 64; ++d) a4 += s1[k*64+d] * e2w[4*2048 + d*32 + o];
      A4[(b*40+k)*32 + o] = a4;
    }
    if (tid < 32){
      float a = e2b[tid];
      for (int d = 0; d < 64; ++d) a += ss2[d] * e2w[7*2048 + d*32 + tid];
      A7[b*32 + tid] = a;
    }
  } else {
    for (int i = tid; i < 2560; i += 256){ s1[i] = ssik[b*2560 + i]; s2[i] = ssjk[b*2560 + i]; }
    __syncthreads();
    for (int idx = tid; idx < 1280; idx += 256){
      int k = idx >> 5, o = idx & 31;
      float a5 = 0.f, a6 = 0.f;
      for (int d = 0; d < 64; ++d){
        a5 += s1[k*64+d] * e2w[5*2048 + d*32 + o];
        a6 += s2[k*64+d] * e2w[6*2048 + d*32 + o];
      }
      A5[(b*40+k)*32 + o] = a5;
      A6[(b*40+k)*32 + o] = a6;
    }
  }
}

// ---------------- big addends, f4-vectorized ----------------
__global__ __launch_bounds__(256) void k5b(const float* __restrict__ si2, const float* __restrict__ sj2,
    const float* __restrict__ sk2, const float* __restrict__ e2w,
    const float* __restrict__ A4, const float* __restrict__ A5, const float* __restrict__ A6,
    const float* __restrict__ A7,
    float* __restrict__ A1p, float* __restrict__ A2t, float* __restrict__ Cc){
  int which = blockIdx.y;
  int blk = blockIdx.x, b = blk/40, f = blk%40, tid = threadIdx.x;
  __shared__ __align__(16) f4_t ssrc[640];
  __shared__ __align__(16) f4_t swt[32*17];
  const float* S = (which == 0) ? si2 : (which == 1) ? sj2 : sk2;
  int wop = which + 1;
  const f4_t* Sg4 = (const f4_t*)&S[(size_t)(b*40+f)*2560];
  for (int idx = tid; idx < 640; idx += 256) ssrc[idx] = Sg4[idx];
  for (int idx = tid; idx < 512; idx += 256){
    int o = idx >> 4, d4 = idx & 15;
    f4_t w;
    #pragma unroll
    for (int r = 0; r < 4; ++r) w[r] = e2w[wop*2048 + (4*d4+r)*32 + o];
    swt[o*17 + d4] = w;
  }
  __syncthreads();
  const int o = tid & 31, rb = tid >> 5;
  float acc[5] = {0.f, 0.f, 0.f, 0.f, 0.f};
  #pragma unroll 4
  for (int d4 = 0; d4 < 16; ++d4){
    f4_t w = swt[o*17 + d4];
    #pragma unroll
    for (int it = 0; it < 5; ++it){
      f4_t s = ssrc[(rb + 8*it)*16 + d4];
      acc[it] += s[0]*w[0] + s[1]*w[1] + s[2]*w[2] + s[3]*w[3];
    }
  }
  #pragma unroll
  for (int it = 0; it < 5; ++it){
    int r = rb + 8*it;
    size_t oi = ((size_t)(b*40+f)*40 + r)*32 + o;
    float a = acc[it];
    if (which == 0)      A1p[oi] = a + A4[(b*40+r)*32 + o];
    else if (which == 1) A2t[oi] = a;
    else                 Cc[oi]  = a + A5[(b*40+r)*32 + o] + A6[(b*40+f)*32 + o] + A7[b*32 + o];
  }
}

// ---------------- mode2: layer-2; 512 thr, l-split, 4 sH buffers ----------------
__global__ __launch_bounds__(512, 6) void kh2(
    const u16* __restrict__ e_b, const float* __restrict__ e_f,
    const u16* __restrict__ Vt, const float* __restrict__ Q3c, const u16* __restrict__ W2T0,
    const float* __restrict__ A1p, const float* __restrict__ A2t, const float* __restrict__ Cc,
    float* __restrict__ out_part)
{
  __shared__ __align__(16) char smem[48512];
  u16*   sB1 = (u16*)smem;                    // loop: sH g0 p0
  u16*   sB0 = (u16*)(smem + 9216);           // loop: sH g0 p1
  // smem+18432: sH g1 p0 ; smem+27648: sH g1 p1
  u16*   sU  = (u16*)(smem + 36864);          // dead after setup
  u16*   sW2 = (u16*)(smem + 36864 + 6912);   // dead after setup
  float* sUf = (float*)(smem + 36864);        // 10240B aliases sU+sW2
  float* soacc = (float*)(smem + 48384);      // 128B
  const int tid = threadIdx.x;
  const int b = blockIdx.x / 40, fix = blockIdx.x % 40;   // fix = j
  const int wave = tid >> 6, lane = tid & 63, l15 = lane & 15, quad = lane >> 4;
  const int g = wave >> 2, w4 = wave & 3;
  const int lbeg = g*20;
  const f4_t z4 = (f4_t){0.f,0.f,0.f,0.f};

  for (int idx = tid; idx < 1536; idx += 512){
    int r = idx >> 5, c = idx & 31;
    unsigned v = (r < 40) ? ((const unsigned*)e_b)[(b*40 + r)*32 + c] : 0u;
    ((unsigned*)(sU + r*LSTR))[c] = v;
  }
  float efr[5];
  #pragma unroll
  for (int t = 0; t < 5; ++t) efr[t] = e_f[b*2560 + tid + t*512];
  const unsigned* eg = (const unsigned*)(e_b + (size_t)(b*40 + fix)*64);
  const unsigned* Vb = (const unsigned*)(Vt + (size_t)b*16384);
  for (int idx = tid; idx < 2048; idx += 512){
    int o = idx >> 5, d2 = idx & 31;
    unsigned eu = eg[d2];
    unsigned v0 = Vb[o*32 + d2];
    unsigned vA = Vb[2*2048 + o*32 + d2];
    unsigned vB = Vb[1*2048 + o*32 + d2];
    unsigned v3 = Vb[3*2048 + o*32 + d2];
    float e0 = bflo(eu), e1 = bfhi(eu);
    ((unsigned*)(sB1 + o*LSTR))[d2] = pack2(e0*bflo(v0)+bflo(vA), e1*bfhi(v0)+bfhi(vA));
    ((unsigned*)(sB0 + o*LSTR))[d2] = pack2(e0*bflo(vB)+bflo(v3), e1*bfhi(vB)+bfhi(v3));
  }
  for (int idx = tid; idx < 1024; idx += 512){
    int o = idx >> 5, c = idx & 31;
    ((unsigned*)(sW2 + o*LSTR))[c] = ((const unsigned*)W2T0)[idx];
  }
  if (tid < 32) soacc[tid] = 0.f;
  __syncthreads();

  f4_t b1v[4];
  bf8_t ua[3][2], wfA[2][2];
  f4_t Y0[3];
  {
    bf8_t b0f[2], b1f[2];
    float tmp[8];
    #pragma unroll
    for (int ks = 0; ks < 2; ++ks){
      b1f[ks] = *(const bf8_t*)&sB1[(w4*16 + l15)*LSTR + ks*32 + quad*8];
      b0f[ks] = *(const bf8_t*)&sB0[(w4*16 + l15)*LSTR + ks*32 + quad*8];
      unpack8(b1f[ks], tmp);
      b1v[2*ks]   = (f4_t){tmp[0],tmp[1],tmp[2],tmp[3]};
      b1v[2*ks+1] = (f4_t){tmp[4],tmp[5],tmp[6],tmp[7]};
      #pragma unroll
      for (int m = 0; m < 2; ++m)
        wfA[m][ks] = *(const bf8_t*)&sW2[(m*16 + l15)*LSTR + ks*32 + quad*8];
    }
    #pragma unroll
    for (int n = 0; n < 3; ++n){
      f4_t a = z4;
      #pragma unroll
      for (int ks = 0; ks < 2; ++ks){
        ua[n][ks] = *(const bf8_t*)&sU[(n*16 + l15)*LSTR + ks*32 + quad*8];
        a = __builtin_amdgcn_mfma_f32_16x16x32_bf16(b0f[ks], ua[n][ks], a, 0, 0, 0);
      }
      Y0[n] = a;
    }
  }
  __syncthreads();   // setup reads done (sB1/sB0/sU/sW2 all dead)
  #pragma unroll
  for (int t = 0; t < 5; ++t) sUf[tid + t*512] = efr[t];
  __syncthreads();

  const int obase = w4*16 + quad*4;
  const int o2b   = quad*4;
  const int kme   = w4*16 + l15;
  const int kmc   = kme < 40 ? kme : 39;
  const bool kval = (kme < 40) & (w4 < 3);
  f4_t pa1[2], psum[2];
  psum[0] = z4; psum[1] = z4;
  if (w4 < 3){
    #pragma unroll
    for (int m = 0; m < 2; ++m)
      pa1[m] = *(const f4_t*)&A1p[((size_t)((b*40 + fix)*40 + kmc))*32 + m*16 + o2b];
  }

  // pointer-carried streams (offset to group's l-range)
  const float* qp  = Q3c + (size_t)b*102400 + (size_t)fix*64 + (size_t)lbeg*2560 + obase;   // stride 2560
  const float* a2p = A2t + ((size_t)b*1600 + (size_t)lbeg*40 + kmc)*32 + o2b;               // stride 1280
  const float* ccp = Cc  + ((size_t)b*1600 + (size_t)lbeg*40 + fix)*32 + o2b;               // stride 1280
  const float* ep  = sUf + lbeg*64 + quad*8;

  f4_t cadd_n = *(const f4_t*)qp; qp += 2560;
  #pragma unroll 2
  for (int l = 0; l < 20; ++l){
    f4_t cadd = cadd_n;
    if (l < 19){ cadd_n = *(const f4_t*)qp; qp += 2560; }
    f4_t a2v[2], ccv[2];
    if (w4 < 3){
      a2v[0] = *(const f4_t*)(a2p);      a2v[1] = *(const f4_t*)(a2p + 16);
      ccv[0] = *(const f4_t*)(ccp);      ccv[1] = *(const f4_t*)(ccp + 16);
    }
    a2p += 1280; ccp += 1280;
    f4_t p00 = b1v[0] * *(const f4_t*)(ep);
    f4_t p01 = b1v[1] * *(const f4_t*)(ep + 4);
    f4_t p10 = b1v[2] * *(const f4_t*)(ep + 32);
    f4_t p11 = b1v[3] * *(const f4_t*)(ep + 36);
    ep += 64;
    union { bf8_t v; unsigned u[4]; } m0, m1;
    m0.u[0] = cvtpk(p00[0], p00[1]); m0.u[1] = cvtpk(p00[2], p00[3]);
    m0.u[2] = cvtpk(p01[0], p01[1]); m0.u[3] = cvtpk(p01[2], p01[3]);
    m1.u[0] = cvtpk(p10[0], p10[1]); m1.u[1] = cvtpk(p10[2], p10[3]);
    m1.u[2] = cvtpk(p11[0], p11[1]); m1.u[3] = cvtpk(p11[2], p11[3]);
    u16* Hb = (u16*)(smem + (g*2 + (l & 1))*9216);
    #pragma unroll
    for (int n = 0; n < 3; ++n){
      f4_t a = Y0[n];
      a = __builtin_amdgcn_mfma_f32_16x16x32_bf16(m0.v, ua[n][0], a, 0, 0, 0);
      a = __builtin_amdgcn_mfma_f32_16x16x32_bf16(m1.v, ua[n][1], a, 0, 0, 0);
      f4_t h = __builtin_elementwise_max(a + cadd, z4);   // k>=40 rows masked at psum
      uint2 pw;
      pw.x = cvtpk(h[0], h[1]);
      pw.y = cvtpk(h[2], h[3]);
      *(uint2*)&Hb[(n*16 + l15)*LSTR + obase] = pw;
    }
    __syncthreads();
    if (w4 < 3){
      bf8_t hB[2];
      #pragma unroll
      for (int ks = 0; ks < 2; ++ks)
        hB[ks] = *(const bf8_t*)&Hb[(w4*16 + l15)*LSTR + ks*32 + quad*8];
      #pragma unroll
      for (int m = 0; m < 2; ++m){
        f4_t y = z4;
        y = __builtin_amdgcn_mfma_f32_16x16x32_bf16(wfA[m][0], hB[0], y, 0, 0, 0);
        y = __builtin_amdgcn_mfma_f32_16x16x32_bf16(wfA[m][1], hB[1], y, 0, 0, 0);
        if (kval){
          f4_t v = y + pa1[m] + a2v[m] + ccv[m];
          psum[m] += __builtin_elementwise_max(v, z4);
        }
      }
    }
  }

  if (w4 < 3){
    #pragma unroll
    for (int m = 0; m < 2; ++m){
      f4_t v = psum[m];
      v += shfl4x(v, 1); v += shfl4x(v, 2); v += shfl4x(v, 4); v += shfl4x(v, 8);
      if (l15 == 0){
        #pragma unroll
        for (int r = 0; r < 4; ++r) atomicAdd(&soacc[m*16 + o2b + r], v[r]);
      }
    }
  }
  __syncthreads();
  if (tid < 32) out_part[(b*40 + fix)*32 + tid] = soacc[tid];
}

// ---------------- final: sum_j out_part, relu, dot out_w (parallel) ----------------
__global__ __launch_bounds__(512) void k7(const float* __restrict__ out_part, const float* __restrict__ ow,
                                          const float* __restrict__ ob, float* __restrict__ out){
  int tid = threadIdx.x;
  int b = tid >> 5, o = tid & 31;
  float s = 0.f;
  for (int j = 0; j < 40; ++j) s += out_part[(b*40 + j)*32 + o];
  s = s > 0.f ? s : 0.f;
  float v = s * ow[o];
  v += __shfl_xor(v, 1); v += __shfl_xor(v, 2); v += __shfl_xor(v, 4);
  v += __shfl_xor(v, 8); v += __shfl_xor(v, 16);
  if (o == 0) out[b] = v + ob[0];
}

extern "C" void kernel_launch(void* const* d_in, const int* in_sizes, int n_in,
                              void* d_out, int out_size, void* d_ws, size_t ws_size,
                              hipStream_t stream){
  const float* x    = (const float*)d_in[0];
  const float* c1w  = (const float*)d_in[1];
  const float* c1b  = (const float*)d_in[2];
  const float* c2w  = (const float*)d_in[3];
  const float* c2b  = (const float*)d_in[4];
  const float* fcw  = (const float*)d_in[5];
  const float* fcb  = (const float*)d_in[6];
  const float* e1w  = (const float*)d_in[7];
  const float* e1b  = (const float*)d_in[8];
  const float* e2w  = (const float*)d_in[9];
  const float* e2b  = (const float*)d_in[10];
  const float* ow   = (const float*)d_in[11];
  const float* ob   = (const float*)d_in[12];

  char* ws = (char*)d_ws;
  size_t off = 0;
  auto alloc = [&](size_t bytes) -> void* {
    void* p = ws + off;
    off += (bytes + 255) & ~(size_t)255;
    return p;
  };
  u16*   z1t  = (u16*)  alloc((size_t)640*4608*2);
  u16*   wt2  = (u16*)  alloc(51200*2);
  u16*   fcwT = (u16*)  alloc(65536*2);
  u16*   z2g  = (u16*)  alloc((size_t)640*1024*2);
  float* e_f  = (float*)alloc(40960*4);
  u16*   e_b  = (u16*)  alloc(40960*2);
  float* Sg   = (float*)alloc(1024*4);
  u16*   Vt   = (u16*)  alloc((size_t)16*16384*2);
  float* c0   = (float*)alloc(1024*4);
  float* P5   = (float*)alloc(40960*4);
  float* P6   = (float*)alloc(40960*4);
  u16*   W2T0 = (u16*)  alloc(2048*2);
  u16*   W3St = (u16*)  alloc((size_t)16*4096*2);
  float* Q3c  = (float*)alloc((size_t)1638400*4);
  float* si2  = (float*)alloc((size_t)1638400*4);
  float* sj2  = (float*)alloc((size_t)1638400*4);
  float* sk2  = (float*)alloc((size_t)1638400*4);
  float* ssij = (float*)alloc(40960*4);
  float* ssik = (float*)alloc(40960*4);
  float* ssjk = (float*)alloc(40960*4);
  float* A4   = (float*)alloc(20480*4);
  float* A5   = (float*)alloc(20480*4);
  float* A6   = (float*)alloc(20480*4);
  float* A7   = (float*)alloc(512*4);
  float* A1p  = (float*)alloc((size_t)819200*4);
  float* A2t  = (float*)alloc((size_t)819200*4);
  float* Cc   = (float*)alloc((size_t)819200*4);
  float* op   = (float*)alloc(20480*4);
  (void)in_sizes; (void)n_in; (void)out_size; (void)ws_size;

  kconv1 <<<672, 256, 0, stream>>>(x, c1w, c1b, z1t, c2w, fcw, wt2, fcwT);
  kconv2m<<<640, 256, 0, stream>>>(z1t, wt2, c2b, z2g);
  kfc    <<<40,  256, 0, stream>>>(z2g, fcwT, fcb, e_f, e_b);
  kprep  <<<dim3(16,4), 256, 0, stream>>>(e_f, e1w, e1b, e2w, Sg, Vt, c0, P5, P6, W2T0, W3St);
  kpq    <<<640, 256, 0, stream>>>(e_b, W3St, P5, P6, c0, Q3c);
  kh01   <<<dim3(640,2), 512, 0, stream>>>(e_b, e_f, Vt, Q3c, si2, sj2, sk2);
  k5ar   <<<dim3(16,3,2), 256, 0, stream>>>(si2, sj2, ssij, ssik, ssjk);
  k5am   <<<dim3(16,2), 256, 0, stream>>>(ssij, ssik, ssjk, e2w, e2b, A4, A5, A6, A7);
  k5b    <<<dim3(640,3), 256, 0, stream>>>(si2, sj2, sk2, e2w, A4, A5, A6, A7, A1p, A2t, Cc);
  kh2    <<<640, 512, 0, stream>>>(e_b, e_f, Vt, Q3c, W2T0, A1p, A2t, Cc, op);
  k7     <<<1, 512, 0, stream>>>(op, ow, ob, (float*)d_out);
}

// Round 12
// 638.599 us; speedup vs baseline: 1.3867x; 1.3867x over previous
//
#include <hip/hip_runtime.h>
#include <hip/hip_bf16.h>

// UniqueEq3Net: conv stack -> e(640,64); t = e⊗e⊗e never materialized.
// Layer1 (transposed MFMA): h^T[o][k] = (B1⊙e_l)^T · U + Y0 + cadd.
// R12 = R10 verbatim + safe occupancy: kh01 (256,6) [LDS allows 6 blk/CU,
// VGPR cap 84 > 60 used], kh2 (256,5) [5 blk/CU, cap 102 > 72 used].
// R11 lesson: never cap VGPRs below the working set (512,8 -> 64-cap -> 1.3GB spill).

typedef unsigned short u16;
typedef __attribute__((ext_vector_type(8))) short bf8_t;   // 8 bf16 (4 VGPRs)
typedef __attribute__((ext_vector_type(4))) float f4_t;

#define LSTR 72   // padded LDS row stride (u16): 144B rows, 16B-aligned

__device__ inline u16 f2bf(float f){
  union { float f; unsigned u; } v; v.f = f;
  unsigned r = v.u + 0x7fffu + ((v.u >> 16) & 1u);
  return (u16)(r >> 16);
}
__device__ inline float bflo(unsigned u){ union { unsigned x; float f; } v; v.x = u << 16; return v.f; }
__device__ inline float bfhi(unsigned u){ union { unsigned x; float f; } v; v.x = u & 0xffff0000u; return v.f; }
__device__ inline unsigned pack2(float a, float b){ return (unsigned)f2bf(a) | ((unsigned)f2bf(b) << 16); }
__device__ inline unsigned cvtpk(float lo, float hi){
  __hip_bfloat162 h2 = __float22bfloat162_rn(make_float2(lo, hi));
  union { __hip_bfloat162 h; unsigned u; } c; c.h = h2; return c.u;
}
__device__ inline void unpack8(bf8_t x, float* o){
  union { bf8_t v; unsigned u[4]; } q; q.v = x;
  #pragma unroll
  for (int p = 0; p < 4; ++p){ o[2*p] = bflo(q.u[p]); o[2*p+1] = bfhi(q.u[p]); }
}
__device__ inline f4_t shfl4x(f4_t v, int m){
  f4_t r;
  r[0] = __shfl_xor(v[0], m); r[1] = __shfl_xor(v[1], m);
  r[2] = __shfl_xor(v[2], m); r[3] = __shfl_xor(v[3], m);
  return r;
}

// ---------------- conv1 + pool -> z1t ; blocks >=640 do weight prep ----------------
__global__ __launch_bounds__(256) void kconv1(const float* __restrict__ x, const float* __restrict__ w1,
                                              const float* __restrict__ b1, u16* __restrict__ z1t,
                                              const float* __restrict__ w2, const float* __restrict__ fcw,
                                              u16* __restrict__ wt2, u16* __restrict__ fcwT){
  __shared__ float simg[784];
  int img = blockIdx.x, tid = threadIdx.x;
  if (img >= 640){
    int t = (img - 640)*256 + tid, stride = 32*256;
    for (int i = t; i < 51200; i += stride){
      int tap = i >> 11, rc = i & 2047, co = rc >> 5, ci = rc & 31;
      wt2[i] = f2bf(w2[co*800 + ci*25 + tap]);
    }
    for (int i = t; i < 65536; i += stride){
      int o = i >> 10, k = i & 1023;
      fcwT[i] = f2bf(fcw[k*64 + o]);
    }
    return;
  }
  for (int i = tid; i < 784; i += 256) simg[i] = x[img*784 + i];
  const int c = tid & 31;
  float wc[25];
  #pragma unroll
  for (int t = 0; t < 25; ++t) wc[t] = w1[c*25 + t];
  const float bb = b1[c];
  __syncthreads();
  #pragma unroll 2
  for (int it = 0; it < 18; ++it){
    int p = (tid >> 5) + it*8;
    int py = p / 12, px = p % 12;
    float patch[36];
    const float* sp = &simg[2*py*28 + 2*px];
    #pragma unroll
    for (int yy = 0; yy < 6; ++yy)
      #pragma unroll
      for (int xx = 0; xx < 6; ++xx) patch[yy*6+xx] = sp[yy*28+xx];
    float mx = -1e30f;
    #pragma unroll
    for (int sy = 0; sy < 2; ++sy)
    #pragma unroll
    for (int sx = 0; sx < 2; ++sx){
      float s = bb;
      #pragma unroll
      for (int dy = 0; dy < 5; ++dy)
        #pragma unroll
        for (int dx = 0; dx < 5; ++dx)
          s += patch[(sy+dy)*6 + sx+dx] * wc[dy*5+dx];
      mx = fmaxf(mx, s);
    }
    z1t[(size_t)img*4608 + p*32 + c] = f2bf(fmaxf(mx, 0.f));
  }
}

// ---------------- conv2 (MFMA, 25 shifted K=32 GEMMs) + pool -> z2g (640,1024) bf16 ----------------
__global__ __launch_bounds__(256) void kconv2m(const u16* __restrict__ z1t, const u16* __restrict__ wt2,
                                               const float* __restrict__ b2, u16* __restrict__ z2g){
  __shared__ __align__(16) u16 sz[4608];
  __shared__ __align__(16) u16 sz2[1024];
  int img = blockIdx.x, tid = threadIdx.x;
  for (int i = tid; i < 576; i += 256)
    ((uint4*)sz)[i] = ((const uint4*)(z1t + (size_t)img*4608))[i];
  __syncthreads();
  const int wave = tid >> 6, lane = tid & 63, l15 = lane & 15, quad = lane >> 4;
  const int y = wave*2 + (l15 >> 3), x = l15 & 7;
  f4_t acc[4];
  acc[0] = (f4_t){0.f,0.f,0.f,0.f}; acc[1] = acc[0]; acc[2] = acc[0]; acc[3] = acc[0];
  #pragma unroll
  for (int dy = 0; dy < 5; ++dy)
    #pragma unroll
    for (int dx = 0; dx < 5; ++dx){
      const int tap = dy*5 + dx;
      bf8_t af = *(const bf8_t*)&sz[((y+dy)*12 + (x+dx))*32 + quad*8];
      const u16* wp = wt2 + tap*2048 + l15*32 + quad*8;
      #pragma unroll
      for (int nt = 0; nt < 4; ++nt){
        bf8_t bf = *(const bf8_t*)(wp + nt*512);
        acc[nt] = __builtin_amdgcn_mfma_f32_16x16x32_bf16(af, bf, acc[nt], 0, 0, 0);
      }
    }
  #pragma unroll
  for (int nt = 0; nt < 4; ++nt){
    int co = nt*16 + l15;
    float v0 = fmaxf(acc[nt][0], acc[nt][1]);
    float v1 = fmaxf(acc[nt][2], acc[nt][3]);
    v0 = fmaxf(v0, __shfl_xor(v0, 32));
    v1 = fmaxf(v1, __shfl_xor(v1, 32));
    if (quad < 2){
      float bb = b2[co];
      sz2[co*16 + wave*4 + quad*2 + 0] = f2bf(fmaxf(v0 + bb, 0.f));
      sz2[co*16 + wave*4 + quad*2 + 1] = f2bf(fmaxf(v1 + bb, 0.f));
    }
  }
  __syncthreads();
  if (tid < 128) ((uint4*)(z2g + (size_t)img*1024))[tid] = ((const uint4*)sz2)[tid];
}

// ---------------- fc: e = relu(z2g @ fcw + fcb) ----------------
__global__ __launch_bounds__(256) void kfc(const u16* __restrict__ z2g, const u16* __restrict__ fcwT,
                                           const float* __restrict__ fcb,
                                           float* __restrict__ e_f, u16* __restrict__ e_b){
  __shared__ __align__(16) u16 sA[16*1032];
  int img0 = blockIdx.x*16, tid = threadIdx.x;
  for (int i = tid; i < 2048; i += 256){
    int row = i >> 7, c16 = i & 127;
    ((uint4*)(sA + row*1032))[c16] = ((const uint4*)(z2g + (size_t)(img0+row)*1024))[c16];
  }
  __syncthreads();
  const int wave = tid >> 6, lane = tid & 63, l15 = lane & 15, quad = lane >> 4;
  const int o = wave*16 + l15;
  f4_t acc = (f4_t){0.f,0.f,0.f,0.f};
  #pragma unroll 8
  for (int ks = 0; ks < 32; ++ks){
    bf8_t af = *(const bf8_t*)&sA[l15*1032 + ks*32 + quad*8];
    bf8_t bf = *(const bf8_t*)(fcwT + (size_t)o*1024 + ks*32 + quad*8);
    acc = __builtin_amdgcn_mfma_f32_16x16x32_bf16(af, bf, acc, 0, 0, 0);
  }
  const float bb = fcb[o];
  #pragma unroll
  for (int r = 0; r < 4; ++r){
    int img = img0 + quad*4 + r;
    float v = fmaxf(acc[r] + bb, 0.f);
    e_f[img*64 + o] = v;
    e_b[img*64 + o] = f2bf(v);
  }
}

// ---------------- per-b precompute, grid (16,4) ----------------
__global__ __launch_bounds__(256) void kprep(const float* __restrict__ e_f, const float* __restrict__ e1w,
    const float* __restrict__ e1b, const float* __restrict__ e2w,
    float* __restrict__ Sg, u16* __restrict__ Vt, float* __restrict__ c0,
    float* __restrict__ P5, float* __restrict__ P6, u16* __restrict__ W2T0,
    u16* __restrict__ W3St){
  int b = blockIdx.x, ph = blockIdx.y, tid = threadIdx.x;
  __shared__ float se[2560];
  __shared__ float S[64], S2[64], S3[64];
  for (int i = tid; i < 2560; i += 256) se[i] = e_f[b*2560 + i];
  __syncthreads();
  if (tid < 64){
    float s = 0.f;
    for (int i = 0; i < 40; ++i) s += se[i*64 + tid];
    S[tid] = s; S2[tid] = s*s; S3[tid] = s*s*s;
    if (ph == 0) Sg[b*64 + tid] = s;
  }
  __syncthreads();
  {
    const int m = ph;
    for (int idx = tid; idx < 4096; idx += 256){
      int o = idx >> 6, d = idx & 63;
      float v;
      if (m == 0)      v = e1w[d*64 + o];
      else if (m == 1) v = S[d] * e1w[4096  + d*64 + o];
      else if (m == 2) v = S[d] * e1w[8192  + d*64 + o];
      else             v = S2[d] * e1w[16384 + d*64 + o];
      Vt[(size_t)b*16384 + m*4096 + idx] = f2bf(v);
    }
  }
  if (ph == 0){
    if (tid < 64){
      float a = e1b[tid];
      for (int d = 0; d < 64; ++d) a += S3[d] * e1w[7*4096 + d*64 + tid];
      c0[b*64 + tid] = a;
    }
  } else if (ph == 1){
    for (int idx = tid; idx < 4096; idx += 256){
      int o = idx >> 6, d = idx & 63;
      W3St[(size_t)b*4096 + idx] = f2bf(S[d] * e1w[3*4096 + d*64 + o]);
    }
  } else {
    int lo = (ph == 2) ? 0 : 1280, hi = lo + 1280;
    for (int idx = lo + tid; idx < hi; idx += 256){
      int j = idx >> 6, o = idx & 63;
      float a5 = 0.f, a6 = 0.f;
      for (int d = 0; d < 64; ++d){
        float es = se[j*64 + d] * S2[d];
        a5 += es * e1w[5*4096 + d*64 + o];
        a6 += es * e1w[6*4096 + d*64 + o];
      }
      P5[(b*40+j)*64 + o] = a5;
      P6[(b*40+j)*64 + o] = a6;
    }
    if (ph == 3 && b == 0){
      for (int idx = tid; idx < 2048; idx += 256){
        int o = idx >> 6, d = idx & 63;
        W2T0[o*64 + d] = f2bf(e2w[d*32 + o]);
      }
    }
  }
}

// ---------------- kpq: P[i] tile in LDS AND Q3c[b,i,:,:] via MFMA ----------------
__global__ __launch_bounds__(256) void kpq(const u16* __restrict__ e_b, const u16* __restrict__ W3St,
    const float* __restrict__ P5, const float* __restrict__ P6, const float* __restrict__ c0,
    float* __restrict__ Q3c){
  __shared__ __align__(16) u16 sP[48*LSTR];
  __shared__ __align__(16) u16 sW[64*LSTR];
  int blk = blockIdx.x, b = blk/40, i = blk%40, tid = threadIdx.x;
  const int wave = tid >> 6, lane = tid & 63, l15 = lane & 15, quad = lane >> 4;
  for (int idx = tid; idx < 2048; idx += 256){
    int o = idx >> 5, c = idx & 31;
    ((unsigned*)(sW + o*LSTR))[c] = ((const unsigned*)(W3St + (size_t)b*4096))[idx];
  }
  const unsigned* eb32 = (const unsigned*)(e_b + (size_t)b*2560);
  const unsigned* el = eb32 + i*32;
  #pragma unroll
  for (int it = 0; it < 6; ++it){
    int idx = tid + it*256;
    int k = idx >> 5, d2 = idx & 31;
    unsigned pv = 0;
    if (k < 40){
      unsigned ul = el[d2], uk = eb32[k*32 + d2];
      pv = pack2(bflo(ul)*bflo(uk), bfhi(ul)*bfhi(uk));
    }
    ((unsigned*)(sP + k*LSTR))[d2] = pv;
  }
  __syncthreads();
  bf8_t wf[2];
  #pragma unroll
  for (int ks = 0; ks < 2; ++ks)
    wf[ks] = *(const bf8_t*)&sW[(wave*16 + l15)*LSTR + ks*32 + quad*8];
  f4_t acc[3];
  #pragma unroll
  for (int n = 0; n < 3; ++n){
    f4_t a = (f4_t){0.f,0.f,0.f,0.f};
    #pragma unroll
    for (int ks = 0; ks < 2; ++ks){
      bf8_t pkf = *(const bf8_t*)&sP[(n*16 + l15)*LSTR + ks*32 + quad*8];
      a = __builtin_amdgcn_mfma_f32_16x16x32_bf16(wf[ks], pkf, a, 0, 0, 0);
    }
    acc[n] = a;
  }
  const int obase = wave*16 + quad*4;
  f4_t p6v = *(const f4_t*)&P6[(b*40+i)*64 + obase];
  f4_t c0v = *(const f4_t*)&c0[b*64 + obase];
  #pragma unroll
  for (int n = 0; n < 3; ++n){
    int j = n*16 + l15;
    if (j < 40){
      f4_t p5v = *(const f4_t*)&P5[(b*40+j)*64 + obase];
      f4_t outv = acc[n] + p5v + p6v + c0v;
      *(f4_t*)&Q3c[((size_t)((b*40+i)*40 + j))*64 + obase] = outv;
    }
  }
}

// ---------------- layer-1 reduction passes (modes 0 & 1); pointer-carried streams ----------------
__global__ __launch_bounds__(256, 6) void kh01(
    const u16* __restrict__ e_b, const float* __restrict__ e_f,
    const u16* __restrict__ Vt, const float* __restrict__ Q3c,
    float* __restrict__ si2, float* __restrict__ sj2, float* __restrict__ sk2)
{
  __shared__ __align__(16) char smem[25344];
  u16*   sU  = (u16*)smem;             // dead after setup
  u16*   sB1 = (u16*)(smem + 6912);    // dead after setup
  u16*   sB0 = (u16*)(smem + 16128);
  float* sUf = (float*)smem;           // aliases sU+sB1
  const int tid = threadIdx.x;
  const int b = blockIdx.x / 40, fix = blockIdx.x % 40;
  const int mode = blockIdx.y;
  const int wave = tid >> 6, lane = tid & 63, l15 = lane & 15, quad = lane >> 4;
  const f4_t z4 = (f4_t){0.f,0.f,0.f,0.f};

  for (int idx = tid; idx < 1536; idx += 256){
    int r = idx >> 5, c = idx & 31;
    unsigned v = (r < 40) ? ((const unsigned*)e_b)[(b*40 + r)*32 + c] : 0u;
    ((unsigned*)(sU + r*LSTR))[c] = v;
  }
  float efr[10];
  #pragma unroll
  for (int t = 0; t < 10; ++t) efr[t] = e_f[b*2560 + tid + t*256];
  const unsigned* eg = (const unsigned*)(e_b + (size_t)(b*40 + fix)*64);
  const unsigned* Vb = (const unsigned*)(Vt + (size_t)b*16384);
  for (int idx = tid; idx < 2048; idx += 256){
    int o = idx >> 5, d2 = idx & 31;
    unsigned eu = eg[d2];
    unsigned v0 = Vb[o*32 + d2];
    unsigned vA = Vb[(2-mode)*2048 + o*32 + d2];
    unsigned vB = Vb[(1+mode)*2048 + o*32 + d2];
    unsigned v3 = Vb[3*2048 + o*32 + d2];
    float e0 = bflo(eu), e1 = bfhi(eu);
    ((unsigned*)(sB1 + o*LSTR))[d2] = pack2(e0*bflo(v0)+bflo(vA), e1*bfhi(v0)+bfhi(vA));
    ((unsigned*)(sB0 + o*LSTR))[d2] = pack2(e0*bflo(vB)+bflo(v3), e1*bfhi(vB)+bfhi(v3));
  }
  __syncthreads();

  f4_t b1v[4];
  bf8_t ua[3][2];
  f4_t Y0[3];
  {
    bf8_t b0f[2], b1f[2];
    float tmp[8];
    #pragma unroll
    for (int ks = 0; ks < 2; ++ks){
      b1f[ks] = *(const bf8_t*)&sB1[(wave*16 + l15)*LSTR + ks*32 + quad*8];
      b0f[ks] = *(const bf8_t*)&sB0[(wave*16 + l15)*LSTR + ks*32 + quad*8];
      unpack8(b1f[ks], tmp);
      b1v[2*ks]   = (f4_t){tmp[0],tmp[1],tmp[2],tmp[3]};
      b1v[2*ks+1] = (f4_t){tmp[4],tmp[5],tmp[6],tmp[7]};
    }
    #pragma unroll
    for (int n = 0; n < 3; ++n){
      f4_t a = z4;
      #pragma unroll
      for (int ks = 0; ks < 2; ++ks){
        ua[n][ks] = *(const bf8_t*)&sU[(n*16 + l15)*LSTR + ks*32 + quad*8];
        a = __builtin_amdgcn_mfma_f32_16x16x32_bf16(b0f[ks], ua[n][ks], a, 0, 0, 0);
      }
      Y0[n] = a;
    }
  }
  __syncthreads();
  #pragma unroll
  for (int t = 0; t < 10; ++t) sUf[tid + t*256] = efr[t];
  __syncthreads();

  const int obase = wave*16 + quad*4;
  const float km = (l15 < 8) ? 1.f : 0.f;
  const f4_t km4 = (f4_t){km, km, km, km};
  f4_t sacc[3];
  sacc[0] = z4; sacc[1] = z4; sacc[2] = z4;

  // pointer-carried streams (no per-iter 64-bit address mul)
  const int qstride = mode ? 64 : 2560;
  const float* qp = Q3c + (size_t)b*102400 + (mode ? (size_t)fix*2560 : (size_t)fix*64) + obase;
  float* skp = sk2 + ((size_t)(b*40)*40 + fix)*64 + obase;   // mode0 only; stride 2560
  const float* ep = sUf + quad*8;

  f4_t cadd_n = *(const f4_t*)qp; qp += qstride;
  #pragma unroll 2
  for (int l = 0; l < 40; ++l){
    f4_t cadd = cadd_n;
    if (l < 39){ cadd_n = *(const f4_t*)qp; qp += qstride; }
    f4_t p00 = b1v[0] * *(const f4_t*)(ep);
    f4_t p01 = b1v[1] * *(const f4_t*)(ep + 4);
    f4_t p10 = b1v[2] * *(const f4_t*)(ep + 32);
    f4_t p11 = b1v[3] * *(const f4_t*)(ep + 36);
    ep += 64;
    union { bf8_t v; unsigned u[4]; } m0, m1;
    m0.u[0] = cvtpk(p00[0], p00[1]); m0.u[1] = cvtpk(p00[2], p00[3]);
    m0.u[2] = cvtpk(p01[0], p01[1]); m0.u[3] = cvtpk(p01[2], p01[3]);
    m1.u[0] = cvtpk(p10[0], p10[1]); m1.u[1] = cvtpk(p10[2], p10[3]);
    m1.u[2] = cvtpk(p11[0], p11[1]); m1.u[3] = cvtpk(p11[2], p11[3]);
    f4_t khs = z4;
    #pragma unroll
    for (int n = 0; n < 3; ++n){
      f4_t a = Y0[n];
      a = __builtin_amdgcn_mfma_f32_16x16x32_bf16(m0.v, ua[n][0], a, 0, 0, 0);
      a = __builtin_amdgcn_mfma_f32_16x16x32_bf16(m1.v, ua[n][1], a, 0, 0, 0);
      f4_t h = __builtin_elementwise_max(a + cadd, z4);
      sacc[n] += h;                         // k>=40 garbage: write-guarded later
      if (mode == 0) khs += (n == 2) ? h * km4 : h;
    }
    if (mode == 0){
      khs += shfl4x(khs, 1);
      khs += shfl4x(khs, 2);
      khs += shfl4x(khs, 4);
      khs += shfl4x(khs, 8);
      if (l15 == 0) *(f4_t*)skp = khs;
      skp += 2560;
    }
  }
  float* dst = mode ? sj2 : si2;
  #pragma unroll
  for (int n = 0; n < 3; ++n){
    int k = n*16 + l15;
    if (k < 40)
      *(f4_t*)&dst[((size_t)((b*40 + fix)*40 + k))*64 + obase] = sacc[n];
  }
}

// ---------------- k5ar: the three 40-deep sums, grid (16,3,2) ----------------
__global__ __launch_bounds__(256) void k5ar(const float* __restrict__ si2, const float* __restrict__ sj2,
    float* __restrict__ ssij, float* __restrict__ ssik, float* __restrict__ ssjk){
  int b = blockIdx.x, which = blockIdx.y, half = blockIdx.z, tid = threadIdx.x;
  int base = half*1280;
  for (int idx = base + tid; idx < base + 1280; idx += 256){
    int r = idx >> 6, d = idx & 63;
    float a = 0.f;
    if (which == 0){
      for (int j = 0; j < 40; ++j) a += si2[((size_t)(b*40+j)*40 + r)*64 + d];
      ssij[b*2560 + idx] = a;
    } else if (which == 1){
      const float* p = &si2[(size_t)(b*40+r)*2560 + d];
      for (int k = 0; k < 40; ++k) a += p[k*64];
      ssik[b*2560 + idx] = a;
    } else {
      const float* q = &sj2[(size_t)(b*40+r)*2560 + d];
      for (int k = 0; k < 40; ++k) a += q[k*64];
      ssjk[b*2560 + idx] = a;
    }
  }
}

// ---------------- k5am: A4/A5/A6/A7 matmuls, grid (16,2) ----------------
__global__ __launch_bounds__(256) void k5am(const float* __restrict__ ssij, const float* __restrict__ ssik,
    const float* __restrict__ ssjk, const float* __restrict__ e2w, const float* __restrict__ e2b,
    float* __restrict__ A4, float* __restrict__ A5, float* __restrict__ A6, float* __restrict__ A7){
  int b = blockIdx.x, half = blockIdx.y, tid = threadIdx.x;
  __shared__ float s1[2560], s2[2560], ss2[64];
  if (half == 0){
    for (int i = tid; i < 2560; i += 256) s1[i] = ssij[b*2560 + i];
    __syncthreads();
    if (tid < 64){
      float a = 0.f;
      for (int k = 0; k < 40; ++k) a += s1[k*64 + tid];
      ss2[tid] = a;
    }
    __syncthreads();
    for (int idx = tid; idx < 1280; idx += 256){
      int k = idx >> 5, o = idx & 31;
      float a4 = 0.f;
      for (int d = 0; d < 64; ++d) a4 += s1[k*64+d] * e2w[4*2048 + d*32 + o];
      A4[(b*40+k)*32 + o] = a4;
    }
    if (tid < 32){
      float a = e2b[tid];
      for (int d = 0; d < 64; ++d) a += ss2[d] * e2w[7*2048 + d*32 + tid];
      A7[b*32 + tid] = a;
    }
  } else {
    for (int i = tid; i < 2560; i += 256){ s1[i] = ssik[b*2560 + i]; s2[i] = ssjk[b*2560 + i]; }
    __syncthreads();
    for (int idx = tid; idx < 1280; idx += 256){
      int k = idx >> 5, o = idx & 31;
      float a5 = 0.f, a6 = 0.f;
      for (int d = 0; d < 64; ++d){
        a5 += s1[k*64+d] * e2w[5*2048 + d*32 + o];
        a6 += s2[k*64+d] * e2w[6*2048 + d*32 + o];
      }
      A5[(b*40+k)*32 + o] = a5;
      A6[(b*40+k)*32 + o] = a6;
    }
  }
}

// ---------------- big addends, f4-vectorized ----------------
__global__ __launch_bounds__(256) void k5b(const float* __restrict__ si2, const float* __restrict__ sj2,
    const float* __restrict__ sk2, const float* __restrict__ e2w,
    const float* __restrict__ A4, const float* __restrict__ A5, const float* __restrict__ A6,
    const float* __restrict__ A7,
    float* __restrict__ A1p, float* __restrict__ A2t, float* __restrict__ Cc){
  int which = blockIdx.y;
  int blk = blockIdx.x, b = blk/40, f = blk%40, tid = threadIdx.x;
  __shared__ __align__(16) f4_t ssrc[640];
  __shared__ __align__(16) f4_t swt[32*17];
  const float* S = (which == 0) ? si2 : (which == 1) ? sj2 : sk2;
  int wop = which + 1;
  const f4_t* Sg4 = (const f4_t*)&S[(size_t)(b*40+f)*2560];
  for (int idx = tid; idx < 640; idx += 256) ssrc[idx] = Sg4[idx];
  for (int idx = tid; idx < 512; idx += 256){
    int o = idx >> 4, d4 = idx & 15;
    f4_t w;
    #pragma unroll
    for (int r = 0; r < 4; ++r) w[r] = e2w[wop*2048 + (4*d4+r)*32 + o];
    swt[o*17 + d4] = w;
  }
  __syncthreads();
  const int o = tid & 31, rb = tid >> 5;
  float acc[5] = {0.f, 0.f, 0.f, 0.f, 0.f};
  #pragma unroll 4
  for (int d4 = 0; d4 < 16; ++d4){
    f4_t w = swt[o*17 + d4];
    #pragma unroll
    for (int it = 0; it < 5; ++it){
      f4_t s = ssrc[(rb + 8*it)*16 + d4];
      acc[it] += s[0]*w[0] + s[1]*w[1] + s[2]*w[2] + s[3]*w[3];
    }
  }
  #pragma unroll
  for (int it = 0; it < 5; ++it){
    int r = rb + 8*it;
    size_t oi = ((size_t)(b*40+f)*40 + r)*32 + o;
    float a = acc[it];
    if (which == 0)      A1p[oi] = a + A4[(b*40+r)*32 + o];
    else if (which == 1) A2t[oi] = a;
    else                 Cc[oi]  = a + A5[(b*40+r)*32 + o] + A6[(b*40+f)*32 + o] + A7[b*32 + o];
  }
}

// ---------------- mode2: layer-2; pointer-carried streams; sH dbuf over sB1/sB0 ----------------
__global__ __launch_bounds__(256, 5) void kh2(
    const u16* __restrict__ e_b, const float* __restrict__ e_f,
    const u16* __restrict__ Vt, const float* __restrict__ Q3c, const u16* __restrict__ W2T0,
    const float* __restrict__ A1p, const float* __restrict__ A2t, const float* __restrict__ Cc,
    float* __restrict__ out_part)
{
  __shared__ __align__(16) char smem[30080];
  u16*   sB1 = (u16*)smem;                  // loop: sH buf0
  u16*   sB0 = (u16*)(smem + 9216);         // loop: sH buf1
  u16*   sU  = (u16*)(smem + 18432);        // dead after setup
  u16*   sW2 = (u16*)(smem + 18432 + 6912); // dead after setup
  float* sUf = (float*)(smem + 18432);      // aliases sU+sW2
  float* soacc = (float*)(smem + 29952);
  const int tid = threadIdx.x;
  const int b = blockIdx.x / 40, fix = blockIdx.x % 40;   // fix = j
  const int wave = tid >> 6, lane = tid & 63, l15 = lane & 15, quad = lane >> 4;
  const f4_t z4 = (f4_t){0.f,0.f,0.f,0.f};

  for (int idx = tid; idx < 1536; idx += 256){
    int r = idx >> 5, c = idx & 31;
    unsigned v = (r < 40) ? ((const unsigned*)e_b)[(b*40 + r)*32 + c] : 0u;
    ((unsigned*)(sU + r*LSTR))[c] = v;
  }
  float efr[10];
  #pragma unroll
  for (int t = 0; t < 10; ++t) efr[t] = e_f[b*2560 + tid + t*256];
  const unsigned* eg = (const unsigned*)(e_b + (size_t)(b*40 + fix)*64);
  const unsigned* Vb = (const unsigned*)(Vt + (size_t)b*16384);
  for (int idx = tid; idx < 2048; idx += 256){
    int o = idx >> 5, d2 = idx & 31;
    unsigned eu = eg[d2];
    unsigned v0 = Vb[o*32 + d2];
    unsigned vA = Vb[2*2048 + o*32 + d2];
    unsigned vB = Vb[1*2048 + o*32 + d2];
    unsigned v3 = Vb[3*2048 + o*32 + d2];
    float e0 = bflo(eu), e1 = bfhi(eu);
    ((unsigned*)(sB1 + o*LSTR))[d2] = pack2(e0*bflo(v0)+bflo(vA), e1*bfhi(v0)+bfhi(vA));
    ((unsigned*)(sB0 + o*LSTR))[d2] = pack2(e0*bflo(vB)+bflo(v3), e1*bfhi(vB)+bfhi(v3));
  }
  for (int idx = tid; idx < 1024; idx += 256){
    int o = idx >> 5, c = idx & 31;
    ((unsigned*)(sW2 + o*LSTR))[c] = ((const unsigned*)W2T0)[idx];
  }
  if (tid < 32) soacc[tid] = 0.f;
  __syncthreads();

  f4_t b1v[4];
  bf8_t ua[3][2], wfA[2][2];
  f4_t Y0[3];
  {
    bf8_t b0f[2], b1f[2];
    float tmp[8];
    #pragma unroll
    for (int ks = 0; ks < 2; ++ks){
      b1f[ks] = *(const bf8_t*)&sB1[(wave*16 + l15)*LSTR + ks*32 + quad*8];
      b0f[ks] = *(const bf8_t*)&sB0[(wave*16 + l15)*LSTR + ks*32 + quad*8];
      unpack8(b1f[ks], tmp);
      b1v[2*ks]   = (f4_t){tmp[0],tmp[1],tmp[2],tmp[3]};
      b1v[2*ks+1] = (f4_t){tmp[4],tmp[5],tmp[6],tmp[7]};
      #pragma unroll
      for (int m = 0; m < 2; ++m)
        wfA[m][ks] = *(const bf8_t*)&sW2[(m*16 + l15)*LSTR + ks*32 + quad*8];
    }
    #pragma unroll
    for (int n = 0; n < 3; ++n){
      f4_t a = z4;
      #pragma unroll
      for (int ks = 0; ks < 2; ++ks){
        ua[n][ks] = *(const bf8_t*)&sU[(n*16 + l15)*LSTR + ks*32 + quad*8];
        a = __builtin_amdgcn_mfma_f32_16x16x32_bf16(b0f[ks], ua[n][ks], a, 0, 0, 0);
      }
      Y0[n] = a;
    }
  }
  __syncthreads();   // setup reads done (sB1/sB0/sU/sW2 all dead)
  #pragma unroll
  for (int t = 0; t < 10; ++t) sUf[tid + t*256] = efr[t];
  __syncthreads();

  const int obase = wave*16 + quad*4;
  const int o2b   = quad*4;
  const int kme   = wave*16 + l15;
  const int kmc   = kme < 40 ? kme : 39;
  const bool kval = (kme < 40) & (wave < 3);
  f4_t pa1[2], psum[2];
  psum[0] = z4; psum[1] = z4;
  if (wave < 3){
    #pragma unroll
    for (int m = 0; m < 2; ++m)
      pa1[m] = *(const f4_t*)&A1p[((size_t)((b*40 + fix)*40 + kmc))*32 + m*16 + o2b];
  }

  // pointer-carried streams
  const float* qp  = Q3c + (size_t)b*102400 + (size_t)fix*64 + obase;        // stride 2560
  const float* a2p = A2t + ((size_t)b*1600 + kmc)*32 + o2b;                  // stride 1280
  const float* ccp = Cc  + ((size_t)b*1600 + fix)*32 + o2b;                  // stride 1280
  const float* ep  = sUf + quad*8;

  f4_t cadd_n = *(const f4_t*)qp; qp += 2560;
  #pragma unroll 2
  for (int l = 0; l < 40; ++l){
    f4_t cadd = cadd_n;
    if (l < 39){ cadd_n = *(const f4_t*)qp; qp += 2560; }
    f4_t a2v[2], ccv[2];
    if (wave < 3){
      a2v[0] = *(const f4_t*)(a2p);      a2v[1] = *(const f4_t*)(a2p + 16);
      ccv[0] = *(const f4_t*)(ccp);      ccv[1] = *(const f4_t*)(ccp + 16);
    }
    a2p += 1280; ccp += 1280;
    f4_t p00 = b1v[0] * *(const f4_t*)(ep);
    f4_t p01 = b1v[1] * *(const f4_t*)(ep + 4);
    f4_t p10 = b1v[2] * *(const f4_t*)(ep + 32);
    f4_t p11 = b1v[3] * *(const f4_t*)(ep + 36);
    ep += 64;
    union { bf8_t v; unsigned u[4]; } m0, m1;
    m0.u[0] = cvtpk(p00[0], p00[1]); m0.u[1] = cvtpk(p00[2], p00[3]);
    m0.u[2] = cvtpk(p01[0], p01[1]); m0.u[3] = cvtpk(p01[2], p01[3]);
    m1.u[0] = cvtpk(p10[0], p10[1]); m1.u[1] = cvtpk(p10[2], p10[3]);
    m1.u[2] = cvtpk(p11[0], p11[1]); m1.u[3] = cvtpk(p11[2], p11[3]);
    u16* Hb = (u16*)(smem + (l & 1)*9216);
    #pragma unroll
    for (int n = 0; n < 3; ++n){
      f4_t a = Y0[n];
      a = __builtin_amdgcn_mfma_f32_16x16x32_bf16(m0.v, ua[n][0], a, 0, 0, 0);
      a = __builtin_amdgcn_mfma_f32_16x16x32_bf16(m1.v, ua[n][1], a, 0, 0, 0);
      f4_t h = __builtin_elementwise_max(a + cadd, z4);   // k>=40 rows masked at psum
      uint2 pw;
      pw.x = cvtpk(h[0], h[1]);
      pw.y = cvtpk(h[2], h[3]);
      *(uint2*)&Hb[(n*16 + l15)*LSTR + obase] = pw;
    }
    __syncthreads();
    if (wave < 3){
      bf8_t hB[2];
      #pragma unroll
      for (int ks = 0; ks < 2; ++ks)
        hB[ks] = *(const bf8_t*)&Hb[(wave*16 + l15)*LSTR + ks*32 + quad*8];
      #pragma unroll
      for (int m = 0; m < 2; ++m){
        f4_t y = z4;
        y = __builtin_amdgcn_mfma_f32_16x16x32_bf16(wfA[m][0], hB[0], y, 0, 0, 0);
        y = __builtin_amdgcn_mfma_f32_16x16x32_bf16(wfA[m][1], hB[1], y, 0, 0, 0);
        if (kval){
          f4_t v = y + pa1[m] + a2v[m] + ccv[m];
          psum[m] += __builtin_elementwise_max(v, z4);
        }
      }
    }
  }

  if (wave < 3){
    #pragma unroll
    for (int m = 0; m < 2; ++m){
      f4_t v = psum[m];
      v += shfl4x(v, 1); v += shfl4x(v, 2); v += shfl4x(v, 4); v += shfl4x(v, 8);
      if (l15 == 0){
        #pragma unroll
        for (int r = 0; r < 4; ++r) atomicAdd(&soacc[m*16 + o2b + r], v[r]);
      }
    }
  }
  __syncthreads();
  if (tid < 32) out_part[(b*40 + fix)*32 + tid] = soacc[tid];
}

// ---------------- final: sum_j out_part, relu, dot out_w (parallel) ----------------
__global__ __launch_bounds__(512) void k7(const float* __restrict__ out_part, const float* __restrict__ ow,
                                          const float* __restrict__ ob, float* __restrict__ out){
  int tid = threadIdx.x;
  int b = tid >> 5, o = tid & 31;
  float s = 0.f;
  for (int j = 0; j < 40; ++j) s += out_part[(b*40 + j)*32 + o];
  s = s > 0.f ? s : 0.f;
  float v = s * ow[o];
  v += __shfl_xor(v, 1); v += __shfl_xor(v, 2); v += __shfl_xor(v, 4);
  v += __shfl_xor(v, 8); v += __shfl_xor(v, 16);
  if (o == 0) out[b] = v + ob[0];
}

extern "C" void kernel_launch(void* const* d_in, const int* in_sizes, int n_in,
                              void* d_out, int out_size, void* d_ws, size_t ws_size,
                              hipStream_t stream){
  const float* x    = (const float*)d_in[0];
  const float* c1w  = (const float*)d_in[1];
  const float* c1b  = (const float*)d_in[2];
  const float* c2w  = (const float*)d_in[3];
  const float* c2b  = (const float*)d_in[4];
  const float* fcw  = (const float*)d_in[5];
  const float* fcb  = (const float*)d_in[6];
  const float* e1w  = (const float*)d_in[7];
  const float* e1b  = (const float*)d_in[8];
  const float* e2w  = (const float*)d_in[9];
  const float* e2b  = (const float*)d_in[10];
  const float* ow   = (const float*)d_in[11];
  const float* ob   = (const float*)d_in[12];

  char* ws = (char*)d_ws;
  size_t off = 0;
  auto alloc = [&](size_t bytes) -> void* {
    void* p = ws + off;
    off += (bytes + 255) & ~(size_t)255;
    return p;
  };
  u16*   z1t  = (u16*)  alloc((size_t)640*4608*2);
  u16*   wt2  = (u16*)  alloc(51200*2);
  u16*   fcwT = (u16*)  alloc(65536*2);
  u16*   z2g  = (u16*)  alloc((size_t)640*1024*2);
  float* e_f  = (float*)alloc(40960*4);
  u16*   e_b  = (u16*)  alloc(40960*2);
  float* Sg   = (float*)alloc(1024*4);
  u16*   Vt   = (u16*)  alloc((size_t)16*16384*2);
  float* c0   = (float*)alloc(1024*4);
  float* P5   = (float*)alloc(40960*4);
  float* P6   = (float*)alloc(40960*4);
  u16*   W2T0 = (u16*)  alloc(2048*2);
  u16*   W3St = (u16*)  alloc((size_t)16*4096*2);
  float* Q3c  = (float*)alloc((size_t)1638400*4);
  float* si2  = (float*)alloc((size_t)1638400*4);
  float* sj2  = (float*)alloc((size_t)1638400*4);
  float* sk2  = (float*)alloc((size_t)1638400*4);
  float* ssij = (float*)alloc(40960*4);
  float* ssik = (float*)alloc(40960*4);
  float* ssjk = (float*)alloc(40960*4);
  float* A4   = (float*)alloc(20480*4);
  float* A5   = (float*)alloc(20480*4);
  float* A6   = (float*)alloc(20480*4);
  float* A7   = (float*)alloc(512*4);
  float* A1p  = (float*)alloc((size_t)819200*4);
  float* A2t  = (float*)alloc((size_t)819200*4);
  float* Cc   = (float*)alloc((size_t)819200*4);
  float* op   = (float*)alloc(20480*4);
  (void)in_sizes; (void)n_in; (void)out_size; (void)ws_size;

  kconv1 <<<672, 256, 0, stream>>>(x, c1w, c1b, z1t, c2w, fcw, wt2, fcwT);
  kconv2m<<<640, 256, 0, stream>>>(z1t, wt2, c2b, z2g);
  kfc    <<<40,  256, 0, stream>>>(z2g, fcwT, fcb, e_f, e_b);
  kprep  <<<dim3(16,4), 256, 0, stream>>>(e_f, e1w, e1b, e2w, Sg, Vt, c0, P5, P6, W2T0, W3St);
  kpq    <<<640, 256, 0, stream>>>(e_b, W3St, P5, P6, c0, Q3c);
  kh01   <<<dim3(640,2), 256, 0, stream>>>(e_b, e_f, Vt, Q3c, si2, sj2, sk2);
  k5ar   <<<dim3(16,3,2), 256, 0, stream>>>(si2, sj2, ssij, ssik, ssjk);
  k5am   <<<dim3(16,2), 256, 0, stream>>>(ssij, ssik, ssjk, e2w, e2b, A4, A5, A6, A7);
  k5b    <<<dim3(640,3), 256, 0, stream>>>(si2, sj2, sk2, e2w, A4, A5, A6, A7, A1p, A2t, Cc);
  kh2    <<<640, 256, 0, stream>>>(e_b, e_f, Vt, Q3c, W2T0, A1p, A2t, Cc, op);
  k7     <<<1, 512, 0, stream>>>(op, ow, ob, (float*)d_out);
}

// Round 13
// 278.784 us; speedup vs baseline: 3.1764x; 2.2907x over previous
//
#include <hip/hip_runtime.h>
#include <hip/hip_bf16.h>

// UniqueEq3Net: conv stack -> e(640,64); t = e⊗e⊗e never materialized.
// Layer1 (transposed MFMA): h^T[o][k] = (B1⊙e_l)^T · U + Y0 + cadd.
// R13 = exact R10 re-baseline (279 µs). R11/R12 lesson: kh01/kh2 working set is
// ~60 VGPR + ~40 acc regs in the unified file; min-waves>4 caps combined regs
// below that -> spill (FETCH 0.9-1.3 GB). Occupancy ceiling here is structural.

typedef unsigned short u16;
typedef __attribute__((ext_vector_type(8))) short bf8_t;   // 8 bf16 (4 VGPRs)
typedef __attribute__((ext_vector_type(4))) float f4_t;

#define LSTR 72   // padded LDS row stride (u16): 144B rows, 16B-aligned

__device__ inline u16 f2bf(float f){
  union { float f; unsigned u; } v; v.f = f;
  unsigned r = v.u + 0x7fffu + ((v.u >> 16) & 1u);
  return (u16)(r >> 16);
}
__device__ inline float bflo(unsigned u){ union { unsigned x; float f; } v; v.x = u << 16; return v.f; }
__device__ inline float bfhi(unsigned u){ union { unsigned x; float f; } v; v.x = u & 0xffff0000u; return v.f; }
__device__ inline unsigned pack2(float a, float b){ return (unsigned)f2bf(a) | ((unsigned)f2bf(b) << 16); }
__device__ inline unsigned cvtpk(float lo, float hi){
  __hip_bfloat162 h2 = __float22bfloat162_rn(make_float2(lo, hi));
  union { __hip_bfloat162 h; unsigned u; } c; c.h = h2; return c.u;
}
__device__ inline void unpack8(bf8_t x, float* o){
  union { bf8_t v; unsigned u[4]; } q; q.v = x;
  #pragma unroll
  for (int p = 0; p < 4; ++p){ o[2*p] = bflo(q.u[p]); o[2*p+1] = bfhi(q.u[p]); }
}
__device__ inline f4_t shfl4x(f4_t v, int m){
  f4_t r;
  r[0] = __shfl_xor(v[0], m); r[1] = __shfl_xor(v[1], m);
  r[2] = __shfl_xor(v[2], m); r[3] = __shfl_xor(v[3], m);
  return r;
}

// ---------------- conv1 + pool -> z1t ; blocks >=640 do weight prep ----------------
__global__ __launch_bounds__(256) void kconv1(const float* __restrict__ x, const float* __restrict__ w1,
                                              const float* __restrict__ b1, u16* __restrict__ z1t,
                                              const float* __restrict__ w2, const float* __restrict__ fcw,
                                              u16* __restrict__ wt2, u16* __restrict__ fcwT){
  __shared__ float simg[784];
  int img = blockIdx.x, tid = threadIdx.x;
  if (img >= 640){
    int t = (img - 640)*256 + tid, stride = 32*256;
    for (int i = t; i < 51200; i += stride){
      int tap = i >> 11, rc = i & 2047, co = rc >> 5, ci = rc & 31;
      wt2[i] = f2bf(w2[co*800 + ci*25 + tap]);
    }
    for (int i = t; i < 65536; i += stride){
      int o = i >> 10, k = i & 1023;
      fcwT[i] = f2bf(fcw[k*64 + o]);
    }
    return;
  }
  for (int i = tid; i < 784; i += 256) simg[i] = x[img*784 + i];
  const int c = tid & 31;
  float wc[25];
  #pragma unroll
  for (int t = 0; t < 25; ++t) wc[t] = w1[c*25 + t];
  const float bb = b1[c];
  __syncthreads();
  #pragma unroll 2
  for (int it = 0; it < 18; ++it){
    int p = (tid >> 5) + it*8;
    int py = p / 12, px = p % 12;
    float patch[36];
    const float* sp = &simg[2*py*28 + 2*px];
    #pragma unroll
    for (int yy = 0; yy < 6; ++yy)
      #pragma unroll
      for (int xx = 0; xx < 6; ++xx) patch[yy*6+xx] = sp[yy*28+xx];
    float mx = -1e30f;
    #pragma unroll
    for (int sy = 0; sy < 2; ++sy)
    #pragma unroll
    for (int sx = 0; sx < 2; ++sx){
      float s = bb;
      #pragma unroll
      for (int dy = 0; dy < 5; ++dy)
        #pragma unroll
        for (int dx = 0; dx < 5; ++dx)
          s += patch[(sy+dy)*6 + sx+dx] * wc[dy*5+dx];
      mx = fmaxf(mx, s);
    }
    z1t[(size_t)img*4608 + p*32 + c] = f2bf(fmaxf(mx, 0.f));
  }
}

// ---------------- conv2 (MFMA, 25 shifted K=32 GEMMs) + pool -> z2g (640,1024) bf16 ----------------
__global__ __launch_bounds__(256) void kconv2m(const u16* __restrict__ z1t, const u16* __restrict__ wt2,
                                               const float* __restrict__ b2, u16* __restrict__ z2g){
  __shared__ __align__(16) u16 sz[4608];
  __shared__ __align__(16) u16 sz2[1024];
  int img = blockIdx.x, tid = threadIdx.x;
  for (int i = tid; i < 576; i += 256)
    ((uint4*)sz)[i] = ((const uint4*)(z1t + (size_t)img*4608))[i];
  __syncthreads();
  const int wave = tid >> 6, lane = tid & 63, l15 = lane & 15, quad = lane >> 4;
  const int y = wave*2 + (l15 >> 3), x = l15 & 7;
  f4_t acc[4];
  acc[0] = (f4_t){0.f,0.f,0.f,0.f}; acc[1] = acc[0]; acc[2] = acc[0]; acc[3] = acc[0];
  #pragma unroll
  for (int dy = 0; dy < 5; ++dy)
    #pragma unroll
    for (int dx = 0; dx < 5; ++dx){
      const int tap = dy*5 + dx;
      bf8_t af = *(const bf8_t*)&sz[((y+dy)*12 + (x+dx))*32 + quad*8];
      const u16* wp = wt2 + tap*2048 + l15*32 + quad*8;
      #pragma unroll
      for (int nt = 0; nt < 4; ++nt){
        bf8_t bf = *(const bf8_t*)(wp + nt*512);
        acc[nt] = __builtin_amdgcn_mfma_f32_16x16x32_bf16(af, bf, acc[nt], 0, 0, 0);
      }
    }
  #pragma unroll
  for (int nt = 0; nt < 4; ++nt){
    int co = nt*16 + l15;
    float v0 = fmaxf(acc[nt][0], acc[nt][1]);
    float v1 = fmaxf(acc[nt][2], acc[nt][3]);
    v0 = fmaxf(v0, __shfl_xor(v0, 32));
    v1 = fmaxf(v1, __shfl_xor(v1, 32));
    if (quad < 2){
      float bb = b2[co];
      sz2[co*16 + wave*4 + quad*2 + 0] = f2bf(fmaxf(v0 + bb, 0.f));
      sz2[co*16 + wave*4 + quad*2 + 1] = f2bf(fmaxf(v1 + bb, 0.f));
    }
  }
  __syncthreads();
  if (tid < 128) ((uint4*)(z2g + (size_t)img*1024))[tid] = ((const uint4*)sz2)[tid];
}

// ---------------- fc: e = relu(z2g @ fcw + fcb) ----------------
__global__ __launch_bounds__(256) void kfc(const u16* __restrict__ z2g, const u16* __restrict__ fcwT,
                                           const float* __restrict__ fcb,
                                           float* __restrict__ e_f, u16* __restrict__ e_b){
  __shared__ __align__(16) u16 sA[16*1032];
  int img0 = blockIdx.x*16, tid = threadIdx.x;
  for (int i = tid; i < 2048; i += 256){
    int row = i >> 7, c16 = i & 127;
    ((uint4*)(sA + row*1032))[c16] = ((const uint4*)(z2g + (size_t)(img0+row)*1024))[c16];
  }
  __syncthreads();
  const int wave = tid >> 6, lane = tid & 63, l15 = lane & 15, quad = lane >> 4;
  const int o = wave*16 + l15;
  f4_t acc = (f4_t){0.f,0.f,0.f,0.f};
  #pragma unroll 8
  for (int ks = 0; ks < 32; ++ks){
    bf8_t af = *(const bf8_t*)&sA[l15*1032 + ks*32 + quad*8];
    bf8_t bf = *(const bf8_t*)(fcwT + (size_t)o*1024 + ks*32 + quad*8);
    acc = __builtin_amdgcn_mfma_f32_16x16x32_bf16(af, bf, acc, 0, 0, 0);
  }
  const float bb = fcb[o];
  #pragma unroll
  for (int r = 0; r < 4; ++r){
    int img = img0 + quad*4 + r;
    float v = fmaxf(acc[r] + bb, 0.f);
    e_f[img*64 + o] = v;
    e_b[img*64 + o] = f2bf(v);
  }
}

// ---------------- per-b precompute, grid (16,4) ----------------
__global__ __launch_bounds__(256) void kprep(const float* __restrict__ e_f, const float* __restrict__ e1w,
    const float* __restrict__ e1b, const float* __restrict__ e2w,
    float* __restrict__ Sg, u16* __restrict__ Vt, float* __restrict__ c0,
    float* __restrict__ P5, float* __restrict__ P6, u16* __restrict__ W2T0,
    u16* __restrict__ W3St){
  int b = blockIdx.x, ph = blockIdx.y, tid = threadIdx.x;
  __shared__ float se[2560];
  __shared__ float S[64], S2[64], S3[64];
  for (int i = tid; i < 2560; i += 256) se[i] = e_f[b*2560 + i];
  __syncthreads();
  if (tid < 64){
    float s = 0.f;
    for (int i = 0; i < 40; ++i) s += se[i*64 + tid];
    S[tid] = s; S2[tid] = s*s; S3[tid] = s*s*s;
    if (ph == 0) Sg[b*64 + tid] = s;
  }
  __syncthreads();
  {
    const int m = ph;
    for (int idx = tid; idx < 4096; idx += 256){
      int o = idx >> 6, d = idx & 63;
      float v;
      if (m == 0)      v = e1w[d*64 + o];
      else if (m == 1) v = S[d] * e1w[4096  + d*64 + o];
      else if (m == 2) v = S[d] * e1w[8192  + d*64 + o];
      else             v = S2[d] * e1w[16384 + d*64 + o];
      Vt[(size_t)b*16384 + m*4096 + idx] = f2bf(v);
    }
  }
  if (ph == 0){
    if (tid < 64){
      float a = e1b[tid];
      for (int d = 0; d < 64; ++d) a += S3[d] * e1w[7*4096 + d*64 + tid];
      c0[b*64 + tid] = a;
    }
  } else if (ph == 1){
    for (int idx = tid; idx < 4096; idx += 256){
      int o = idx >> 6, d = idx & 63;
      W3St[(size_t)b*4096 + idx] = f2bf(S[d] * e1w[3*4096 + d*64 + o]);
    }
  } else {
    int lo = (ph == 2) ? 0 : 1280, hi = lo + 1280;
    for (int idx = lo + tid; idx < hi; idx += 256){
      int j = idx >> 6, o = idx & 63;
      float a5 = 0.f, a6 = 0.f;
      for (int d = 0; d < 64; ++d){
        float es = se[j*64 + d] * S2[d];
        a5 += es * e1w[5*4096 + d*64 + o];
        a6 += es * e1w[6*4096 + d*64 + o];
      }
      P5[(b*40+j)*64 + o] = a5;
      P6[(b*40+j)*64 + o] = a6;
    }
    if (ph == 3 && b == 0){
      for (int idx = tid; idx < 2048; idx += 256){
        int o = idx >> 6, d = idx & 63;
        W2T0[o*64 + d] = f2bf(e2w[d*32 + o]);
      }
    }
  }
}

// ---------------- kpq: P[i] tile in LDS AND Q3c[b,i,:,:] via MFMA ----------------
__global__ __launch_bounds__(256) void kpq(const u16* __restrict__ e_b, const u16* __restrict__ W3St,
    const float* __restrict__ P5, const float* __restrict__ P6, const float* __restrict__ c0,
    float* __restrict__ Q3c){
  __shared__ __align__(16) u16 sP[48*LSTR];
  __shared__ __align__(16) u16 sW[64*LSTR];
  int blk = blockIdx.x, b = blk/40, i = blk%40, tid = threadIdx.x;
  const int wave = tid >> 6, lane = tid & 63, l15 = lane & 15, quad = lane >> 4;
  for (int idx = tid; idx < 2048; idx += 256){
    int o = idx >> 5, c = idx & 31;
    ((unsigned*)(sW + o*LSTR))[c] = ((const unsigned*)(W3St + (size_t)b*4096))[idx];
  }
  const unsigned* eb32 = (const unsigned*)(e_b + (size_t)b*2560);
  const unsigned* el = eb32 + i*32;
  #pragma unroll
  for (int it = 0; it < 6; ++it){
    int idx = tid + it*256;
    int k = idx >> 5, d2 = idx & 31;
    unsigned pv = 0;
    if (k < 40){
      unsigned ul = el[d2], uk = eb32[k*32 + d2];
      pv = pack2(bflo(ul)*bflo(uk), bfhi(ul)*bfhi(uk));
    }
    ((unsigned*)(sP + k*LSTR))[d2] = pv;
  }
  __syncthreads();
  bf8_t wf[2];
  #pragma unroll
  for (int ks = 0; ks < 2; ++ks)
    wf[ks] = *(const bf8_t*)&sW[(wave*16 + l15)*LSTR + ks*32 + quad*8];
  f4_t acc[3];
  #pragma unroll
  for (int n = 0; n < 3; ++n){
    f4_t a = (f4_t){0.f,0.f,0.f,0.f};
    #pragma unroll
    for (int ks = 0; ks < 2; ++ks){
      bf8_t pkf = *(const bf8_t*)&sP[(n*16 + l15)*LSTR + ks*32 + quad*8];
      a = __builtin_amdgcn_mfma_f32_16x16x32_bf16(wf[ks], pkf, a, 0, 0, 0);
    }
    acc[n] = a;
  }
  const int obase = wave*16 + quad*4;
  f4_t p6v = *(const f4_t*)&P6[(b*40+i)*64 + obase];
  f4_t c0v = *(const f4_t*)&c0[b*64 + obase];
  #pragma unroll
  for (int n = 0; n < 3; ++n){
    int j = n*16 + l15;
    if (j < 40){
      f4_t p5v = *(const f4_t*)&P5[(b*40+j)*64 + obase];
      f4_t outv = acc[n] + p5v + p6v + c0v;
      *(f4_t*)&Q3c[((size_t)((b*40+i)*40 + j))*64 + obase] = outv;
    }
  }
}

// ---------------- layer-1 reduction passes (modes 0 & 1); pointer-carried streams ----------------
__global__ __launch_bounds__(256, 4) void kh01(
    const u16* __restrict__ e_b, const float* __restrict__ e_f,
    const u16* __restrict__ Vt, const float* __restrict__ Q3c,
    float* __restrict__ si2, float* __restrict__ sj2, float* __restrict__ sk2)
{
  __shared__ __align__(16) char smem[25344];
  u16*   sU  = (u16*)smem;             // dead after setup
  u16*   sB1 = (u16*)(smem + 6912);    // dead after setup
  u16*   sB0 = (u16*)(smem + 16128);
  float* sUf = (float*)smem;           // aliases sU+sB1
  const int tid = threadIdx.x;
  const int b = blockIdx.x / 40, fix = blockIdx.x % 40;
  const int mode = blockIdx.y;
  const int wave = tid >> 6, lane = tid & 63, l15 = lane & 15, quad = lane >> 4;
  const f4_t z4 = (f4_t){0.f,0.f,0.f,0.f};

  for (int idx = tid; idx < 1536; idx += 256){
    int r = idx >> 5, c = idx & 31;
    unsigned v = (r < 40) ? ((const unsigned*)e_b)[(b*40 + r)*32 + c] : 0u;
    ((unsigned*)(sU + r*LSTR))[c] = v;
  }
  float efr[10];
  #pragma unroll
  for (int t = 0; t < 10; ++t) efr[t] = e_f[b*2560 + tid + t*256];
  const unsigned* eg = (const unsigned*)(e_b + (size_t)(b*40 + fix)*64);
  const unsigned* Vb = (const unsigned*)(Vt + (size_t)b*16384);
  for (int idx = tid; idx < 2048; idx += 256){
    int o = idx >> 5, d2 = idx & 31;
    unsigned eu = eg[d2];
    unsigned v0 = Vb[o*32 + d2];
    unsigned vA = Vb[(2-mode)*2048 + o*32 + d2];
    unsigned vB = Vb[(1+mode)*2048 + o*32 + d2];
    unsigned v3 = Vb[3*2048 + o*32 + d2];
    float e0 = bflo(eu), e1 = bfhi(eu);
    ((unsigned*)(sB1 + o*LSTR))[d2] = pack2(e0*bflo(v0)+bflo(vA), e1*bfhi(v0)+bfhi(vA));
    ((unsigned*)(sB0 + o*LSTR))[d2] = pack2(e0*bflo(vB)+bflo(v3), e1*bfhi(vB)+bfhi(v3));
  }
  __syncthreads();

  f4_t b1v[4];
  bf8_t ua[3][2];
  f4_t Y0[3];
  {
    bf8_t b0f[2], b1f[2];
    float tmp[8];
    #pragma unroll
    for (int ks = 0; ks < 2; ++ks){
      b1f[ks] = *(const bf8_t*)&sB1[(wave*16 + l15)*LSTR + ks*32 + quad*8];
      b0f[ks] = *(const bf8_t*)&sB0[(wave*16 + l15)*LSTR + ks*32 + quad*8];
      unpack8(b1f[ks], tmp);
      b1v[2*ks]   = (f4_t){tmp[0],tmp[1],tmp[2],tmp[3]};
      b1v[2*ks+1] = (f4_t){tmp[4],tmp[5],tmp[6],tmp[7]};
    }
    #pragma unroll
    for (int n = 0; n < 3; ++n){
      f4_t a = z4;
      #pragma unroll
      for (int ks = 0; ks < 2; ++ks){
        ua[n][ks] = *(const bf8_t*)&sU[(n*16 + l15)*LSTR + ks*32 + quad*8];
        a = __builtin_amdgcn_mfma_f32_16x16x32_bf16(b0f[ks], ua[n][ks], a, 0, 0, 0);
      }
      Y0[n] = a;
    }
  }
  __syncthreads();
  #pragma unroll
  for (int t = 0; t < 10; ++t) sUf[tid + t*256] = efr[t];
  __syncthreads();

  const int obase = wave*16 + quad*4;
  const float km = (l15 < 8) ? 1.f : 0.f;
  const f4_t km4 = (f4_t){km, km, km, km};
  f4_t sacc[3];
  sacc[0] = z4; sacc[1] = z4; sacc[2] = z4;

  // pointer-carried streams (no per-iter 64-bit address mul)
  const int qstride = mode ? 64 : 2560;
  const float* qp = Q3c + (size_t)b*102400 + (mode ? (size_t)fix*2560 : (size_t)fix*64) + obase;
  float* skp = sk2 + ((size_t)(b*40)*40 + fix)*64 + obase;   // mode0 only; stride 2560
  const float* ep = sUf + quad*8;

  f4_t cadd_n = *(const f4_t*)qp; qp += qstride;
  #pragma unroll 2
  for (int l = 0; l < 40; ++l){
    f4_t cadd = cadd_n;
    if (l < 39){ cadd_n = *(const f4_t*)qp; qp += qstride; }
    f4_t p00 = b1v[0] * *(const f4_t*)(ep);
    f4_t p01 = b1v[1] * *(const f4_t*)(ep + 4);
    f4_t p10 = b1v[2] * *(const f4_t*)(ep + 32);
    f4_t p11 = b1v[3] * *(const f4_t*)(ep + 36);
    ep += 64;
    union { bf8_t v; unsigned u[4]; } m0, m1;
    m0.u[0] = cvtpk(p00[0], p00[1]); m0.u[1] = cvtpk(p00[2], p00[3]);
    m0.u[2] = cvtpk(p01[0], p01[1]); m0.u[3] = cvtpk(p01[2], p01[3]);
    m1.u[0] = cvtpk(p10[0], p10[1]); m1.u[1] = cvtpk(p10[2], p10[3]);
    m1.u[2] = cvtpk(p11[0], p11[1]); m1.u[3] = cvtpk(p11[2], p11[3]);
    f4_t khs = z4;
    #pragma unroll
    for (int n = 0; n < 3; ++n){
      f4_t a = Y0[n];
      a = __builtin_amdgcn_mfma_f32_16x16x32_bf16(m0.v, ua[n][0], a, 0, 0, 0);
      a = __builtin_amdgcn_mfma_f32_16x16x32_bf16(m1.v, ua[n][1], a, 0, 0, 0);
      f4_t h = __builtin_elementwise_max(a + cadd, z4);
      sacc[n] += h;                         // k>=40 garbage: write-guarded later
      if (mode == 0) khs += (n == 2) ? h * km4 : h;
    }
    if (mode == 0){
      khs += shfl4x(khs, 1);
      khs += shfl4x(khs, 2);
      khs += shfl4x(khs, 4);
      khs += shfl4x(khs, 8);
      if (l15 == 0) *(f4_t*)skp = khs;
      skp += 2560;
    }
  }
  float* dst = mode ? sj2 : si2;
  #pragma unroll
  for (int n = 0; n < 3; ++n){
    int k = n*16 + l15;
    if (k < 40)
      *(f4_t*)&dst[((size_t)((b*40 + fix)*40 + k))*64 + obase] = sacc[n];
  }
}

// ---------------- k5ar: the three 40-deep sums, grid (16,3,2) ----------------
__global__ __launch_bounds__(256) void k5ar(const float* __restrict__ si2, const float* __restrict__ sj2,
    float* __restrict__ ssij, float* __restrict__ ssik, float* __restrict__ ssjk){
  int b = blockIdx.x, which = blockIdx.y, half = blockIdx.z, tid = threadIdx.x;
  int base = half*1280;
  for (int idx = base + tid; idx < base + 1280; idx += 256){
    int r = idx >> 6, d = idx & 63;
    float a = 0.f;
    if (which == 0){
      for (int j = 0; j < 40; ++j) a += si2[((size_t)(b*40+j)*40 + r)*64 + d];
      ssij[b*2560 + idx] = a;
    } else if (which == 1){
      const float* p = &si2[(size_t)(b*40+r)*2560 + d];
      for (int k = 0; k < 40; ++k) a += p[k*64];
      ssik[b*2560 + idx] = a;
    } else {
      const float* q = &sj2[(size_t)(b*40+r)*2560 + d];
      for (int k = 0; k < 40; ++k) a += q[k*64];
      ssjk[b*2560 + idx] = a;
    }
  }
}

// ---------------- k5am: A4/A5/A6/A7 matmuls, grid (16,2) ----------------
__global__ __launch_bounds__(256) void k5am(const float* __restrict__ ssij, const float* __restrict__ ssik,
    const float* __restrict__ ssjk, const float* __restrict__ e2w, const float* __restrict__ e2b,
    float* __restrict__ A4, float* __restrict__ A5, float* __restrict__ A6, float* __restrict__ A7){
  int b = blockIdx.x, half = blockIdx.y, tid = threadIdx.x;
  __shared__ float s1[2560], s2[2560], ss2[64];
  if (half == 0){
    for (int i = tid; i < 2560; i += 256) s1[i] = ssij[b*2560 + i];
    __syncthreads();
    if (tid < 64){
      float a = 0.f;
      for (int k = 0; k < 40; ++k) a += s1[k*64 + tid];
      ss2[tid] = a;
    }
    __syncthreads();
    for (int idx = tid; idx < 1280; idx += 256){
      int k = idx >> 5, o = idx & 31;
      float a4 = 0.f;
      for (int d = 0; d < 64; ++d) a4 += s1[k*64+d] * e2w[4*2048 + d*32 + o];
      A4[(b*40+k)*32 + o] = a4;
    }
    if (tid < 32){
      float a = e2b[tid];
      for (int d = 0; d < 64; ++d) a += ss2[d] * e2w[7*2048 + d*32 + tid];
      A7[b*32 + tid] = a;
    }
  } else {
    for (int i = tid; i < 2560; i += 256){ s1[i] = ssik[b*2560 + i]; s2[i] = ssjk[b*2560 + i]; }
    __syncthreads();
    for (int idx = tid; idx < 1280; idx += 256){
      int k = idx >> 5, o = idx & 31;
      float a5 = 0.f, a6 = 0.f;
      for (int d = 0; d < 64; ++d){
        a5 += s1[k*64+d] * e2w[5*2048 + d*32 + o];
        a6 += s2[k*64+d] * e2w[6*2048 + d*32 + o];
      }
      A5[(b*40+k)*32 + o] = a5;
      A6[(b*40+k)*32 + o] = a6;
    }
  }
}

// ---------------- big addends, f4-vectorized ----------------
__global__ __launch_bounds__(256) void k5b(const float* __restrict__ si2, const float* __restrict__ sj2,
    const float* __restrict__ sk2, const float* __restrict__ e2w,
    const float* __restrict__ A4, const float* __restrict__ A5, const float* __restrict__ A6,
    const float* __restrict__ A7,
    float* __restrict__ A1p, float* __restrict__ A2t, float* __restrict__ Cc){
  int which = blockIdx.y;
  int blk = blockIdx.x, b = blk/40, f = blk%40, tid = threadIdx.x;
  __shared__ __align__(16) f4_t ssrc[640];
  __shared__ __align__(16) f4_t swt[32*17];
  const float* S = (which == 0) ? si2 : (which == 1) ? sj2 : sk2;
  int wop = which + 1;
  const f4_t* Sg4 = (const f4_t*)&S[(size_t)(b*40+f)*2560];
  for (int idx = tid; idx < 640; idx += 256) ssrc[idx] = Sg4[idx];
  for (int idx = tid; idx < 512; idx += 256){
    int o = idx >> 4, d4 = idx & 15;
    f4_t w;
    #pragma unroll
    for (int r = 0; r < 4; ++r) w[r] = e2w[wop*2048 + (4*d4+r)*32 + o];
    swt[o*17 + d4] = w;
  }
  __syncthreads();
  const int o = tid & 31, rb = tid >> 5;
  float acc[5] = {0.f, 0.f, 0.f, 0.f, 0.f};
  #pragma unroll 4
  for (int d4 = 0; d4 < 16; ++d4){
    f4_t w = swt[o*17 + d4];
    #pragma unroll
    for (int it = 0; it < 5; ++it){
      f4_t s = ssrc[(rb + 8*it)*16 + d4];
      acc[it] += s[0]*w[0] + s[1]*w[1] + s[2]*w[2] + s[3]*w[3];
    }
  }
  #pragma unroll
  for (int it = 0; it < 5; ++it){
    int r = rb + 8*it;
    size_t oi = ((size_t)(b*40+f)*40 + r)*32 + o;
    float a = acc[it];
    if (which == 0)      A1p[oi] = a + A4[(b*40+r)*32 + o];
    else if (which == 1) A2t[oi] = a;
    else                 Cc[oi]  = a + A5[(b*40+r)*32 + o] + A6[(b*40+f)*32 + o] + A7[b*32 + o];
  }
}

// ---------------- mode2: layer-2; pointer-carried streams; sH dbuf over sB1/sB0 ----------------
__global__ __launch_bounds__(256, 3) void kh2(
    const u16* __restrict__ e_b, const float* __restrict__ e_f,
    const u16* __restrict__ Vt, const float* __restrict__ Q3c, const u16* __restrict__ W2T0,
    const float* __restrict__ A1p, const float* __restrict__ A2t, const float* __restrict__ Cc,
    float* __restrict__ out_part)
{
  __shared__ __align__(16) char smem[30080];
  u16*   sB1 = (u16*)smem;                  // loop: sH buf0
  u16*   sB0 = (u16*)(smem + 9216);         // loop: sH buf1
  u16*   sU  = (u16*)(smem + 18432);        // dead after setup
  u16*   sW2 = (u16*)(smem + 18432 + 6912); // dead after setup
  float* sUf = (float*)(smem + 18432);      // aliases sU+sW2
  float* soacc = (float*)(smem + 29952);
  const int tid = threadIdx.x;
  const int b = blockIdx.x / 40, fix = blockIdx.x % 40;   // fix = j
  const int wave = tid >> 6, lane = tid & 63, l15 = lane & 15, quad = lane >> 4;
  const f4_t z4 = (f4_t){0.f,0.f,0.f,0.f};

  for (int idx = tid; idx < 1536; idx += 256){
    int r = idx >> 5, c = idx & 31;
    unsigned v = (r < 40) ? ((const unsigned*)e_b)[(b*40 + r)*32 + c] : 0u;
    ((unsigned*)(sU + r*LSTR))[c] = v;
  }
  float efr[10];
  #pragma unroll
  for (int t = 0; t < 10; ++t) efr[t] = e_f[b*2560 + tid + t*256];
  const unsigned* eg = (const unsigned*)(e_b + (size_t)(b*40 + fix)*64);
  const unsigned* Vb = (const unsigned*)(Vt + (size_t)b*16384);
  for (int idx = tid; idx < 2048; idx += 256){
    int o = idx >> 5, d2 = idx & 31;
    unsigned eu = eg[d2];
    unsigned v0 = Vb[o*32 + d2];
    unsigned vA = Vb[2*2048 + o*32 + d2];
    unsigned vB = Vb[1*2048 + o*32 + d2];
    unsigned v3 = Vb[3*2048 + o*32 + d2];
    float e0 = bflo(eu), e1 = bfhi(eu);
    ((unsigned*)(sB1 + o*LSTR))[d2] = pack2(e0*bflo(v0)+bflo(vA), e1*bfhi(v0)+bfhi(vA));
    ((unsigned*)(sB0 + o*LSTR))[d2] = pack2(e0*bflo(vB)+bflo(v3), e1*bfhi(vB)+bfhi(v3));
  }
  for (int idx = tid; idx < 1024; idx += 256){
    int o = idx >> 5, c = idx & 31;
    ((unsigned*)(sW2 + o*LSTR))[c] = ((const unsigned*)W2T0)[idx];
  }
  if (tid < 32) soacc[tid] = 0.f;
  __syncthreads();

  f4_t b1v[4];
  bf8_t ua[3][2], wfA[2][2];
  f4_t Y0[3];
  {
    bf8_t b0f[2], b1f[2];
    float tmp[8];
    #pragma unroll
    for (int ks = 0; ks < 2; ++ks){
      b1f[ks] = *(const bf8_t*)&sB1[(wave*16 + l15)*LSTR + ks*32 + quad*8];
      b0f[ks] = *(const bf8_t*)&sB0[(wave*16 + l15)*LSTR + ks*32 + quad*8];
      unpack8(b1f[ks], tmp);
      b1v[2*ks]   = (f4_t){tmp[0],tmp[1],tmp[2],tmp[3]};
      b1v[2*ks+1] = (f4_t){tmp[4],tmp[5],tmp[6],tmp[7]};
      #pragma unroll
      for (int m = 0; m < 2; ++m)
        wfA[m][ks] = *(const bf8_t*)&sW2[(m*16 + l15)*LSTR + ks*32 + quad*8];
    }
    #pragma unroll
    for (int n = 0; n < 3; ++n){
      f4_t a = z4;
      #pragma unroll
      for (int ks = 0; ks < 2; ++ks){
        ua[n][ks] = *(const bf8_t*)&sU[(n*16 + l15)*LSTR + ks*32 + quad*8];
        a = __builtin_amdgcn_mfma_f32_16x16x32_bf16(b0f[ks], ua[n][ks], a, 0, 0, 0);
      }
      Y0[n] = a;
    }
  }
  __syncthreads();   // setup reads done (sB1/sB0/sU/sW2 all dead)
  #pragma unroll
  for (int t = 0; t < 10; ++t) sUf[tid + t*256] = efr[t];
  __syncthreads();

  const int obase = wave*16 + quad*4;
  const int o2b   = quad*4;
  const int kme   = wave*16 + l15;
  const int kmc   = kme < 40 ? kme : 39;
  const bool kval = (kme < 40) & (wave < 3);
  f4_t pa1[2], psum[2];
  psum[0] = z4; psum[1] = z4;
  if (wave < 3){
    #pragma unroll
    for (int m = 0; m < 2; ++m)
      pa1[m] = *(const f4_t*)&A1p[((size_t)((b*40 + fix)*40 + kmc))*32 + m*16 + o2b];
  }

  // pointer-carried streams
  const float* qp  = Q3c + (size_t)b*102400 + (size_t)fix*64 + obase;        // stride 2560
  const float* a2p = A2t + ((size_t)b*1600 + kmc)*32 + o2b;                  // stride 1280
  const float* ccp = Cc  + ((size_t)b*1600 + fix)*32 + o2b;                  // stride 1280
  const float* ep  = sUf + quad*8;

  f4_t cadd_n = *(const f4_t*)qp; qp += 2560;
  #pragma unroll 2
  for (int l = 0; l < 40; ++l){
    f4_t cadd = cadd_n;
    if (l < 39){ cadd_n = *(const f4_t*)qp; qp += 2560; }
    f4_t a2v[2], ccv[2];
    if (wave < 3){
      a2v[0] = *(const f4_t*)(a2p);      a2v[1] = *(const f4_t*)(a2p + 16);
      ccv[0] = *(const f4_t*)(ccp);      ccv[1] = *(const f4_t*)(ccp + 16);
    }
    a2p += 1280; ccp += 1280;
    f4_t p00 = b1v[0] * *(const f4_t*)(ep);
    f4_t p01 = b1v[1] * *(const f4_t*)(ep + 4);
    f4_t p10 = b1v[2] * *(const f4_t*)(ep + 32);
    f4_t p11 = b1v[3] * *(const f4_t*)(ep + 36);
    ep += 64;
    union { bf8_t v; unsigned u[4]; } m0, m1;
    m0.u[0] = cvtpk(p00[0], p00[1]); m0.u[1] = cvtpk(p00[2], p00[3]);
    m0.u[2] = cvtpk(p01[0], p01[1]); m0.u[3] = cvtpk(p01[2], p01[3]);
    m1.u[0] = cvtpk(p10[0], p10[1]); m1.u[1] = cvtpk(p10[2], p10[3]);
    m1.u[2] = cvtpk(p11[0], p11[1]); m1.u[3] = cvtpk(p11[2], p11[3]);
    u16* Hb = (u16*)(smem + (l & 1)*9216);
    #pragma unroll
    for (int n = 0; n < 3; ++n){
      f4_t a = Y0[n];
      a = __builtin_amdgcn_mfma_f32_16x16x32_bf16(m0.v, ua[n][0], a, 0, 0, 0);
      a = __builtin_amdgcn_mfma_f32_16x16x32_bf16(m1.v, ua[n][1], a, 0, 0, 0);
      f4_t h = __builtin_elementwise_max(a + cadd, z4);   // k>=40 rows masked at psum
      uint2 pw;
      pw.x = cvtpk(h[0], h[1]);
      pw.y = cvtpk(h[2], h[3]);
      *(uint2*)&Hb[(n*16 + l15)*LSTR + obase] = pw;
    }
    __syncthreads();
    if (wave < 3){
      bf8_t hB[2];
      #pragma unroll
      for (int ks = 0; ks < 2; ++ks)
        hB[ks] = *(const bf8_t*)&Hb[(wave*16 + l15)*LSTR + ks*32 + quad*8];
      #pragma unroll
      for (int m = 0; m < 2; ++m){
        f4_t y = z4;
        y = __builtin_amdgcn_mfma_f32_16x16x32_bf16(wfA[m][0], hB[0], y, 0, 0, 0);
        y = __builtin_amdgcn_mfma_f32_16x16x32_bf16(wfA[m][1], hB[1], y, 0, 0, 0);
        if (kval){
          f4_t v = y + pa1[m] + a2v[m] + ccv[m];
          psum[m] += __builtin_elementwise_max(v, z4);
        }
      }
    }
  }

  if (wave < 3){
    #pragma unroll
    for (int m = 0; m < 2; ++m){
      f4_t v = psum[m];
      v += shfl4x(v, 1); v += shfl4x(v, 2); v += shfl4x(v, 4); v += shfl4x(v, 8);
      if (l15 == 0){
        #pragma unroll
        for (int r = 0; r < 4; ++r) atomicAdd(&soacc[m*16 + o2b + r], v[r]);
      }
    }
  }
  __syncthreads();
  if (tid < 32) out_part[(b*40 + fix)*32 + tid] = soacc[tid];
}

// ---------------- final: sum_j out_part, relu, dot out_w (parallel) ----------------
__global__ __launch_bounds__(512) void k7(const float* __restrict__ out_part, const float* __restrict__ ow,
                                          const float* __restrict__ ob, float* __restrict__ out){
  int tid = threadIdx.x;
  int b = tid >> 5, o = tid & 31;
  float s = 0.f;
  for (int j = 0; j < 40; ++j) s += out_part[(b*40 + j)*32 + o];
  s = s > 0.f ? s : 0.f;
  float v = s * ow[o];
  v += __shfl_xor(v, 1); v += __shfl_xor(v, 2); v += __shfl_xor(v, 4);
  v += __shfl_xor(v, 8); v += __shfl_xor(v, 16);
  if (o == 0) out[b] = v + ob[0];
}

extern "C" void kernel_launch(void* const* d_in, const int* in_sizes, int n_in,
                              void* d_out, int out_size, void* d_ws, size_t ws_size,
                              hipStream_t stream){
  const float* x    = (const float*)d_in[0];
  const float* c1w  = (const float*)d_in[1];
  const float* c1b  = (const float*)d_in[2];
  const float* c2w  = (const float*)d_in[3];
  const float* c2b  = (const float*)d_in[4];
  const float* fcw  = (const float*)d_in[5];
  const float* fcb  = (const float*)d_in[6];
  const float* e1w  = (const float*)d_in[7];
  const float* e1b  = (const float*)d_in[8];
  const float* e2w  = (const float*)d_in[9];
  const float* e2b  = (const float*)d_in[10];
  const float* ow   = (const float*)d_in[11];
  const float* ob   = (const float*)d_in[12];

  char* ws = (char*)d_ws;
  size_t off = 0;
  auto alloc = [&](size_t bytes) -> void* {
    void* p = ws + off;
    off += (bytes + 255) & ~(size_t)255;
    return p;
  };
  u16*   z1t  = (u16*)  alloc((size_t)640*4608*2);
  u16*   wt2  = (u16*)  alloc(51200*2);
  u16*   fcwT = (u16*)  alloc(65536*2);
  u16*   z2g  = (u16*)  alloc((size_t)640*1024*2);
  float* e_f  = (float*)alloc(40960*4);
  u16*   e_b  = (u16*)  alloc(40960*2);
  float* Sg   = (float*)alloc(1024*4);
  u16*   Vt   = (u16*)  alloc((size_t)16*16384*2);
  float* c0   = (float*)alloc(1024*4);
  float* P5   = (float*)alloc(40960*4);
  float* P6   = (float*)alloc(40960*4);
  u16*   W2T0 = (u16*)  alloc(2048*2);
  u16*   W3St = (u16*)  alloc((size_t)16*4096*2);
  float* Q3c  = (float*)alloc((size_t)1638400*4);
  float* si2  = (float*)alloc((size_t)1638400*4);
  float* sj2  = (float*)alloc((size_t)1638400*4);
  float* sk2  = (float*)alloc((size_t)1638400*4);
  float* ssij = (float*)alloc(40960*4);
  float* ssik = (float*)alloc(40960*4);
  float* ssjk = (float*)alloc(40960*4);
  float* A4   = (float*)alloc(20480*4);
  float* A5   = (float*)alloc(20480*4);
  float* A6   = (float*)alloc(20480*4);
  float* A7   = (float*)alloc(512*4);
  float* A1p  = (float*)alloc((size_t)819200*4);
  float* A2t  = (float*)alloc((size_t)819200*4);
  float* Cc   = (float*)alloc((size_t)819200*4);
  float* op   = (float*)alloc(20480*4);
  (void)in_sizes; (void)n_in; (void)out_size; (void)ws_size;

  kconv1 <<<672, 256, 0, stream>>>(x, c1w, c1b, z1t, c2w, fcw, wt2, fcwT);
  kconv2m<<<640, 256, 0, stream>>>(z1t, wt2, c2b, z2g);
  kfc    <<<40,  256, 0, stream>>>(z2g, fcwT, fcb, e_f, e_b);
  kprep  <<<dim3(16,4), 256, 0, stream>>>(e_f, e1w, e1b, e2w, Sg, Vt, c0, P5, P6, W2T0, W3St);
  kpq    <<<640, 256, 0, stream>>>(e_b, W3St, P5, P6, c0, Q3c);
  kh01   <<<dim3(640,2), 256, 0, stream>>>(e_b, e_f, Vt, Q3c, si2, sj2, sk2);
  k5ar   <<<dim3(16,3,2), 256, 0, stream>>>(si2, sj2, ssij, ssik, ssjk);
  k5am   <<<dim3(16,2), 256, 0, stream>>>(ssij, ssik, ssjk, e2w, e2b, A4, A5, A6, A7);
  k5b    <<<dim3(640,3), 256, 0, stream>>>(si2, sj2, sk2, e2w, A4, A5, A6, A7, A1p, A2t, Cc);
  kh2    <<<640, 256, 0, stream>>>(e_b, e_f, Vt, Q3c, W2T0, A1p, A2t, Cc, op);
  k7     <<<1, 512, 0, stream>>>(op, ow, ob, (float*)d_out);
}

// Round 14
// 276.751 us; speedup vs baseline: 3.1997x; 1.0073x over previous
//
#include <hip/hip_runtime.h>
#include <hip/hip_bf16.h>

// UniqueEq3Net: conv stack -> e(640,64); t = e⊗e⊗e never materialized.
// Layer1 (transposed MFMA): h^T[o][k] = (B1⊙e_l)^T · U + Y0 + cadd.
// R14 = R13 + middle-kernel cleanup: ssik/ssjk computed in kh01's epilogue
// (register-resident si2/sj2 rows -> one shfl reduce), k5ar -> k5ij (ssij only,
// f4), k5am LDS-staged f4 weights. kh01/kh2 hot loops untouched.

typedef unsigned short u16;
typedef __attribute__((ext_vector_type(8))) short bf8_t;   // 8 bf16 (4 VGPRs)
typedef __attribute__((ext_vector_type(4))) float f4_t;

#define LSTR 72   // padded LDS row stride (u16): 144B rows, 16B-aligned

__device__ inline u16 f2bf(float f){
  union { float f; unsigned u; } v; v.f = f;
  unsigned r = v.u + 0x7fffu + ((v.u >> 16) & 1u);
  return (u16)(r >> 16);
}
__device__ inline float bflo(unsigned u){ union { unsigned x; float f; } v; v.x = u << 16; return v.f; }
__device__ inline float bfhi(unsigned u){ union { unsigned x; float f; } v; v.x = u & 0xffff0000u; return v.f; }
__device__ inline unsigned pack2(float a, float b){ return (unsigned)f2bf(a) | ((unsigned)f2bf(b) << 16); }
__device__ inline unsigned cvtpk(float lo, float hi){
  __hip_bfloat162 h2 = __float22bfloat162_rn(make_float2(lo, hi));
  union { __hip_bfloat162 h; unsigned u; } c; c.h = h2; return c.u;
}
__device__ inline void unpack8(bf8_t x, float* o){
  union { bf8_t v; unsigned u[4]; } q; q.v = x;
  #pragma unroll
  for (int p = 0; p < 4; ++p){ o[2*p] = bflo(q.u[p]); o[2*p+1] = bfhi(q.u[p]); }
}
__device__ inline f4_t shfl4x(f4_t v, int m){
  f4_t r;
  r[0] = __shfl_xor(v[0], m); r[1] = __shfl_xor(v[1], m);
  r[2] = __shfl_xor(v[2], m); r[3] = __shfl_xor(v[3], m);
  return r;
}

// ---------------- conv1 + pool -> z1t ; blocks >=640 do weight prep ----------------
__global__ __launch_bounds__(256) void kconv1(const float* __restrict__ x, const float* __restrict__ w1,
                                              const float* __restrict__ b1, u16* __restrict__ z1t,
                                              const float* __restrict__ w2, const float* __restrict__ fcw,
                                              u16* __restrict__ wt2, u16* __restrict__ fcwT){
  __shared__ float simg[784];
  int img = blockIdx.x, tid = threadIdx.x;
  if (img >= 640){
    int t = (img - 640)*256 + tid, stride = 32*256;
    for (int i = t; i < 51200; i += stride){
      int tap = i >> 11, rc = i & 2047, co = rc >> 5, ci = rc & 31;
      wt2[i] = f2bf(w2[co*800 + ci*25 + tap]);
    }
    for (int i = t; i < 65536; i += stride){
      int o = i >> 10, k = i & 1023;
      fcwT[i] = f2bf(fcw[k*64 + o]);
    }
    return;
  }
  for (int i = tid; i < 784; i += 256) simg[i] = x[img*784 + i];
  const int c = tid & 31;
  float wc[25];
  #pragma unroll
  for (int t = 0; t < 25; ++t) wc[t] = w1[c*25 + t];
  const float bb = b1[c];
  __syncthreads();
  #pragma unroll 2
  for (int it = 0; it < 18; ++it){
    int p = (tid >> 5) + it*8;
    int py = p / 12, px = p % 12;
    float patch[36];
    const float* sp = &simg[2*py*28 + 2*px];
    #pragma unroll
    for (int yy = 0; yy < 6; ++yy)
      #pragma unroll
      for (int xx = 0; xx < 6; ++xx) patch[yy*6+xx] = sp[yy*28+xx];
    float mx = -1e30f;
    #pragma unroll
    for (int sy = 0; sy < 2; ++sy)
    #pragma unroll
    for (int sx = 0; sx < 2; ++sx){
      float s = bb;
      #pragma unroll
      for (int dy = 0; dy < 5; ++dy)
        #pragma unroll
        for (int dx = 0; dx < 5; ++dx)
          s += patch[(sy+dy)*6 + sx+dx] * wc[dy*5+dx];
      mx = fmaxf(mx, s);
    }
    z1t[(size_t)img*4608 + p*32 + c] = f2bf(fmaxf(mx, 0.f));
  }
}

// ---------------- conv2 (MFMA, 25 shifted K=32 GEMMs) + pool -> z2g (640,1024) bf16 ----------------
__global__ __launch_bounds__(256) void kconv2m(const u16* __restrict__ z1t, const u16* __restrict__ wt2,
                                               const float* __restrict__ b2, u16* __restrict__ z2g){
  __shared__ __align__(16) u16 sz[4608];
  __shared__ __align__(16) u16 sz2[1024];
  int img = blockIdx.x, tid = threadIdx.x;
  for (int i = tid; i < 576; i += 256)
    ((uint4*)sz)[i] = ((const uint4*)(z1t + (size_t)img*4608))[i];
  __syncthreads();
  const int wave = tid >> 6, lane = tid & 63, l15 = lane & 15, quad = lane >> 4;
  const int y = wave*2 + (l15 >> 3), x = l15 & 7;
  f4_t acc[4];
  acc[0] = (f4_t){0.f,0.f,0.f,0.f}; acc[1] = acc[0]; acc[2] = acc[0]; acc[3] = acc[0];
  #pragma unroll
  for (int dy = 0; dy < 5; ++dy)
    #pragma unroll
    for (int dx = 0; dx < 5; ++dx){
      const int tap = dy*5 + dx;
      bf8_t af = *(const bf8_t*)&sz[((y+dy)*12 + (x+dx))*32 + quad*8];
      const u16* wp = wt2 + tap*2048 + l15*32 + quad*8;
      #pragma unroll
      for (int nt = 0; nt < 4; ++nt){
        bf8_t bf = *(const bf8_t*)(wp + nt*512);
        acc[nt] = __builtin_amdgcn_mfma_f32_16x16x32_bf16(af, bf, acc[nt], 0, 0, 0);
      }
    }
  #pragma unroll
  for (int nt = 0; nt < 4; ++nt){
    int co = nt*16 + l15;
    float v0 = fmaxf(acc[nt][0], acc[nt][1]);
    float v1 = fmaxf(acc[nt][2], acc[nt][3]);
    v0 = fmaxf(v0, __shfl_xor(v0, 32));
    v1 = fmaxf(v1, __shfl_xor(v1, 32));
    if (quad < 2){
      float bb = b2[co];
      sz2[co*16 + wave*4 + quad*2 + 0] = f2bf(fmaxf(v0 + bb, 0.f));
      sz2[co*16 + wave*4 + quad*2 + 1] = f2bf(fmaxf(v1 + bb, 0.f));
    }
  }
  __syncthreads();
  if (tid < 128) ((uint4*)(z2g + (size_t)img*1024))[tid] = ((const uint4*)sz2)[tid];
}

// ---------------- fc: e = relu(z2g @ fcw + fcb) ----------------
__global__ __launch_bounds__(256) void kfc(const u16* __restrict__ z2g, const u16* __restrict__ fcwT,
                                           const float* __restrict__ fcb,
                                           float* __restrict__ e_f, u16* __restrict__ e_b){
  __shared__ __align__(16) u16 sA[16*1032];
  int img0 = blockIdx.x*16, tid = threadIdx.x;
  for (int i = tid; i < 2048; i += 256){
    int row = i >> 7, c16 = i & 127;
    ((uint4*)(sA + row*1032))[c16] = ((const uint4*)(z2g + (size_t)(img0+row)*1024))[c16];
  }
  __syncthreads();
  const int wave = tid >> 6, lane = tid & 63, l15 = lane & 15, quad = lane >> 4;
  const int o = wave*16 + l15;
  f4_t acc = (f4_t){0.f,0.f,0.f,0.f};
  #pragma unroll 8
  for (int ks = 0; ks < 32; ++ks){
    bf8_t af = *(const bf8_t*)&sA[l15*1032 + ks*32 + quad*8];
    bf8_t bf = *(const bf8_t*)(fcwT + (size_t)o*1024 + ks*32 + quad*8);
    acc = __builtin_amdgcn_mfma_f32_16x16x32_bf16(af, bf, acc, 0, 0, 0);
  }
  const float bb = fcb[o];
  #pragma unroll
  for (int r = 0; r < 4; ++r){
    int img = img0 + quad*4 + r;
    float v = fmaxf(acc[r] + bb, 0.f);
    e_f[img*64 + o] = v;
    e_b[img*64 + o] = f2bf(v);
  }
}

// ---------------- per-b precompute, grid (16,4) ----------------
__global__ __launch_bounds__(256) void kprep(const float* __restrict__ e_f, const float* __restrict__ e1w,
    const float* __restrict__ e1b, const float* __restrict__ e2w,
    float* __restrict__ Sg, u16* __restrict__ Vt, float* __restrict__ c0,
    float* __restrict__ P5, float* __restrict__ P6, u16* __restrict__ W2T0,
    u16* __restrict__ W3St){
  int b = blockIdx.x, ph = blockIdx.y, tid = threadIdx.x;
  __shared__ float se[2560];
  __shared__ float S[64], S2[64], S3[64];
  for (int i = tid; i < 2560; i += 256) se[i] = e_f[b*2560 + i];
  __syncthreads();
  if (tid < 64){
    float s = 0.f;
    for (int i = 0; i < 40; ++i) s += se[i*64 + tid];
    S[tid] = s; S2[tid] = s*s; S3[tid] = s*s*s;
    if (ph == 0) Sg[b*64 + tid] = s;
  }
  __syncthreads();
  {
    const int m = ph;
    for (int idx = tid; idx < 4096; idx += 256){
      int o = idx >> 6, d = idx & 63;
      float v;
      if (m == 0)      v = e1w[d*64 + o];
      else if (m == 1) v = S[d] * e1w[4096  + d*64 + o];
      else if (m == 2) v = S[d] * e1w[8192  + d*64 + o];
      else             v = S2[d] * e1w[16384 + d*64 + o];
      Vt[(size_t)b*16384 + m*4096 + idx] = f2bf(v);
    }
  }
  if (ph == 0){
    if (tid < 64){
      float a = e1b[tid];
      for (int d = 0; d < 64; ++d) a += S3[d] * e1w[7*4096 + d*64 + tid];
      c0[b*64 + tid] = a;
    }
  } else if (ph == 1){
    for (int idx = tid; idx < 4096; idx += 256){
      int o = idx >> 6, d = idx & 63;
      W3St[(size_t)b*4096 + idx] = f2bf(S[d] * e1w[3*4096 + d*64 + o]);
    }
  } else {
    int lo = (ph == 2) ? 0 : 1280, hi = lo + 1280;
    for (int idx = lo + tid; idx < hi; idx += 256){
      int j = idx >> 6, o = idx & 63;
      float a5 = 0.f, a6 = 0.f;
      for (int d = 0; d < 64; ++d){
        float es = se[j*64 + d] * S2[d];
        a5 += es * e1w[5*4096 + d*64 + o];
        a6 += es * e1w[6*4096 + d*64 + o];
      }
      P5[(b*40+j)*64 + o] = a5;
      P6[(b*40+j)*64 + o] = a6;
    }
    if (ph == 3 && b == 0){
      for (int idx = tid; idx < 2048; idx += 256){
        int o = idx >> 6, d = idx & 63;
        W2T0[o*64 + d] = f2bf(e2w[d*32 + o]);
      }
    }
  }
}

// ---------------- kpq: P[i] tile in LDS AND Q3c[b,i,:,:] via MFMA ----------------
__global__ __launch_bounds__(256) void kpq(const u16* __restrict__ e_b, const u16* __restrict__ W3St,
    const float* __restrict__ P5, const float* __restrict__ P6, const float* __restrict__ c0,
    float* __restrict__ Q3c){
  __shared__ __align__(16) u16 sP[48*LSTR];
  __shared__ __align__(16) u16 sW[64*LSTR];
  int blk = blockIdx.x, b = blk/40, i = blk%40, tid = threadIdx.x;
  const int wave = tid >> 6, lane = tid & 63, l15 = lane & 15, quad = lane >> 4;
  for (int idx = tid; idx < 2048; idx += 256){
    int o = idx >> 5, c = idx & 31;
    ((unsigned*)(sW + o*LSTR))[c] = ((const unsigned*)(W3St + (size_t)b*4096))[idx];
  }
  const unsigned* eb32 = (const unsigned*)(e_b + (size_t)b*2560);
  const unsigned* el = eb32 + i*32;
  #pragma unroll
  for (int it = 0; it < 6; ++it){
    int idx = tid + it*256;
    int k = idx >> 5, d2 = idx & 31;
    unsigned pv = 0;
    if (k < 40){
      unsigned ul = el[d2], uk = eb32[k*32 + d2];
      pv = pack2(bflo(ul)*bflo(uk), bfhi(ul)*bfhi(uk));
    }
    ((unsigned*)(sP + k*LSTR))[d2] = pv;
  }
  __syncthreads();
  bf8_t wf[2];
  #pragma unroll
  for (int ks = 0; ks < 2; ++ks)
    wf[ks] = *(const bf8_t*)&sW[(wave*16 + l15)*LSTR + ks*32 + quad*8];
  f4_t acc[3];
  #pragma unroll
  for (int n = 0; n < 3; ++n){
    f4_t a = (f4_t){0.f,0.f,0.f,0.f};
    #pragma unroll
    for (int ks = 0; ks < 2; ++ks){
      bf8_t pkf = *(const bf8_t*)&sP[(n*16 + l15)*LSTR + ks*32 + quad*8];
      a = __builtin_amdgcn_mfma_f32_16x16x32_bf16(wf[ks], pkf, a, 0, 0, 0);
    }
    acc[n] = a;
  }
  const int obase = wave*16 + quad*4;
  f4_t p6v = *(const f4_t*)&P6[(b*40+i)*64 + obase];
  f4_t c0v = *(const f4_t*)&c0[b*64 + obase];
  #pragma unroll
  for (int n = 0; n < 3; ++n){
    int j = n*16 + l15;
    if (j < 40){
      f4_t p5v = *(const f4_t*)&P5[(b*40+j)*64 + obase];
      f4_t outv = acc[n] + p5v + p6v + c0v;
      *(f4_t*)&Q3c[((size_t)((b*40+i)*40 + j))*64 + obase] = outv;
    }
  }
}

// ---------------- layer-1 reduction passes (modes 0 & 1); +ssik/ssjk epilogue ----------------
__global__ __launch_bounds__(256, 4) void kh01(
    const u16* __restrict__ e_b, const float* __restrict__ e_f,
    const u16* __restrict__ Vt, const float* __restrict__ Q3c,
    float* __restrict__ si2, float* __restrict__ sj2, float* __restrict__ sk2,
    float* __restrict__ ssik, float* __restrict__ ssjk)
{
  __shared__ __align__(16) char smem[25344];
  u16*   sU  = (u16*)smem;             // dead after setup
  u16*   sB1 = (u16*)(smem + 6912);    // dead after setup
  u16*   sB0 = (u16*)(smem + 16128);
  float* sUf = (float*)smem;           // aliases sU+sB1
  const int tid = threadIdx.x;
  const int b = blockIdx.x / 40, fix = blockIdx.x % 40;
  const int mode = blockIdx.y;
  const int wave = tid >> 6, lane = tid & 63, l15 = lane & 15, quad = lane >> 4;
  const f4_t z4 = (f4_t){0.f,0.f,0.f,0.f};

  for (int idx = tid; idx < 1536; idx += 256){
    int r = idx >> 5, c = idx & 31;
    unsigned v = (r < 40) ? ((const unsigned*)e_b)[(b*40 + r)*32 + c] : 0u;
    ((unsigned*)(sU + r*LSTR))[c] = v;
  }
  float efr[10];
  #pragma unroll
  for (int t = 0; t < 10; ++t) efr[t] = e_f[b*2560 + tid + t*256];
  const unsigned* eg = (const unsigned*)(e_b + (size_t)(b*40 + fix)*64);
  const unsigned* Vb = (const unsigned*)(Vt + (size_t)b*16384);
  for (int idx = tid; idx < 2048; idx += 256){
    int o = idx >> 5, d2 = idx & 31;
    unsigned eu = eg[d2];
    unsigned v0 = Vb[o*32 + d2];
    unsigned vA = Vb[(2-mode)*2048 + o*32 + d2];
    unsigned vB = Vb[(1+mode)*2048 + o*32 + d2];
    unsigned v3 = Vb[3*2048 + o*32 + d2];
    float e0 = bflo(eu), e1 = bfhi(eu);
    ((unsigned*)(sB1 + o*LSTR))[d2] = pack2(e0*bflo(v0)+bflo(vA), e1*bfhi(v0)+bfhi(vA));
    ((unsigned*)(sB0 + o*LSTR))[d2] = pack2(e0*bflo(vB)+bflo(v3), e1*bfhi(vB)+bfhi(v3));
  }
  __syncthreads();

  f4_t b1v[4];
  bf8_t ua[3][2];
  f4_t Y0[3];
  {
    bf8_t b0f[2], b1f[2];
    float tmp[8];
    #pragma unroll
    for (int ks = 0; ks < 2; ++ks){
      b1f[ks] = *(const bf8_t*)&sB1[(wave*16 + l15)*LSTR + ks*32 + quad*8];
      b0f[ks] = *(const bf8_t*)&sB0[(wave*16 + l15)*LSTR + ks*32 + quad*8];
      unpack8(b1f[ks], tmp);
      b1v[2*ks]   = (f4_t){tmp[0],tmp[1],tmp[2],tmp[3]};
      b1v[2*ks+1] = (f4_t){tmp[4],tmp[5],tmp[6],tmp[7]};
    }
    #pragma unroll
    for (int n = 0; n < 3; ++n){
      f4_t a = z4;
      #pragma unroll
      for (int ks = 0; ks < 2; ++ks){
        ua[n][ks] = *(const bf8_t*)&sU[(n*16 + l15)*LSTR + ks*32 + quad*8];
        a = __builtin_amdgcn_mfma_f32_16x16x32_bf16(b0f[ks], ua[n][ks], a, 0, 0, 0);
      }
      Y0[n] = a;
    }
  }
  __syncthreads();
  #pragma unroll
  for (int t = 0; t < 10; ++t) sUf[tid + t*256] = efr[t];
  __syncthreads();

  const int obase = wave*16 + quad*4;
  const float km = (l15 < 8) ? 1.f : 0.f;
  const f4_t km4 = (f4_t){km, km, km, km};
  f4_t sacc[3];
  sacc[0] = z4; sacc[1] = z4; sacc[2] = z4;

  // pointer-carried streams (no per-iter 64-bit address mul)
  const int qstride = mode ? 64 : 2560;
  const float* qp = Q3c + (size_t)b*102400 + (mode ? (size_t)fix*2560 : (size_t)fix*64) + obase;
  float* skp = sk2 + ((size_t)(b*40)*40 + fix)*64 + obase;   // mode0 only; stride 2560
  const float* ep = sUf + quad*8;

  f4_t cadd_n = *(const f4_t*)qp; qp += qstride;
  #pragma unroll 2
  for (int l = 0; l < 40; ++l){
    f4_t cadd = cadd_n;
    if (l < 39){ cadd_n = *(const f4_t*)qp; qp += qstride; }
    f4_t p00 = b1v[0] * *(const f4_t*)(ep);
    f4_t p01 = b1v[1] * *(const f4_t*)(ep + 4);
    f4_t p10 = b1v[2] * *(const f4_t*)(ep + 32);
    f4_t p11 = b1v[3] * *(const f4_t*)(ep + 36);
    ep += 64;
    union { bf8_t v; unsigned u[4]; } m0, m1;
    m0.u[0] = cvtpk(p00[0], p00[1]); m0.u[1] = cvtpk(p00[2], p00[3]);
    m0.u[2] = cvtpk(p01[0], p01[1]); m0.u[3] = cvtpk(p01[2], p01[3]);
    m1.u[0] = cvtpk(p10[0], p10[1]); m1.u[1] = cvtpk(p10[2], p10[3]);
    m1.u[2] = cvtpk(p11[0], p11[1]); m1.u[3] = cvtpk(p11[2], p11[3]);
    f4_t khs = z4;
    #pragma unroll
    for (int n = 0; n < 3; ++n){
      f4_t a = Y0[n];
      a = __builtin_amdgcn_mfma_f32_16x16x32_bf16(m0.v, ua[n][0], a, 0, 0, 0);
      a = __builtin_amdgcn_mfma_f32_16x16x32_bf16(m1.v, ua[n][1], a, 0, 0, 0);
      f4_t h = __builtin_elementwise_max(a + cadd, z4);
      sacc[n] += h;                         // k>=40 garbage: masked at reductions
      if (mode == 0) khs += (n == 2) ? h * km4 : h;
    }
    if (mode == 0){
      khs += shfl4x(khs, 1);
      khs += shfl4x(khs, 2);
      khs += shfl4x(khs, 4);
      khs += shfl4x(khs, 8);
      if (l15 == 0) *(f4_t*)skp = khs;
      skp += 2560;
    }
  }
  float* dst = mode ? sj2 : si2;
  #pragma unroll
  for (int n = 0; n < 3; ++n){
    int k = n*16 + l15;
    if (k < 40)
      *(f4_t*)&dst[((size_t)((b*40 + fix)*40 + k))*64 + obase] = sacc[n];
  }
  // epilogue: ssik (mode0) / ssjk (mode1) = Σ_k of this block's si2/sj2 row
  f4_t t4 = sacc[0] + sacc[1] + sacc[2]*km4;
  t4 += shfl4x(t4, 1); t4 += shfl4x(t4, 2);
  t4 += shfl4x(t4, 4); t4 += shfl4x(t4, 8);
  float* sred = mode ? ssjk : ssik;
  if (l15 == 0) *(f4_t*)&sred[b*2560 + fix*64 + obase] = t4;
}

// ---------------- k5ij: ssij[b,k,d] = Σ_j si2[b,j,k,d], f4, grid (16,2) ----------------
__global__ __launch_bounds__(256) void k5ij(const float* __restrict__ si2, float* __restrict__ ssij){
  int b = blockIdx.x, half = blockIdx.y, tid = threadIdx.x;
  const f4_t z4 = (f4_t){0.f,0.f,0.f,0.f};
  int base = half*320;
  for (int idx = base + tid; idx < base + 320; idx += 256){
    f4_t a = z4;
    const f4_t* p = (const f4_t*)&si2[(size_t)(b*40)*2560] + idx;  // idx = k*16 + d4
    #pragma unroll 4
    for (int j = 0; j < 40; ++j){ a += *p; p += 640; }
    ((f4_t*)&ssij[b*2560])[idx] = a;
  }
}

// ---------------- k5am: A4/A5/A6/A7 matmuls, LDS f4 weights, grid (16,2) ----------------
__global__ __launch_bounds__(256) void k5am(const float* __restrict__ ssij, const float* __restrict__ ssik,
    const float* __restrict__ ssjk, const float* __restrict__ e2w, const float* __restrict__ e2b,
    float* __restrict__ A4, float* __restrict__ A5, float* __restrict__ A6, float* __restrict__ A7){
  int b = blockIdx.x, half = blockIdx.y, tid = threadIdx.x;
  __shared__ __align__(16) f4_t s1[640], s2[640];
  __shared__ __align__(16) f4_t w1t[32*17], w2t[32*17];
  __shared__ float ss2[64];
  const int o = tid & 31, rb = tid >> 5;
  if (half == 0){
    for (int i = tid; i < 640; i += 256) s1[i] = ((const f4_t*)&ssij[b*2560])[i];
    for (int idx = tid; idx < 512; idx += 256){
      int oo = idx >> 4, d4 = idx & 15;
      f4_t w;
      #pragma unroll
      for (int r = 0; r < 4; ++r) w[r] = e2w[4*2048 + (4*d4+r)*32 + oo];
      w1t[oo*17 + d4] = w;
    }
    __syncthreads();
    if (tid < 64){
      const float* s1f = (const float*)s1;
      float a = 0.f;
      for (int k = 0; k < 40; ++k) a += s1f[k*64 + tid];
      ss2[tid] = a;
    }
    __syncthreads();
    float acc[5] = {0.f,0.f,0.f,0.f,0.f};
    #pragma unroll 4
    for (int d4 = 0; d4 < 16; ++d4){
      f4_t w = w1t[o*17 + d4];
      #pragma unroll
      for (int it = 0; it < 5; ++it){
        f4_t s = s1[(rb + 8*it)*16 + d4];
        acc[it] += s[0]*w[0] + s[1]*w[1] + s[2]*w[2] + s[3]*w[3];
      }
    }
    #pragma unroll
    for (int it = 0; it < 5; ++it)
      A4[(b*40 + rb + 8*it)*32 + o] = acc[it];
    if (tid < 32){
      float a = e2b[tid];
      for (int d = 0; d < 64; ++d) a += ss2[d] * e2w[7*2048 + d*32 + tid];
      A7[b*32 + tid] = a;
    }
  } else {
    for (int i = tid; i < 640; i += 256){
      s1[i] = ((const f4_t*)&ssik[b*2560])[i];
      s2[i] = ((const f4_t*)&ssjk[b*2560])[i];
    }
    for (int idx = tid; idx < 512; idx += 256){
      int oo = idx >> 4, d4 = idx & 15;
      f4_t w5, w6;
      #pragma unroll
      for (int r = 0; r < 4; ++r){
        w5[r] = e2w[5*2048 + (4*d4+r)*32 + oo];
        w6[r] = e2w[6*2048 + (4*d4+r)*32 + oo];
      }
      w1t[oo*17 + d4] = w5;
      w2t[oo*17 + d4] = w6;
    }
    __syncthreads();
    float a5[5] = {0.f,0.f,0.f,0.f,0.f}, a6[5] = {0.f,0.f,0.f,0.f,0.f};
    #pragma unroll 4
    for (int d4 = 0; d4 < 16; ++d4){
      f4_t w5 = w1t[o*17 + d4], w6 = w2t[o*17 + d4];
      #pragma unroll
      for (int it = 0; it < 5; ++it){
        f4_t sa = s1[(rb + 8*it)*16 + d4];
        f4_t sb = s2[(rb + 8*it)*16 + d4];
        a5[it] += sa[0]*w5[0] + sa[1]*w5[1] + sa[2]*w5[2] + sa[3]*w5[3];
        a6[it] += sb[0]*w6[0] + sb[1]*w6[1] + sb[2]*w6[2] + sb[3]*w6[3];
      }
    }
    #pragma unroll
    for (int it = 0; it < 5; ++it){
      A5[(b*40 + rb + 8*it)*32 + o] = a5[it];
      A6[(b*40 + rb + 8*it)*32 + o] = a6[it];
    }
  }
}

// ---------------- big addends, f4-vectorized ----------------
__global__ __launch_bounds__(256) void k5b(const float* __restrict__ si2, const float* __restrict__ sj2,
    const float* __restrict__ sk2, const float* __restrict__ e2w,
    const float* __restrict__ A4, const float* __restrict__ A5, const float* __restrict__ A6,
    const float* __restrict__ A7,
    float* __restrict__ A1p, float* __restrict__ A2t, float* __restrict__ Cc){
  int which = blockIdx.y;
  int blk = blockIdx.x, b = blk/40, f = blk%40, tid = threadIdx.x;
  __shared__ __align__(16) f4_t ssrc[640];
  __shared__ __align__(16) f4_t swt[32*17];
  const float* S = (which == 0) ? si2 : (which == 1) ? sj2 : sk2;
  int wop = which + 1;
  const f4_t* Sg4 = (const f4_t*)&S[(size_t)(b*40+f)*2560];
  for (int idx = tid; idx < 640; idx += 256) ssrc[idx] = Sg4[idx];
  for (int idx = tid; idx < 512; idx += 256){
    int o = idx >> 4, d4 = idx & 15;
    f4_t w;
    #pragma unroll
    for (int r = 0; r < 4; ++r) w[r] = e2w[wop*2048 + (4*d4+r)*32 + o];
    swt[o*17 + d4] = w;
  }
  __syncthreads();
  const int o = tid & 31, rb = tid >> 5;
  float acc[5] = {0.f, 0.f, 0.f, 0.f, 0.f};
  #pragma unroll 4
  for (int d4 = 0; d4 < 16; ++d4){
    f4_t w = swt[o*17 + d4];
    #pragma unroll
    for (int it = 0; it < 5; ++it){
      f4_t s = ssrc[(rb + 8*it)*16 + d4];
      acc[it] += s[0]*w[0] + s[1]*w[1] + s[2]*w[2] + s[3]*w[3];
    }
  }
  #pragma unroll
  for (int it = 0; it < 5; ++it){
    int r = rb + 8*it;
    size_t oi = ((size_t)(b*40+f)*40 + r)*32 + o;
    float a = acc[it];
    if (which == 0)      A1p[oi] = a + A4[(b*40+r)*32 + o];
    else if (which == 1) A2t[oi] = a;
    else                 Cc[oi]  = a + A5[(b*40+r)*32 + o] + A6[(b*40+f)*32 + o] + A7[b*32 + o];
  }
}

// ---------------- mode2: layer-2; pointer-carried streams; sH dbuf over sB1/sB0 ----------------
__global__ __launch_bounds__(256, 3) void kh2(
    const u16* __restrict__ e_b, const float* __restrict__ e_f,
    const u16* __restrict__ Vt, const float* __restrict__ Q3c, const u16* __restrict__ W2T0,
    const float* __restrict__ A1p, const float* __restrict__ A2t, const float* __restrict__ Cc,
    float* __restrict__ out_part)
{
  __shared__ __align__(16) char smem[30080];
  u16*   sB1 = (u16*)smem;                  // loop: sH buf0
  u16*   sB0 = (u16*)(smem + 9216);         // loop: sH buf1
  u16*   sU  = (u16*)(smem + 18432);        // dead after setup
  u16*   sW2 = (u16*)(smem + 18432 + 6912); // dead after setup
  float* sUf = (float*)(smem + 18432);      // aliases sU+sW2
  float* soacc = (float*)(smem + 29952);
  const int tid = threadIdx.x;
  const int b = blockIdx.x / 40, fix = blockIdx.x % 40;   // fix = j
  const int wave = tid >> 6, lane = tid & 63, l15 = lane & 15, quad = lane >> 4;
  const f4_t z4 = (f4_t){0.f,0.f,0.f,0.f};

  for (int idx = tid; idx < 1536; idx += 256){
    int r = idx >> 5, c = idx & 31;
    unsigned v = (r < 40) ? ((const unsigned*)e_b)[(b*40 + r)*32 + c] : 0u;
    ((unsigned*)(sU + r*LSTR))[c] = v;
  }
  float efr[10];
  #pragma unroll
  for (int t = 0; t < 10; ++t) efr[t] = e_f[b*2560 + tid + t*256];
  const unsigned* eg = (const unsigned*)(e_b + (size_t)(b*40 + fix)*64);
  const unsigned* Vb = (const unsigned*)(Vt + (size_t)b*16384);
  for (int idx = tid; idx < 2048; idx += 256){
    int o = idx >> 5, d2 = idx & 31;
    unsigned eu = eg[d2];
    unsigned v0 = Vb[o*32 + d2];
    unsigned vA = Vb[2*2048 + o*32 + d2];
    unsigned vB = Vb[1*2048 + o*32 + d2];
    unsigned v3 = Vb[3*2048 + o*32 + d2];
    float e0 = bflo(eu), e1 = bfhi(eu);
    ((unsigned*)(sB1 + o*LSTR))[d2] = pack2(e0*bflo(v0)+bflo(vA), e1*bfhi(v0)+bfhi(vA));
    ((unsigned*)(sB0 + o*LSTR))[d2] = pack2(e0*bflo(vB)+bflo(v3), e1*bfhi(vB)+bfhi(v3));
  }
  for (int idx = tid; idx < 1024; idx += 256){
    int o = idx >> 5, c = idx & 31;
    ((unsigned*)(sW2 + o*LSTR))[c] = ((const unsigned*)W2T0)[idx];
  }
  if (tid < 32) soacc[tid] = 0.f;
  __syncthreads();

  f4_t b1v[4];
  bf8_t ua[3][2], wfA[2][2];
  f4_t Y0[3];
  {
    bf8_t b0f[2], b1f[2];
    float tmp[8];
    #pragma unroll
    for (int ks = 0; ks < 2; ++ks){
      b1f[ks] = *(const bf8_t*)&sB1[(wave*16 + l15)*LSTR + ks*32 + quad*8];
      b0f[ks] = *(const bf8_t*)&sB0[(wave*16 + l15)*LSTR + ks*32 + quad*8];
      unpack8(b1f[ks], tmp);
      b1v[2*ks]   = (f4_t){tmp[0],tmp[1],tmp[2],tmp[3]};
      b1v[2*ks+1] = (f4_t){tmp[4],tmp[5],tmp[6],tmp[7]};
      #pragma unroll
      for (int m = 0; m < 2; ++m)
        wfA[m][ks] = *(const bf8_t*)&sW2[(m*16 + l15)*LSTR + ks*32 + quad*8];
    }
    #pragma unroll
    for (int n = 0; n < 3; ++n){
      f4_t a = z4;
      #pragma unroll
      for (int ks = 0; ks < 2; ++ks){
        ua[n][ks] = *(const bf8_t*)&sU[(n*16 + l15)*LSTR + ks*32 + quad*8];
        a = __builtin_amdgcn_mfma_f32_16x16x32_bf16(b0f[ks], ua[n][ks], a, 0, 0, 0);
      }
      Y0[n] = a;
    }
  }
  __syncthreads();   // setup reads done (sB1/sB0/sU/sW2 all dead)
  #pragma unroll
  for (int t = 0; t < 10; ++t) sUf[tid + t*256] = efr[t];
  __syncthreads();

  const int obase = wave*16 + quad*4;
  const int o2b   = quad*4;
  const int kme   = wave*16 + l15;
  const int kmc   = kme < 40 ? kme : 39;
  const bool kval = (kme < 40) & (wave < 3);
  f4_t pa1[2], psum[2];
  psum[0] = z4; psum[1] = z4;
  if (wave < 3){
    #pragma unroll
    for (int m = 0; m < 2; ++m)
      pa1[m] = *(const f4_t*)&A1p[((size_t)((b*40 + fix)*40 + kmc))*32 + m*16 + o2b];
  }

  // pointer-carried streams
  const float* qp  = Q3c + (size_t)b*102400 + (size_t)fix*64 + obase;        // stride 2560
  const float* a2p = A2t + ((size_t)b*1600 + kmc)*32 + o2b;                  // stride 1280
  const float* ccp = Cc  + ((size_t)b*1600 + fix)*32 + o2b;                  // stride 1280
  const float* ep  = sUf + quad*8;

  f4_t cadd_n = *(const f4_t*)qp; qp += 2560;
  #pragma unroll 2
  for (int l = 0; l < 40; ++l){
    f4_t cadd = cadd_n;
    if (l < 39){ cadd_n = *(const f4_t*)qp; qp += 2560; }
    f4_t a2v[2], ccv[2];
    if (wave < 3){
      a2v[0] = *(const f4_t*)(a2p);      a2v[1] = *(const f4_t*)(a2p + 16);
      ccv[0] = *(const f4_t*)(ccp);      ccv[1] = *(const f4_t*)(ccp + 16);
    }
    a2p += 1280; ccp += 1280;
    f4_t p00 = b1v[0] * *(const f4_t*)(ep);
    f4_t p01 = b1v[1] * *(const f4_t*)(ep + 4);
    f4_t p10 = b1v[2] * *(const f4_t*)(ep + 32);
    f4_t p11 = b1v[3] * *(const f4_t*)(ep + 36);
    ep += 64;
    union { bf8_t v; unsigned u[4]; } m0, m1;
    m0.u[0] = cvtpk(p00[0], p00[1]); m0.u[1] = cvtpk(p00[2], p00[3]);
    m0.u[2] = cvtpk(p01[0], p01[1]); m0.u[3] = cvtpk(p01[2], p01[3]);
    m1.u[0] = cvtpk(p10[0], p10[1]); m1.u[1] = cvtpk(p10[2], p10[3]);
    m1.u[2] = cvtpk(p11[0], p11[1]); m1.u[3] = cvtpk(p11[2], p11[3]);
    u16* Hb = (u16*)(smem + (l & 1)*9216);
    #pragma unroll
    for (int n = 0; n < 3; ++n){
      f4_t a = Y0[n];
      a = __builtin_amdgcn_mfma_f32_16x16x32_bf16(m0.v, ua[n][0], a, 0, 0, 0);
      a = __builtin_amdgcn_mfma_f32_16x16x32_bf16(m1.v, ua[n][1], a, 0, 0, 0);
      f4_t h = __builtin_elementwise_max(a + cadd, z4);   // k>=40 rows masked at psum
      uint2 pw;
      pw.x = cvtpk(h[0], h[1]);
      pw.y = cvtpk(h[2], h[3]);
      *(uint2*)&Hb[(n*16 + l15)*LSTR + obase] = pw;
    }
    __syncthreads();
    if (wave < 3){
      bf8_t hB[2];
      #pragma unroll
      for (int ks = 0; ks < 2; ++ks)
        hB[ks] = *(const bf8_t*)&Hb[(wave*16 + l15)*LSTR + ks*32 + quad*8];
      #pragma unroll
      for (int m = 0; m < 2; ++m){
        f4_t y = z4;
        y = __builtin_amdgcn_mfma_f32_16x16x32_bf16(wfA[m][0], hB[0], y, 0, 0, 0);
        y = __builtin_amdgcn_mfma_f32_16x16x32_bf16(wfA[m][1], hB[1], y, 0, 0, 0);
        if (kval){
          f4_t v = y + pa1[m] + a2v[m] + ccv[m];
          psum[m] += __builtin_elementwise_max(v, z4);
        }
      }
    }
  }

  if (wave < 3){
    #pragma unroll
    for (int m = 0; m < 2; ++m){
      f4_t v = psum[m];
      v += shfl4x(v, 1); v += shfl4x(v, 2); v += shfl4x(v, 4); v += shfl4x(v, 8);
      if (l15 == 0){
        #pragma unroll
        for (int r = 0; r < 4; ++r) atomicAdd(&soacc[m*16 + o2b + r], v[r]);
      }
    }
  }
  __syncthreads();
  if (tid < 32) out_part[(b*40 + fix)*32 + tid] = soacc[tid];
}

// ---------------- final: sum_j out_part, relu, dot out_w (parallel) ----------------
__global__ __launch_bounds__(512) void k7(const float* __restrict__ out_part, const float* __restrict__ ow,
                                          const float* __restrict__ ob, float* __restrict__ out){
  int tid = threadIdx.x;
  int b = tid >> 5, o = tid & 31;
  float s = 0.f;
  for (int j = 0; j < 40; ++j) s += out_part[(b*40 + j)*32 + o];
  s = s > 0.f ? s : 0.f;
  float v = s * ow[o];
  v += __shfl_xor(v, 1); v += __shfl_xor(v, 2); v += __shfl_xor(v, 4);
  v += __shfl_xor(v, 8); v += __shfl_xor(v, 16);
  if (o == 0) out[b] = v + ob[0];
}

extern "C" void kernel_launch(void* const* d_in, const int* in_sizes, int n_in,
                              void* d_out, int out_size, void* d_ws, size_t ws_size,
                              hipStream_t stream){
  const float* x    = (const float*)d_in[0];
  const float* c1w  = (const float*)d_in[1];
  const float* c1b  = (const float*)d_in[2];
  const float* c2w  = (const float*)d_in[3];
  const float* c2b  = (const float*)d_in[4];
  const float* fcw  = (const float*)d_in[5];
  const float* fcb  = (const float*)d_in[6];
  const float* e1w  = (const float*)d_in[7];
  const float* e1b  = (const float*)d_in[8];
  const float* e2w  = (const float*)d_in[9];
  const float* e2b  = (const float*)d_in[10];
  const float* ow   = (const float*)d_in[11];
  const float* ob   = (const float*)d_in[12];

  char* ws = (char*)d_ws;
  size_t off = 0;
  auto alloc = [&](size_t bytes) -> void* {
    void* p = ws + off;
    off += (bytes + 255) & ~(size_t)255;
    return p;
  };
  u16*   z1t  = (u16*)  alloc((size_t)640*4608*2);
  u16*   wt2  = (u16*)  alloc(51200*2);
  u16*   fcwT = (u16*)  alloc(65536*2);
  u16*   z2g  = (u16*)  alloc((size_t)640*1024*2);
  float* e_f  = (float*)alloc(40960*4);
  u16*   e_b  = (u16*)  alloc(40960*2);
  float* Sg   = (float*)alloc(1024*4);
  u16*   Vt   = (u16*)  alloc((size_t)16*16384*2);
  float* c0   = (float*)alloc(1024*4);
  float* P5   = (float*)alloc(40960*4);
  float* P6   = (float*)alloc(40960*4);
  u16*   W2T0 = (u16*)  alloc(2048*2);
  u16*   W3St = (u16*)  alloc((size_t)16*4096*2);
  float* Q3c  = (float*)alloc((size_t)1638400*4);
  float* si2  = (float*)alloc((size_t)1638400*4);
  float* sj2  = (float*)alloc((size_t)1638400*4);
  float* sk2  = (float*)alloc((size_t)1638400*4);
  float* ssij = (float*)alloc(40960*4);
  float* ssik = (float*)alloc(40960*4);
  float* ssjk = (float*)alloc(40960*4);
  float* A4   = (float*)alloc(20480*4);
  float* A5   = (float*)alloc(20480*4);
  float* A6   = (float*)alloc(20480*4);
  float* A7   = (float*)alloc(512*4);
  float* A1p  = (float*)alloc((size_t)819200*4);
  float* A2t  = (float*)alloc((size_t)819200*4);
  float* Cc   = (float*)alloc((size_t)819200*4);
  float* op   = (float*)alloc(20480*4);
  (void)in_sizes; (void)n_in; (void)out_size; (void)ws_size;

  kconv1 <<<672, 256, 0, stream>>>(x, c1w, c1b, z1t, c2w, fcw, wt2, fcwT);
  kconv2m<<<640, 256, 0, stream>>>(z1t, wt2, c2b, z2g);
  kfc    <<<40,  256, 0, stream>>>(z2g, fcwT, fcb, e_f, e_b);
  kprep  <<<dim3(16,4), 256, 0, stream>>>(e_f, e1w, e1b, e2w, Sg, Vt, c0, P5, P6, W2T0, W3St);
  kpq    <<<640, 256, 0, stream>>>(e_b, W3St, P5, P6, c0, Q3c);
  kh01   <<<dim3(640,2), 256, 0, stream>>>(e_b, e_f, Vt, Q3c, si2, sj2, sk2, ssik, ssjk);
  k5ij   <<<dim3(16,2), 256, 0, stream>>>(si2, ssij);
  k5am   <<<dim3(16,2), 256, 0, stream>>>(ssij, ssik, ssjk, e2w, e2b, A4, A5, A6, A7);
  k5b    <<<dim3(640,3), 256, 0, stream>>>(si2, sj2, sk2, e2w, A4, A5, A6, A7, A1p, A2t, Cc);
  kh2    <<<640, 256, 0, stream>>>(e_b, e_f, Vt, Q3c, W2T0, A1p, A2t, Cc, op);
  k7     <<<1, 512, 0, stream>>>(op, ow, ob, (float*)d_out);
}

// Round 15
// 272.803 us; speedup vs baseline: 3.2460x; 1.0145x over previous
//
#include <hip/hip_runtime.h>
#include <hip/hip_bf16.h>

// UniqueEq3Net: conv stack -> e(640,64); t = e⊗e⊗e never materialized.
// Layer1 (transposed MFMA): h^T[o][k] = (B1⊙e_l)^T · U + Y0 + cadd.
// R15 = R14 + k5ij fused into k5am half-0 (ssij computed in LDS, one fewer
// launch + no global round-trip). kh01/kh2 untouched (structural floor:
// 4 waves/SIMD occupancy cap per R11/R12 spill evidence).

typedef unsigned short u16;
typedef __attribute__((ext_vector_type(8))) short bf8_t;   // 8 bf16 (4 VGPRs)
typedef __attribute__((ext_vector_type(4))) float f4_t;

#define LSTR 72   // padded LDS row stride (u16): 144B rows, 16B-aligned

__device__ inline u16 f2bf(float f){
  union { float f; unsigned u; } v; v.f = f;
  unsigned r = v.u + 0x7fffu + ((v.u >> 16) & 1u);
  return (u16)(r >> 16);
}
__device__ inline float bflo(unsigned u){ union { unsigned x; float f; } v; v.x = u << 16; return v.f; }
__device__ inline float bfhi(unsigned u){ union { unsigned x; float f; } v; v.x = u & 0xffff0000u; return v.f; }
__device__ inline unsigned pack2(float a, float b){ return (unsigned)f2bf(a) | ((unsigned)f2bf(b) << 16); }
__device__ inline unsigned cvtpk(float lo, float hi){
  __hip_bfloat162 h2 = __float22bfloat162_rn(make_float2(lo, hi));
  union { __hip_bfloat162 h; unsigned u; } c; c.h = h2; return c.u;
}
__device__ inline void unpack8(bf8_t x, float* o){
  union { bf8_t v; unsigned u[4]; } q; q.v = x;
  #pragma unroll
  for (int p = 0; p < 4; ++p){ o[2*p] = bflo(q.u[p]); o[2*p+1] = bfhi(q.u[p]); }
}
__device__ inline f4_t shfl4x(f4_t v, int m){
  f4_t r;
  r[0] = __shfl_xor(v[0], m); r[1] = __shfl_xor(v[1], m);
  r[2] = __shfl_xor(v[2], m); r[3] = __shfl_xor(v[3], m);
  return r;
}

// ---------------- conv1 + pool -> z1t ; blocks >=640 do weight prep ----------------
__global__ __launch_bounds__(256) void kconv1(const float* __restrict__ x, const float* __restrict__ w1,
                                              const float* __restrict__ b1, u16* __restrict__ z1t,
                                              const float* __restrict__ w2, const float* __restrict__ fcw,
                                              u16* __restrict__ wt2, u16* __restrict__ fcwT){
  __shared__ float simg[784];
  int img = blockIdx.x, tid = threadIdx.x;
  if (img >= 640){
    int t = (img - 640)*256 + tid, stride = 32*256;
    for (int i = t; i < 51200; i += stride){
      int tap = i >> 11, rc = i & 2047, co = rc >> 5, ci = rc & 31;
      wt2[i] = f2bf(w2[co*800 + ci*25 + tap]);
    }
    for (int i = t; i < 65536; i += stride){
      int o = i >> 10, k = i & 1023;
      fcwT[i] = f2bf(fcw[k*64 + o]);
    }
    return;
  }
  for (int i = tid; i < 784; i += 256) simg[i] = x[img*784 + i];
  const int c = tid & 31;
  float wc[25];
  #pragma unroll
  for (int t = 0; t < 25; ++t) wc[t] = w1[c*25 + t];
  const float bb = b1[c];
  __syncthreads();
  #pragma unroll 2
  for (int it = 0; it < 18; ++it){
    int p = (tid >> 5) + it*8;
    int py = p / 12, px = p % 12;
    float patch[36];
    const float* sp = &simg[2*py*28 + 2*px];
    #pragma unroll
    for (int yy = 0; yy < 6; ++yy)
      #pragma unroll
      for (int xx = 0; xx < 6; ++xx) patch[yy*6+xx] = sp[yy*28+xx];
    float mx = -1e30f;
    #pragma unroll
    for (int sy = 0; sy < 2; ++sy)
    #pragma unroll
    for (int sx = 0; sx < 2; ++sx){
      float s = bb;
      #pragma unroll
      for (int dy = 0; dy < 5; ++dy)
        #pragma unroll
        for (int dx = 0; dx < 5; ++dx)
          s += patch[(sy+dy)*6 + sx+dx] * wc[dy*5+dx];
      mx = fmaxf(mx, s);
    }
    z1t[(size_t)img*4608 + p*32 + c] = f2bf(fmaxf(mx, 0.f));
  }
}

// ---------------- conv2 (MFMA, 25 shifted K=32 GEMMs) + pool -> z2g (640,1024) bf16 ----------------
__global__ __launch_bounds__(256) void kconv2m(const u16* __restrict__ z1t, const u16* __restrict__ wt2,
                                               const float* __restrict__ b2, u16* __restrict__ z2g){
  __shared__ __align__(16) u16 sz[4608];
  __shared__ __align__(16) u16 sz2[1024];
  int img = blockIdx.x, tid = threadIdx.x;
  for (int i = tid; i < 576; i += 256)
    ((uint4*)sz)[i] = ((const uint4*)(z1t + (size_t)img*4608))[i];
  __syncthreads();
  const int wave = tid >> 6, lane = tid & 63, l15 = lane & 15, quad = lane >> 4;
  const int y = wave*2 + (l15 >> 3), x = l15 & 7;
  f4_t acc[4];
  acc[0] = (f4_t){0.f,0.f,0.f,0.f}; acc[1] = acc[0]; acc[2] = acc[0]; acc[3] = acc[0];
  #pragma unroll
  for (int dy = 0; dy < 5; ++dy)
    #pragma unroll
    for (int dx = 0; dx < 5; ++dx){
      const int tap = dy*5 + dx;
      bf8_t af = *(const bf8_t*)&sz[((y+dy)*12 + (x+dx))*32 + quad*8];
      const u16* wp = wt2 + tap*2048 + l15*32 + quad*8;
      #pragma unroll
      for (int nt = 0; nt < 4; ++nt){
        bf8_t bf = *(const bf8_t*)(wp + nt*512);
        acc[nt] = __builtin_amdgcn_mfma_f32_16x16x32_bf16(af, bf, acc[nt], 0, 0, 0);
      }
    }
  #pragma unroll
  for (int nt = 0; nt < 4; ++nt){
    int co = nt*16 + l15;
    float v0 = fmaxf(acc[nt][0], acc[nt][1]);
    float v1 = fmaxf(acc[nt][2], acc[nt][3]);
    v0 = fmaxf(v0, __shfl_xor(v0, 32));
    v1 = fmaxf(v1, __shfl_xor(v1, 32));
    if (quad < 2){
      float bb = b2[co];
      sz2[co*16 + wave*4 + quad*2 + 0] = f2bf(fmaxf(v0 + bb, 0.f));
      sz2[co*16 + wave*4 + quad*2 + 1] = f2bf(fmaxf(v1 + bb, 0.f));
    }
  }
  __syncthreads();
  if (tid < 128) ((uint4*)(z2g + (size_t)img*1024))[tid] = ((const uint4*)sz2)[tid];
}

// ---------------- fc: e = relu(z2g @ fcw + fcb) ----------------
__global__ __launch_bounds__(256) void kfc(const u16* __restrict__ z2g, const u16* __restrict__ fcwT,
                                           const float* __restrict__ fcb,
                                           float* __restrict__ e_f, u16* __restrict__ e_b){
  __shared__ __align__(16) u16 sA[16*1032];
  int img0 = blockIdx.x*16, tid = threadIdx.x;
  for (int i = tid; i < 2048; i += 256){
    int row = i >> 7, c16 = i & 127;
    ((uint4*)(sA + row*1032))[c16] = ((const uint4*)(z2g + (size_t)(img0+row)*1024))[c16];
  }
  __syncthreads();
  const int wave = tid >> 6, lane = tid & 63, l15 = lane & 15, quad = lane >> 4;
  const int o = wave*16 + l15;
  f4_t acc = (f4_t){0.f,0.f,0.f,0.f};
  #pragma unroll 8
  for (int ks = 0; ks < 32; ++ks){
    bf8_t af = *(const bf8_t*)&sA[l15*1032 + ks*32 + quad*8];
    bf8_t bf = *(const bf8_t*)(fcwT + (size_t)o*1024 + ks*32 + quad*8);
    acc = __builtin_amdgcn_mfma_f32_16x16x32_bf16(af, bf, acc, 0, 0, 0);
  }
  const float bb = fcb[o];
  #pragma unroll
  for (int r = 0; r < 4; ++r){
    int img = img0 + quad*4 + r;
    float v = fmaxf(acc[r] + bb, 0.f);
    e_f[img*64 + o] = v;
    e_b[img*64 + o] = f2bf(v);
  }
}

// ---------------- per-b precompute, grid (16,4) ----------------
__global__ __launch_bounds__(256) void kprep(const float* __restrict__ e_f, const float* __restrict__ e1w,
    const float* __restrict__ e1b, const float* __restrict__ e2w,
    float* __restrict__ Sg, u16* __restrict__ Vt, float* __restrict__ c0,
    float* __restrict__ P5, float* __restrict__ P6, u16* __restrict__ W2T0,
    u16* __restrict__ W3St){
  int b = blockIdx.x, ph = blockIdx.y, tid = threadIdx.x;
  __shared__ float se[2560];
  __shared__ float S[64], S2[64], S3[64];
  for (int i = tid; i < 2560; i += 256) se[i] = e_f[b*2560 + i];
  __syncthreads();
  if (tid < 64){
    float s = 0.f;
    for (int i = 0; i < 40; ++i) s += se[i*64 + tid];
    S[tid] = s; S2[tid] = s*s; S3[tid] = s*s*s;
    if (ph == 0) Sg[b*64 + tid] = s;
  }
  __syncthreads();
  {
    const int m = ph;
    for (int idx = tid; idx < 4096; idx += 256){
      int o = idx >> 6, d = idx & 63;
      float v;
      if (m == 0)      v = e1w[d*64 + o];
      else if (m == 1) v = S[d] * e1w[4096  + d*64 + o];
      else if (m == 2) v = S[d] * e1w[8192  + d*64 + o];
      else             v = S2[d] * e1w[16384 + d*64 + o];
      Vt[(size_t)b*16384 + m*4096 + idx] = f2bf(v);
    }
  }
  if (ph == 0){
    if (tid < 64){
      float a = e1b[tid];
      for (int d = 0; d < 64; ++d) a += S3[d] * e1w[7*4096 + d*64 + tid];
      c0[b*64 + tid] = a;
    }
  } else if (ph == 1){
    for (int idx = tid; idx < 4096; idx += 256){
      int o = idx >> 6, d = idx & 63;
      W3St[(size_t)b*4096 + idx] = f2bf(S[d] * e1w[3*4096 + d*64 + o]);
    }
  } else {
    int lo = (ph == 2) ? 0 : 1280, hi = lo + 1280;
    for (int idx = lo + tid; idx < hi; idx += 256){
      int j = idx >> 6, o = idx & 63;
      float a5 = 0.f, a6 = 0.f;
      for (int d = 0; d < 64; ++d){
        float es = se[j*64 + d] * S2[d];
        a5 += es * e1w[5*4096 + d*64 + o];
        a6 += es * e1w[6*4096 + d*64 + o];
      }
      P5[(b*40+j)*64 + o] = a5;
      P6[(b*40+j)*64 + o] = a6;
    }
    if (ph == 3 && b == 0){
      for (int idx = tid; idx < 2048; idx += 256){
        int o = idx >> 6, d = idx & 63;
        W2T0[o*64 + d] = f2bf(e2w[d*32 + o]);
      }
    }
  }
}

// ---------------- kpq: P[i] tile in LDS AND Q3c[b,i,:,:] via MFMA ----------------
__global__ __launch_bounds__(256) void kpq(const u16* __restrict__ e_b, const u16* __restrict__ W3St,
    const float* __restrict__ P5, const float* __restrict__ P6, const float* __restrict__ c0,
    float* __restrict__ Q3c){
  __shared__ __align__(16) u16 sP[48*LSTR];
  __shared__ __align__(16) u16 sW[64*LSTR];
  int blk = blockIdx.x, b = blk/40, i = blk%40, tid = threadIdx.x;
  const int wave = tid >> 6, lane = tid & 63, l15 = lane & 15, quad = lane >> 4;
  for (int idx = tid; idx < 2048; idx += 256){
    int o = idx >> 5, c = idx & 31;
    ((unsigned*)(sW + o*LSTR))[c] = ((const unsigned*)(W3St + (size_t)b*4096))[idx];
  }
  const unsigned* eb32 = (const unsigned*)(e_b + (size_t)b*2560);
  const unsigned* el = eb32 + i*32;
  #pragma unroll
  for (int it = 0; it < 6; ++it){
    int idx = tid + it*256;
    int k = idx >> 5, d2 = idx & 31;
    unsigned pv = 0;
    if (k < 40){
      unsigned ul = el[d2], uk = eb32[k*32 + d2];
      pv = pack2(bflo(ul)*bflo(uk), bfhi(ul)*bfhi(uk));
    }
    ((unsigned*)(sP + k*LSTR))[d2] = pv;
  }
  __syncthreads();
  bf8_t wf[2];
  #pragma unroll
  for (int ks = 0; ks < 2; ++ks)
    wf[ks] = *(const bf8_t*)&sW[(wave*16 + l15)*LSTR + ks*32 + quad*8];
  f4_t acc[3];
  #pragma unroll
  for (int n = 0; n < 3; ++n){
    f4_t a = (f4_t){0.f,0.f,0.f,0.f};
    #pragma unroll
    for (int ks = 0; ks < 2; ++ks){
      bf8_t pkf = *(const bf8_t*)&sP[(n*16 + l15)*LSTR + ks*32 + quad*8];
      a = __builtin_amdgcn_mfma_f32_16x16x32_bf16(wf[ks], pkf, a, 0, 0, 0);
    }
    acc[n] = a;
  }
  const int obase = wave*16 + quad*4;
  f4_t p6v = *(const f4_t*)&P6[(b*40+i)*64 + obase];
  f4_t c0v = *(const f4_t*)&c0[b*64 + obase];
  #pragma unroll
  for (int n = 0; n < 3; ++n){
    int j = n*16 + l15;
    if (j < 40){
      f4_t p5v = *(const f4_t*)&P5[(b*40+j)*64 + obase];
      f4_t outv = acc[n] + p5v + p6v + c0v;
      *(f4_t*)&Q3c[((size_t)((b*40+i)*40 + j))*64 + obase] = outv;
    }
  }
}

// ---------------- layer-1 reduction passes (modes 0 & 1); +ssik/ssjk epilogue ----------------
__global__ __launch_bounds__(256, 4) void kh01(
    const u16* __restrict__ e_b, const float* __restrict__ e_f,
    const u16* __restrict__ Vt, const float* __restrict__ Q3c,
    float* __restrict__ si2, float* __restrict__ sj2, float* __restrict__ sk2,
    float* __restrict__ ssik, float* __restrict__ ssjk)
{
  __shared__ __align__(16) char smem[25344];
  u16*   sU  = (u16*)smem;             // dead after setup
  u16*   sB1 = (u16*)(smem + 6912);    // dead after setup
  u16*   sB0 = (u16*)(smem + 16128);
  float* sUf = (float*)smem;           // aliases sU+sB1
  const int tid = threadIdx.x;
  const int b = blockIdx.x / 40, fix = blockIdx.x % 40;
  const int mode = blockIdx.y;
  const int wave = tid >> 6, lane = tid & 63, l15 = lane & 15, quad = lane >> 4;
  const f4_t z4 = (f4_t){0.f,0.f,0.f,0.f};

  for (int idx = tid; idx < 1536; idx += 256){
    int r = idx >> 5, c = idx & 31;
    unsigned v = (r < 40) ? ((const unsigned*)e_b)[(b*40 + r)*32 + c] : 0u;
    ((unsigned*)(sU + r*LSTR))[c] = v;
  }
  float efr[10];
  #pragma unroll
  for (int t = 0; t < 10; ++t) efr[t] = e_f[b*2560 + tid + t*256];
  const unsigned* eg = (const unsigned*)(e_b + (size_t)(b*40 + fix)*64);
  const unsigned* Vb = (const unsigned*)(Vt + (size_t)b*16384);
  for (int idx = tid; idx < 2048; idx += 256){
    int o = idx >> 5, d2 = idx & 31;
    unsigned eu = eg[d2];
    unsigned v0 = Vb[o*32 + d2];
    unsigned vA = Vb[(2-mode)*2048 + o*32 + d2];
    unsigned vB = Vb[(1+mode)*2048 + o*32 + d2];
    unsigned v3 = Vb[3*2048 + o*32 + d2];
    float e0 = bflo(eu), e1 = bfhi(eu);
    ((unsigned*)(sB1 + o*LSTR))[d2] = pack2(e0*bflo(v0)+bflo(vA), e1*bfhi(v0)+bfhi(vA));
    ((unsigned*)(sB0 + o*LSTR))[d2] = pack2(e0*bflo(vB)+bflo(v3), e1*bfhi(vB)+bfhi(v3));
  }
  __syncthreads();

  f4_t b1v[4];
  bf8_t ua[3][2];
  f4_t Y0[3];
  {
    bf8_t b0f[2], b1f[2];
    float tmp[8];
    #pragma unroll
    for (int ks = 0; ks < 2; ++ks){
      b1f[ks] = *(const bf8_t*)&sB1[(wave*16 + l15)*LSTR + ks*32 + quad*8];
      b0f[ks] = *(const bf8_t*)&sB0[(wave*16 + l15)*LSTR + ks*32 + quad*8];
      unpack8(b1f[ks], tmp);
      b1v[2*ks]   = (f4_t){tmp[0],tmp[1],tmp[2],tmp[3]};
      b1v[2*ks+1] = (f4_t){tmp[4],tmp[5],tmp[6],tmp[7]};
    }
    #pragma unroll
    for (int n = 0; n < 3; ++n){
      f4_t a = z4;
      #pragma unroll
      for (int ks = 0; ks < 2; ++ks){
        ua[n][ks] = *(const bf8_t*)&sU[(n*16 + l15)*LSTR + ks*32 + quad*8];
        a = __builtin_amdgcn_mfma_f32_16x16x32_bf16(b0f[ks], ua[n][ks], a, 0, 0, 0);
      }
      Y0[n] = a;
    }
  }
  __syncthreads();
  #pragma unroll
  for (int t = 0; t < 10; ++t) sUf[tid + t*256] = efr[t];
  __syncthreads();

  const int obase = wave*16 + quad*4;
  const float km = (l15 < 8) ? 1.f : 0.f;
  const f4_t km4 = (f4_t){km, km, km, km};
  f4_t sacc[3];
  sacc[0] = z4; sacc[1] = z4; sacc[2] = z4;

  // pointer-carried streams (no per-iter 64-bit address mul)
  const int qstride = mode ? 64 : 2560;
  const float* qp = Q3c + (size_t)b*102400 + (mode ? (size_t)fix*2560 : (size_t)fix*64) + obase;
  float* skp = sk2 + ((size_t)(b*40)*40 + fix)*64 + obase;   // mode0 only; stride 2560
  const float* ep = sUf + quad*8;

  f4_t cadd_n = *(const f4_t*)qp; qp += qstride;
  #pragma unroll 2
  for (int l = 0; l < 40; ++l){
    f4_t cadd = cadd_n;
    if (l < 39){ cadd_n = *(const f4_t*)qp; qp += qstride; }
    f4_t p00 = b1v[0] * *(const f4_t*)(ep);
    f4_t p01 = b1v[1] * *(const f4_t*)(ep + 4);
    f4_t p10 = b1v[2] * *(const f4_t*)(ep + 32);
    f4_t p11 = b1v[3] * *(const f4_t*)(ep + 36);
    ep += 64;
    union { bf8_t v; unsigned u[4]; } m0, m1;
    m0.u[0] = cvtpk(p00[0], p00[1]); m0.u[1] = cvtpk(p00[2], p00[3]);
    m0.u[2] = cvtpk(p01[0], p01[1]); m0.u[3] = cvtpk(p01[2], p01[3]);
    m1.u[0] = cvtpk(p10[0], p10[1]); m1.u[1] = cvtpk(p10[2], p10[3]);
    m1.u[2] = cvtpk(p11[0], p11[1]); m1.u[3] = cvtpk(p11[2], p11[3]);
    f4_t khs = z4;
    #pragma unroll
    for (int n = 0; n < 3; ++n){
      f4_t a = Y0[n];
      a = __builtin_amdgcn_mfma_f32_16x16x32_bf16(m0.v, ua[n][0], a, 0, 0, 0);
      a = __builtin_amdgcn_mfma_f32_16x16x32_bf16(m1.v, ua[n][1], a, 0, 0, 0);
      f4_t h = __builtin_elementwise_max(a + cadd, z4);
      sacc[n] += h;                         // k>=40 garbage: masked at reductions
      if (mode == 0) khs += (n == 2) ? h * km4 : h;
    }
    if (mode == 0){
      khs += shfl4x(khs, 1);
      khs += shfl4x(khs, 2);
      khs += shfl4x(khs, 4);
      khs += shfl4x(khs, 8);
      if (l15 == 0) *(f4_t*)skp = khs;
      skp += 2560;
    }
  }
  float* dst = mode ? sj2 : si2;
  #pragma unroll
  for (int n = 0; n < 3; ++n){
    int k = n*16 + l15;
    if (k < 40)
      *(f4_t*)&dst[((size_t)((b*40 + fix)*40 + k))*64 + obase] = sacc[n];
  }
  // epilogue: ssik (mode0) / ssjk (mode1) = Σ_k of this block's si2/sj2 row
  f4_t t4 = sacc[0] + sacc[1] + sacc[2]*km4;
  t4 += shfl4x(t4, 1); t4 += shfl4x(t4, 2);
  t4 += shfl4x(t4, 4); t4 += shfl4x(t4, 8);
  float* sred = mode ? ssjk : ssik;
  if (l15 == 0) *(f4_t*)&sred[b*2560 + fix*64 + obase] = t4;
}

// ---------------- k5am: ssij (in-LDS) + A4/A7 | A5/A6, grid (16,2) ----------------
__global__ __launch_bounds__(256) void k5am(const float* __restrict__ si2, const float* __restrict__ ssik,
    const float* __restrict__ ssjk, const float* __restrict__ e2w, const float* __restrict__ e2b,
    float* __restrict__ A4, float* __restrict__ A5, float* __restrict__ A6, float* __restrict__ A7){
  int b = blockIdx.x, half = blockIdx.y, tid = threadIdx.x;
  __shared__ __align__(16) f4_t s1[640], s2[640];
  __shared__ __align__(16) f4_t w1t[32*17], w2t[32*17];
  __shared__ float ss2[64];
  const int o = tid & 31, rb = tid >> 5;
  const f4_t z4 = (f4_t){0.f,0.f,0.f,0.f};
  if (half == 0){
    // ssij[k,d] = sum_j si2[b,j,k,d], computed straight into LDS
    for (int idx = tid; idx < 640; idx += 256){
      f4_t a = z4;
      const f4_t* p = (const f4_t*)&si2[(size_t)(b*40)*2560] + idx;
      #pragma unroll 4
      for (int j = 0; j < 40; ++j){ a += *p; p += 640; }
      s1[idx] = a;
    }
    for (int idx = tid; idx < 512; idx += 256){
      int oo = idx >> 4, d4 = idx & 15;
      f4_t w;
      #pragma unroll
      for (int r = 0; r < 4; ++r) w[r] = e2w[4*2048 + (4*d4+r)*32 + oo];
      w1t[oo*17 + d4] = w;
    }
    __syncthreads();
    if (tid < 64){
      const float* s1f = (const float*)s1;
      float a = 0.f;
      for (int k = 0; k < 40; ++k) a += s1f[k*64 + tid];
      ss2[tid] = a;
    }
    __syncthreads();
    float acc[5] = {0.f,0.f,0.f,0.f,0.f};
    #pragma unroll 4
    for (int d4 = 0; d4 < 16; ++d4){
      f4_t w = w1t[o*17 + d4];
      #pragma unroll
      for (int it = 0; it < 5; ++it){
        f4_t s = s1[(rb + 8*it)*16 + d4];
        acc[it] += s[0]*w[0] + s[1]*w[1] + s[2]*w[2] + s[3]*w[3];
      }
    }
    #pragma unroll
    for (int it = 0; it < 5; ++it)
      A4[(b*40 + rb + 8*it)*32 + o] = acc[it];
    if (tid < 32){
      float a = e2b[tid];
      for (int d = 0; d < 64; ++d) a += ss2[d] * e2w[7*2048 + d*32 + tid];
      A7[b*32 + tid] = a;
    }
  } else {
    for (int i = tid; i < 640; i += 256){
      s1[i] = ((const f4_t*)&ssik[b*2560])[i];
      s2[i] = ((const f4_t*)&ssjk[b*2560])[i];
    }
    for (int idx = tid; idx < 512; idx += 256){
      int oo = idx >> 4, d4 = idx & 15;
      f4_t w5, w6;
      #pragma unroll
      for (int r = 0; r < 4; ++r){
        w5[r] = e2w[5*2048 + (4*d4+r)*32 + oo];
        w6[r] = e2w[6*2048 + (4*d4+r)*32 + oo];
      }
      w1t[oo*17 + d4] = w5;
      w2t[oo*17 + d4] = w6;
    }
    __syncthreads();
    float a5[5] = {0.f,0.f,0.f,0.f,0.f}, a6[5] = {0.f,0.f,0.f,0.f,0.f};
    #pragma unroll 4
    for (int d4 = 0; d4 < 16; ++d4){
      f4_t w5 = w1t[o*17 + d4], w6 = w2t[o*17 + d4];
      #pragma unroll
      for (int it = 0; it < 5; ++it){
        f4_t sa = s1[(rb + 8*it)*16 + d4];
        f4_t sb = s2[(rb + 8*it)*16 + d4];
        a5[it] += sa[0]*w5[0] + sa[1]*w5[1] + sa[2]*w5[2] + sa[3]*w5[3];
        a6[it] += sb[0]*w6[0] + sb[1]*w6[1] + sb[2]*w6[2] + sb[3]*w6[3];
      }
    }
    #pragma unroll
    for (int it = 0; it < 5; ++it){
      A5[(b*40 + rb + 8*it)*32 + o] = a5[it];
      A6[(b*40 + rb + 8*it)*32 + o] = a6[it];
    }
  }
}

// ---------------- big addends, f4-vectorized ----------------
__global__ __launch_bounds__(256) void k5b(const float* __restrict__ si2, const float* __restrict__ sj2,
    const float* __restrict__ sk2, const float* __restrict__ e2w,
    const float* __restrict__ A4, const float* __restrict__ A5, const float* __restrict__ A6,
    const float* __restrict__ A7,
    float* __restrict__ A1p, float* __restrict__ A2t, float* __restrict__ Cc){
  int which = blockIdx.y;
  int blk = blockIdx.x, b = blk/40, f = blk%40, tid = threadIdx.x;
  __shared__ __align__(16) f4_t ssrc[640];
  __shared__ __align__(16) f4_t swt[32*17];
  const float* S = (which == 0) ? si2 : (which == 1) ? sj2 : sk2;
  int wop = which + 1;
  const f4_t* Sg4 = (const f4_t*)&S[(size_t)(b*40+f)*2560];
  for (int idx = tid; idx < 640; idx += 256) ssrc[idx] = Sg4[idx];
  for (int idx = tid; idx < 512; idx += 256){
    int o = idx >> 4, d4 = idx & 15;
    f4_t w;
    #pragma unroll
    for (int r = 0; r < 4; ++r) w[r] = e2w[wop*2048 + (4*d4+r)*32 + o];
    swt[o*17 + d4] = w;
  }
  __syncthreads();
  const int o = tid & 31, rb = tid >> 5;
  float acc[5] = {0.f, 0.f, 0.f, 0.f, 0.f};
  #pragma unroll 4
  for (int d4 = 0; d4 < 16; ++d4){
    f4_t w = swt[o*17 + d4];
    #pragma unroll
    for (int it = 0; it < 5; ++it){
      f4_t s = ssrc[(rb + 8*it)*16 + d4];
      acc[it] += s[0]*w[0] + s[1]*w[1] + s[2]*w[2] + s[3]*w[3];
    }
  }
  #pragma unroll
  for (int it = 0; it < 5; ++it){
    int r = rb + 8*it;
    size_t oi = ((size_t)(b*40+f)*40 + r)*32 + o;
    float a = acc[it];
    if (which == 0)      A1p[oi] = a + A4[(b*40+r)*32 + o];
    else if (which == 1) A2t[oi] = a;
    else                 Cc[oi]  = a + A5[(b*40+r)*32 + o] + A6[(b*40+f)*32 + o] + A7[b*32 + o];
  }
}

// ---------------- mode2: layer-2; pointer-carried streams; sH dbuf over sB1/sB0 ----------------
__global__ __launch_bounds__(256, 3) void kh2(
    const u16* __restrict__ e_b, const float* __restrict__ e_f,
    const u16* __restrict__ Vt, const float* __restrict__ Q3c, const u16* __restrict__ W2T0,
    const float* __restrict__ A1p, const float* __restrict__ A2t, const float* __restrict__ Cc,
    float* __restrict__ out_part)
{
  __shared__ __align__(16) char smem[30080];
  u16*   sB1 = (u16*)smem;                  // loop: sH buf0
  u16*   sB0 = (u16*)(smem + 9216);         // loop: sH buf1
  u16*   sU  = (u16*)(smem + 18432);        // dead after setup
  u16*   sW2 = (u16*)(smem + 18432 + 6912); // dead after setup
  float* sUf = (float*)(smem + 18432);      // aliases sU+sW2
  float* soacc = (float*)(smem + 29952);
  const int tid = threadIdx.x;
  const int b = blockIdx.x / 40, fix = blockIdx.x % 40;   // fix = j
  const int wave = tid >> 6, lane = tid & 63, l15 = lane & 15, quad = lane >> 4;
  const f4_t z4 = (f4_t){0.f,0.f,0.f,0.f};

  for (int idx = tid; idx < 1536; idx += 256){
    int r = idx >> 5, c = idx & 31;
    unsigned v = (r < 40) ? ((const unsigned*)e_b)[(b*40 + r)*32 + c] : 0u;
    ((unsigned*)(sU + r*LSTR))[c] = v;
  }
  float efr[10];
  #pragma unroll
  for (int t = 0; t < 10; ++t) efr[t] = e_f[b*2560 + tid + t*256];
  const unsigned* eg = (const unsigned*)(e_b + (size_t)(b*40 + fix)*64);
  const unsigned* Vb = (const unsigned*)(Vt + (size_t)b*16384);
  for (int idx = tid; idx < 2048; idx += 256){
    int o = idx >> 5, d2 = idx & 31;
    unsigned eu = eg[d2];
    unsigned v0 = Vb[o*32 + d2];
    unsigned vA = Vb[2*2048 + o*32 + d2];
    unsigned vB = Vb[1*2048 + o*32 + d2];
    unsigned v3 = Vb[3*2048 + o*32 + d2];
    float e0 = bflo(eu), e1 = bfhi(eu);
    ((unsigned*)(sB1 + o*LSTR))[d2] = pack2(e0*bflo(v0)+bflo(vA), e1*bfhi(v0)+bfhi(vA));
    ((unsigned*)(sB0 + o*LSTR))[d2] = pack2(e0*bflo(vB)+bflo(v3), e1*bfhi(vB)+bfhi(v3));
  }
  for (int idx = tid; idx < 1024; idx += 256){
    int o = idx >> 5, c = idx & 31;
    ((unsigned*)(sW2 + o*LSTR))[c] = ((const unsigned*)W2T0)[idx];
  }
  if (tid < 32) soacc[tid] = 0.f;
  __syncthreads();

  f4_t b1v[4];
  bf8_t ua[3][2], wfA[2][2];
  f4_t Y0[3];
  {
    bf8_t b0f[2], b1f[2];
    float tmp[8];
    #pragma unroll
    for (int ks = 0; ks < 2; ++ks){
      b1f[ks] = *(const bf8_t*)&sB1[(wave*16 + l15)*LSTR + ks*32 + quad*8];
      b0f[ks] = *(const bf8_t*)&sB0[(wave*16 + l15)*LSTR + ks*32 + quad*8];
      unpack8(b1f[ks], tmp);
      b1v[2*ks]   = (f4_t){tmp[0],tmp[1],tmp[2],tmp[3]};
      b1v[2*ks+1] = (f4_t){tmp[4],tmp[5],tmp[6],tmp[7]};
      #pragma unroll
      for (int m = 0; m < 2; ++m)
        wfA[m][ks] = *(const bf8_t*)&sW2[(m*16 + l15)*LSTR + ks*32 + quad*8];
    }
    #pragma unroll
    for (int n = 0; n < 3; ++n){
      f4_t a = z4;
      #pragma unroll
      for (int ks = 0; ks < 2; ++ks){
        ua[n][ks] = *(const bf8_t*)&sU[(n*16 + l15)*LSTR + ks*32 + quad*8];
        a = __builtin_amdgcn_mfma_f32_16x16x32_bf16(b0f[ks], ua[n][ks], a, 0, 0, 0);
      }
      Y0[n] = a;
    }
  }
  __syncthreads();   // setup reads done (sB1/sB0/sU/sW2 all dead)
  #pragma unroll
  for (int t = 0; t < 10; ++t) sUf[tid + t*256] = efr[t];
  __syncthreads();

  const int obase = wave*16 + quad*4;
  const int o2b   = quad*4;
  const int kme   = wave*16 + l15;
  const int kmc   = kme < 40 ? kme : 39;
  const bool kval = (kme < 40) & (wave < 3);
  f4_t pa1[2], psum[2];
  psum[0] = z4; psum[1] = z4;
  if (wave < 3){
    #pragma unroll
    for (int m = 0; m < 2; ++m)
      pa1[m] = *(const f4_t*)&A1p[((size_t)((b*40 + fix)*40 + kmc))*32 + m*16 + o2b];
  }

  // pointer-carried streams
  const float* qp  = Q3c + (size_t)b*102400 + (size_t)fix*64 + obase;        // stride 2560
  const float* a2p = A2t + ((size_t)b*1600 + kmc)*32 + o2b;                  // stride 1280
  const float* ccp = Cc  + ((size_t)b*1600 + fix)*32 + o2b;                  // stride 1280
  const float* ep  = sUf + quad*8;

  f4_t cadd_n = *(const f4_t*)qp; qp += 2560;
  #pragma unroll 2
  for (int l = 0; l < 40; ++l){
    f4_t cadd = cadd_n;
    if (l < 39){ cadd_n = *(const f4_t*)qp; qp += 2560; }
    f4_t a2v[2], ccv[2];
    if (wave < 3){
      a2v[0] = *(const f4_t*)(a2p);      a2v[1] = *(const f4_t*)(a2p + 16);
      ccv[0] = *(const f4_t*)(ccp);      ccv[1] = *(const f4_t*)(ccp + 16);
    }
    a2p += 1280; ccp += 1280;
    f4_t p00 = b1v[0] * *(const f4_t*)(ep);
    f4_t p01 = b1v[1] * *(const f4_t*)(ep + 4);
    f4_t p10 = b1v[2] * *(const f4_t*)(ep + 32);
    f4_t p11 = b1v[3] * *(const f4_t*)(ep + 36);
    ep += 64;
    union { bf8_t v; unsigned u[4]; } m0, m1;
    m0.u[0] = cvtpk(p00[0], p00[1]); m0.u[1] = cvtpk(p00[2], p00[3]);
    m0.u[2] = cvtpk(p01[0], p01[1]); m0.u[3] = cvtpk(p01[2], p01[3]);
    m1.u[0] = cvtpk(p10[0], p10[1]); m1.u[1] = cvtpk(p10[2], p10[3]);
    m1.u[2] = cvtpk(p11[0], p11[1]); m1.u[3] = cvtpk(p11[2], p11[3]);
    u16* Hb = (u16*)(smem + (l & 1)*9216);
    #pragma unroll
    for (int n = 0; n < 3; ++n){
      f4_t a = Y0[n];
      a = __builtin_amdgcn_mfma_f32_16x16x32_bf16(m0.v, ua[n][0], a, 0, 0, 0);
      a = __builtin_amdgcn_mfma_f32_16x16x32_bf16(m1.v, ua[n][1], a, 0, 0, 0);
      f4_t h = __builtin_elementwise_max(a + cadd, z4);   // k>=40 rows masked at psum
      uint2 pw;
      pw.x = cvtpk(h[0], h[1]);
      pw.y = cvtpk(h[2], h[3]);
      *(uint2*)&Hb[(n*16 + l15)*LSTR + obase] = pw;
    }
    __syncthreads();
    if (wave < 3){
      bf8_t hB[2];
      #pragma unroll
      for (int ks = 0; ks < 2; ++ks)
        hB[ks] = *(const bf8_t*)&Hb[(wave*16 + l15)*LSTR + ks*32 + quad*8];
      #pragma unroll
      for (int m = 0; m < 2; ++m){
        f4_t y = z4;
        y = __builtin_amdgcn_mfma_f32_16x16x32_bf16(wfA[m][0], hB[0], y, 0, 0, 0);
        y = __builtin_amdgcn_mfma_f32_16x16x32_bf16(wfA[m][1], hB[1], y, 0, 0, 0);
        if (kval){
          f4_t v = y + pa1[m] + a2v[m] + ccv[m];
          psum[m] += __builtin_elementwise_max(v, z4);
        }
      }
    }
  }

  if (wave < 3){
    #pragma unroll
    for (int m = 0; m < 2; ++m){
      f4_t v = psum[m];
      v += shfl4x(v, 1); v += shfl4x(v, 2); v += shfl4x(v, 4); v += shfl4x(v, 8);
      if (l15 == 0){
        #pragma unroll
        for (int r = 0; r < 4; ++r) atomicAdd(&soacc[m*16 + o2b + r], v[r]);
      }
    }
  }
  __syncthreads();
  if (tid < 32) out_part[(b*40 + fix)*32 + tid] = soacc[tid];
}

// ---------------- final: sum_j out_part, relu, dot out_w (parallel) ----------------
__global__ __launch_bounds__(512) void k7(const float* __restrict__ out_part, const float* __restrict__ ow,
                                          const float* __restrict__ ob, float* __restrict__ out){
  int tid = threadIdx.x;
  int b = tid >> 5, o = tid & 31;
  float s = 0.f;
  for (int j = 0; j < 40; ++j) s += out_part[(b*40 + j)*32 + o];
  s = s > 0.f ? s : 0.f;
  float v = s * ow[o];
  v += __shfl_xor(v, 1); v += __shfl_xor(v, 2); v += __shfl_xor(v, 4);
  v += __shfl_xor(v, 8); v += __shfl_xor(v, 16);
  if (o == 0) out[b] = v + ob[0];
}

extern "C" void kernel_launch(void* const* d_in, const int* in_sizes, int n_in,
                              void* d_out, int out_size, void* d_ws, size_t ws_size,
                              hipStream_t stream){
  const float* x    = (const float*)d_in[0];
  const float* c1w  = (const float*)d_in[1];
  const float* c1b  = (const float*)d_in[2];
  const float* c2w  = (const float*)d_in[3];
  const float* c2b  = (const float*)d_in[4];
  const float* fcw  = (const float*)d_in[5];
  const float* fcb  = (const float*)d_in[6];
  const float* e1w  = (const float*)d_in[7];
  const float* e1b  = (const float*)d_in[8];
  const float* e2w  = (const float*)d_in[9];
  const float* e2b  = (const float*)d_in[10];
  const float* ow   = (const float*)d_in[11];
  const float* ob   = (const float*)d_in[12];

  char* ws = (char*)d_ws;
  size_t off = 0;
  auto alloc = [&](size_t bytes) -> void* {
    void* p = ws + off;
    off += (bytes + 255) & ~(size_t)255;
    return p;
  };
  u16*   z1t  = (u16*)  alloc((size_t)640*4608*2);
  u16*   wt2  = (u16*)  alloc(51200*2);
  u16*   fcwT = (u16*)  alloc(65536*2);
  u16*   z2g  = (u16*)  alloc((size_t)640*1024*2);
  float* e_f  = (float*)alloc(40960*4);
  u16*   e_b  = (u16*)  alloc(40960*2);
  float* Sg   = (float*)alloc(1024*4);
  u16*   Vt   = (u16*)  alloc((size_t)16*16384*2);
  float* c0   = (float*)alloc(1024*4);
  float* P5   = (float*)alloc(40960*4);
  float* P6   = (float*)alloc(40960*4);
  u16*   W2T0 = (u16*)  alloc(2048*2);
  u16*   W3St = (u16*)  alloc((size_t)16*4096*2);
  float* Q3c  = (float*)alloc((size_t)1638400*4);
  float* si2  = (float*)alloc((size_t)1638400*4);
  float* sj2  = (float*)alloc((size_t)1638400*4);
  float* sk2  = (float*)alloc((size_t)1638400*4);
  float* ssik = (float*)alloc(40960*4);
  float* ssjk = (float*)alloc(40960*4);
  float* A4   = (float*)alloc(20480*4);
  float* A5   = (float*)alloc(20480*4);
  float* A6   = (float*)alloc(20480*4);
  float* A7   = (float*)alloc(512*4);
  float* A1p  = (float*)alloc((size_t)819200*4);
  float* A2t  = (float*)alloc((size_t)819200*4);
  float* Cc   = (float*)alloc((size_t)819200*4);
  float* op   = (float*)alloc(20480*4);
  (void)in_sizes; (void)n_in; (void)out_size; (void)ws_size;

  kconv1 <<<672, 256, 0, stream>>>(x, c1w, c1b, z1t, c2w, fcw, wt2, fcwT);
  kconv2m<<<640, 256, 0, stream>>>(z1t, wt2, c2b, z2g);
  kfc    <<<40,  256, 0, stream>>>(z2g, fcwT, fcb, e_f, e_b);
  kprep  <<<dim3(16,4), 256, 0, stream>>>(e_f, e1w, e1b, e2w, Sg, Vt, c0, P5, P6, W2T0, W3St);
  kpq    <<<640, 256, 0, stream>>>(e_b, W3St, P5, P6, c0, Q3c);
  kh01   <<<dim3(640,2), 256, 0, stream>>>(e_b, e_f, Vt, Q3c, si2, sj2, sk2, ssik, ssjk);
  k5am   <<<dim3(16,2), 256, 0, stream>>>(si2, ssik, ssjk, e2w, e2b, A4, A5, A6, A7);
  k5b    <<<dim3(640,3), 256, 0, stream>>>(si2, sj2, sk2, e2w, A4, A5, A6, A7, A1p, A2t, Cc);
  kh2    <<<640, 256, 0, stream>>>(e_b, e_f, Vt, Q3c, W2T0, A1p, A2t, Cc, op);
  k7     <<<1, 512, 0, stream>>>(op, ow, ob, (float*)d_out);
}